// Round 13
// baseline (806.718 us; speedup 1.0000x reference)
//
#include <hip/hip_runtime.h>
#include <stdint.h>

// Problem constants (fixed instance from setup_inputs)
#define B_   2
#define T_   64
#define S_   1024
#define C_   512
#define H_   8
#define N_   (T_ * S_)      // 65536
#define M_   (B_ * N_)      // 131072
#define WIN_ 5

typedef unsigned short u16;
typedef __bf16 bf16;
typedef __bf16 bf16x8 __attribute__((ext_vector_type(8)));
typedef float  f32x4  __attribute__((ext_vector_type(4)));
typedef u16    u16x8  __attribute__((ext_vector_type(8)));

static __device__ __forceinline__ u16 f2bf(float f) {
    return __builtin_bit_cast(u16, (bf16)f);   // RNE
}
static __device__ __forceinline__ float bf2f(u16 u) {
    return __builtin_bit_cast(float, (uint32_t)u << 16);
}
// async global->LDS, 16B per lane; LDS dest is wave-uniform base + lane*16
static __device__ __forceinline__ void gload16(const void* g, void* l) {
    __builtin_amdgcn_global_load_lds(
        (const __attribute__((address_space(1))) void*)g,
        (__attribute__((address_space(3))) void*)l, 16, 0, 0);
}
// row permutation: logical (b,t,s) flat row -> physical (b,s,t) flat row
static __device__ __forceinline__ long permute_row(long grow) {
    int b = (int)(grow >> 16);
    int t = (int)(grow >> 10) & 63;
    int s = (int)grow & 1023;
    return ((long)((b << 10) | s)) * 64 + t;
}

// A-side pre-swizzle layout (bf16 [row][512] activations, row = PHYSICAL row):
// logical (chunk c in [0,16), granule g in [0,4), elem j) stored at
// r*512 + (c ^ ((r>>3)&1))*32 + ((g ^ ((r>>1)&3))<<3) + j. 0 conflicts measured.
// Weights are LINEAR transposed [NCOL][512] (B read direct from global).

// ---------------------------------------------------------------------------
// Weight prep: W [512][NCOL] fp32 -> WT [NCOL][512] bf16, LINEAR transpose.
// ---------------------------------------------------------------------------
__global__ __launch_bounds__(256) void prep_w(const float* __restrict__ W,
                                              u16* __restrict__ WT, int NCOL) {
    int id = blockIdx.x * 256 + threadIdx.x;
    int n  = id % NCOL;            // consecutive threads -> consecutive n (coalesced)
    int gi = id / NCOL;            // 0..63: 8-elem k-granule
    u16x8 w;
    #pragma unroll
    for (int j = 0; j < 8; ++j) w[j] = f2bf(W[(size_t)(gi * 8 + j) * NCOL + n]);
    *(u16x8*)&WT[(size_t)n * 512 + gi * 8] = w;
}

// ---------------------------------------------------------------------------
// x prep: x [M][512] fp32 (rows (b,t,s)) -> xb bf16 rows PERMUTED to (b,s,t),
// pre-swizzled (A-side layout) with keys from the permuted row index.
// ---------------------------------------------------------------------------
__global__ __launch_bounds__(256) void prep_x(const float* __restrict__ x,
                                              u16* __restrict__ xb) {
    const size_t total = (size_t)M_ * 64;   // 16B granules
    for (size_t id = (size_t)blockIdx.x * 256 + threadIdx.x; id < total;
         id += (size_t)gridDim.x * 256) {
        long r_in = (long)(id >> 6);
        int  gi   = (int)(id & 63);
        int chunk = gi >> 2;
        int g     = gi & 3;
        long rid  = permute_row(r_in);
        int cb  = (int)(rid >> 3) & 1;
        int key = (int)(rid >> 1) & 3;
        const float* src = x + r_in * 512 + chunk * 32 + g * 8;
        f32x4 v0 = *(const f32x4*)(src);
        f32x4 v1 = *(const f32x4*)(src + 4);
        u16x8 w;
        #pragma unroll
        for (int j = 0; j < 4; ++j) { w[j] = f2bf(v0[j]); w[4 + j] = f2bf(v1[j]); }
        *(u16x8*)&xb[(size_t)rid * 512 + (chunk ^ cb) * 32 + ((g ^ key) << 3)] = w;
    }
}

#define LDF(off) __builtin_bit_cast(bf16x8, *(const u16x8*)&lds[(off)])
#define LDG(p)   __builtin_bit_cast(bf16x8, *(const u16x8*)(p))
#define MFMA16(d, a, b) d = __builtin_amdgcn_mfma_f32_16x16x32_bf16(a, b, d, 0, 0, 0)

// ---------------------------------------------------------------------------
// 256x256 GEMM: A in LDS (dbuf 2x32KB, r7-proven geometry: A(t+1) -> OTHER
// dbuf), B DIRECT from global into ping-pong registers breg[2][8] (weight
// panel is L2-hot). Removes B's LDS reads+writes: ~160KB/tile LDS vs 256KB.
// 512 thr = 8 waves (2 wm x 4 wn), BK=64. Per K-tile t (full unroll), phases:
//   ph0: dsA mf0-3 kk0; stageA(t+1,0)->other | SGB | breg[nxt][0-3]=Bkk0(t+1);
//        bar; lgkm0; MFMA mf0-3 kk0
//   ph1: dsA mf4-7 kk0; stageA(t+1,1)->other | SGB | breg[nxt][4-7]=Bkk1(t+1);
//        bar; lgkm0; MFMA mf4-7 kk0
//   ph2: dsA mf0-3 kk1; bar; lgkm0; MFMA mf0-3 kk1
//   ph3: dsA mf4-7 kk1; bar; lgkm0; MFMA mf4-7 kk1; vmcnt(4); bar
// vmem queue/tile = [sA2,b4,sA2,b4] (order pinned by sched_barrier):
// vmcnt(4) retires oldest 8 -> ALL stage writes landed; newest 4 breg loads
// stay in flight (register deps compiler-tracked -> auto-wait at t+1 ph2).
// WAR: stage->other dbuf, whose reads finished before tile t-1's end barrier.
// ---------------------------------------------------------------------------
template<int NCOL, bool OUT_BF16, bool A_PERM>
__global__ __launch_bounds__(512, 2) void gemm8_k(const u16* __restrict__ Ap,
                                                  const u16* __restrict__ Bp,
                                                  void* __restrict__ Dp, int gx) {
    __shared__ u16 lds[32768];   // A dbuf: 2 x 16384 u16 (32KB each)

    const int tid  = threadIdx.x;
    const int lane = tid & 63;
    const int wid  = tid >> 6;    // 0..7
    const int wm   = wid >> 2;    // 0..1
    const int wn   = wid & 3;     // 0..3
    const int fr   = lane & 15;
    const int g0   = lane >> 4;

    // XCD-aware bijective swizzle (grid % 8 == 0)
    const int nwg = gridDim.x;
    const int q8  = nwg >> 3;
    const int bid = blockIdx.x;
    const int wg  = (bid & 7) * q8 + (bid >> 3);
    const int bx  = wg % gx;
    const int by  = wg / gx;
    const long row0 = (long)by * 256;
    const int  col0 = bx * 256;

    // A frag LDS offsets (u16, rel. to dbuf base), kk=0; kk=1 = ^32
    int aoffs[8];
    #pragma unroll
    for (int mf = 0; mf < 8; ++mf) {
        int lr = wm * 128 + mf * 16 + fr;
        aoffs[mf] = lr * 64 + (((lr >> 3) & 1) << 5) + (((g0 ^ (lr >> 1)) & 3) << 3);
    }
    // B frag global base: lane reads WT[(col0+wn*64+nf*16+fr)][t*64 + kk*32 + g0*8]
    const u16* bbase = Bp + (size_t)(col0 + wn * 64 + fr) * 512 + g0 * 8;

    const int srow = lane >> 3;        // staging: row within 8-row wave slab
    const int scol = (lane & 7) * 8;   // u16 offset within 128B row window

    // precompute A staging physical row bases (4 rows per thread)
    long arow_phys[4];
    #pragma unroll
    for (int half = 0; half < 2; ++half)
        #pragma unroll
        for (int i = 0; i < 2; ++i) {
            int r = half * 128 + i * 64 + wid * 8 + srow;
            long grow = row0 + r;
            arow_phys[half * 2 + i] = A_PERM ? permute_row(grow) : grow;
        }

    // stage one half-tile (128 rows x 64 k) into dbuf (tt&1): 2 gload16
    auto stageA = [&](int tt, int half) {
        const int ab = (tt & 1) * 16384;
        #pragma unroll
        for (int i = 0; i < 2; ++i) {
            int r = half * 128 + i * 64 + wid * 8 + srow;
            const u16* g = Ap + arow_phys[half * 2 + i] * 512 + tt * 64 + scol;
            gload16(g, (void*)&lds[ab + r * 64]);
        }
    };

    f32x4 acc[8][4] = {};
    bf16x8 breg[2][8];   // [buf][0..3]=kk0 nf0-3, [4..7]=kk1 nf0-3

    // ---- prologue: stage A(0) (4 gload_lds), then B(0) (8 global loads) ----
    stageA(0, 0); stageA(0, 1);
    __builtin_amdgcn_sched_barrier(0);
    #pragma unroll
    for (int nf = 0; nf < 4; ++nf) {
        breg[0][nf]     = LDG(bbase + (size_t)nf * 8192);
        breg[0][4 + nf] = LDG(bbase + (size_t)nf * 8192 + 32);
    }
    asm volatile("s_waitcnt vmcnt(8)" ::: "memory");   // A(0) landed; B(0) in flight
    __builtin_amdgcn_sched_barrier(0);
    __builtin_amdgcn_s_barrier();

    #pragma unroll
    for (int t = 0; t < 8; ++t) {
        const int ab  = (t & 1) * 16384;
        const int cur = t & 1;
        const int nxt = (t + 1) & 1;
        bf16x8 af[4];
        // ================= phase 0: mf0-3 kk0 =================
        #pragma unroll
        for (int mf = 0; mf < 4; ++mf) af[mf] = LDF(ab + aoffs[mf]);
        if (t < 7) {
            stageA(t + 1, 0);                       // -> other dbuf
            __builtin_amdgcn_sched_barrier(0);      // pin: stages before breg loads
            #pragma unroll
            for (int nf = 0; nf < 4; ++nf)
                breg[nxt][nf] = LDG(bbase + (size_t)nf * 8192 + (t + 1) * 64);
        }
        __builtin_amdgcn_s_barrier();
        asm volatile("s_waitcnt lgkmcnt(0)" ::: "memory");
        __builtin_amdgcn_sched_barrier(0);
        __builtin_amdgcn_s_setprio(1);
        #pragma unroll
        for (int mf = 0; mf < 4; ++mf) {
            MFMA16(acc[mf][0], af[mf], breg[cur][0]);
            MFMA16(acc[mf][1], af[mf], breg[cur][1]);
            MFMA16(acc[mf][2], af[mf], breg[cur][2]);
            MFMA16(acc[mf][3], af[mf], breg[cur][3]);
        }
        __builtin_amdgcn_s_setprio(0);
        __builtin_amdgcn_s_barrier();
        // ================= phase 1: mf4-7 kk0 =================
        #pragma unroll
        for (int mf = 0; mf < 4; ++mf) af[mf] = LDF(ab + aoffs[4 + mf]);
        if (t < 7) {
            stageA(t + 1, 1);
            __builtin_amdgcn_sched_barrier(0);
            #pragma unroll
            for (int nf = 0; nf < 4; ++nf)
                breg[nxt][4 + nf] = LDG(bbase + (size_t)nf * 8192 + (t + 1) * 64 + 32);
        }
        __builtin_amdgcn_s_barrier();
        asm volatile("s_waitcnt lgkmcnt(0)" ::: "memory");
        __builtin_amdgcn_sched_barrier(0);
        __builtin_amdgcn_s_setprio(1);
        #pragma unroll
        for (int mf = 4; mf < 8; ++mf) {
            MFMA16(acc[mf][0], af[mf - 4], breg[cur][0]);
            MFMA16(acc[mf][1], af[mf - 4], breg[cur][1]);
            MFMA16(acc[mf][2], af[mf - 4], breg[cur][2]);
            MFMA16(acc[mf][3], af[mf - 4], breg[cur][3]);
        }
        __builtin_amdgcn_s_setprio(0);
        __builtin_amdgcn_s_barrier();
        // ================= phase 2: mf0-3 kk1 =================
        #pragma unroll
        for (int mf = 0; mf < 4; ++mf) af[mf] = LDF(ab + (aoffs[mf] ^ 32));
        __builtin_amdgcn_s_barrier();
        asm volatile("s_waitcnt lgkmcnt(0)" ::: "memory");
        __builtin_amdgcn_sched_barrier(0);
        __builtin_amdgcn_s_setprio(1);
        #pragma unroll
        for (int mf = 0; mf < 4; ++mf) {
            MFMA16(acc[mf][0], af[mf], breg[cur][4]);
            MFMA16(acc[mf][1], af[mf], breg[cur][5]);
            MFMA16(acc[mf][2], af[mf], breg[cur][6]);
            MFMA16(acc[mf][3], af[mf], breg[cur][7]);
        }
        __builtin_amdgcn_s_setprio(0);
        __builtin_amdgcn_s_barrier();
        // ================= phase 3: mf4-7 kk1 =================
        #pragma unroll
        for (int mf = 0; mf < 4; ++mf) af[mf] = LDF(ab + (aoffs[4 + mf] ^ 32));
        __builtin_amdgcn_s_barrier();
        asm volatile("s_waitcnt lgkmcnt(0)" ::: "memory");
        __builtin_amdgcn_sched_barrier(0);
        __builtin_amdgcn_s_setprio(1);
        #pragma unroll
        for (int mf = 4; mf < 8; ++mf) {
            MFMA16(acc[mf][0], af[mf - 4], breg[cur][4]);
            MFMA16(acc[mf][1], af[mf - 4], breg[cur][5]);
            MFMA16(acc[mf][2], af[mf - 4], breg[cur][6]);
            MFMA16(acc[mf][3], af[mf - 4], breg[cur][7]);
        }
        __builtin_amdgcn_s_setprio(0);
        if (t < 7) {
            // queue [sA2,b4,sA2,b4]: retire oldest 8 -> all A(t+1) stages landed
            asm volatile("s_waitcnt vmcnt(4)" ::: "memory");
        }
        __builtin_amdgcn_sched_barrier(0);
        __builtin_amdgcn_s_barrier();
    }

    // ---- epilogue: C row = (lane>>4)*4 + r, col = lane&15 (logical rows) ----
    #pragma unroll
    for (int mf = 0; mf < 8; ++mf) {
        #pragma unroll
        for (int nf = 0; nf < 4; ++nf) {
            #pragma unroll
            for (int r = 0; r < 4; ++r) {
                long grow = row0 + wm * 128 + mf * 16 + (lane >> 4) * 4 + r;
                int  gcol = col0 + wn * 64 + nf * 16 + fr;
                float v = acc[mf][nf][r];
                if constexpr (OUT_BF16) ((u16*)Dp)[grow * NCOL + gcol] = f2bf(v);
                else                    ((float*)Dp)[grow * NCOL + gcol] = v;
            }
        }
    }
}

// ---------------------------------------------------------------------------
// Banded temporal attention, LDS-staged via global_load_lds, 1 wave/block,
// NO barriers (wave-private LDS visibility via vmcnt(0)). Validated r11.
// Physical LDS slot p of row u holds LOGICAL chunk p ^ (u&7) (global-source
// pre-swizzle, LDS dest linear). qkv rows (b,s,t)-ordered; output rows
// stored PRE-SWIZZLED (A-side layout, s-based keys) for gemm3.
// ---------------------------------------------------------------------------
__global__ __launch_bounds__(64) void attn_k(const u16* __restrict__ qkv,
                                             u16* __restrict__ attn) {
    __shared__ u16 Kl[64 * 64];   // [u][slot] 128B rows, swizzled granules
    __shared__ u16 Vl[64 * 64];

    const int tid = threadIdx.x;
    const int bid = blockIdx.x;
    const int h = bid & (H_ - 1);
    const int s = (bid >> 3) & (S_ - 1);
    const int b = bid >> 13;

    const size_t base = ((size_t)((b << 10) | s) * 64) * 1536 + h * 64;

    // ---- stage K,V: 8 issues each; lane l covers (row it*8+(l>>3), slot l&7)
    {
        const int ur = tid >> 3;     // row-within-group
        const int cp = tid & 7;      // physical granule slot in LDS
        #pragma unroll
        for (int it = 0; it < 8; ++it) {
            int u = it * 8 + ur;
            int c = cp ^ (u & 7);    // logical chunk fetched into slot cp
            gload16(qkv + base + (size_t)u * 1536 + 512 + c * 8,
                    (void*)&Kl[it * 512]);
        }
        #pragma unroll
        for (int it = 0; it < 8; ++it) {
            int u = it * 8 + ur;
            int c = cp ^ (u & 7);
            gload16(qkv + base + (size_t)u * 1536 + 1024 + c * 8,
                    (void*)&Vl[it * 512]);
        }
    }

    // ---- Q row (direct, fp32 in regs) — overlaps with staging in flight ----
    float qf[64];
    const int t = tid;
    {
        const u16* qp = qkv + base + (size_t)t * 1536;
        #pragma unroll
        for (int c = 0; c < 8; ++c) {
            u16x8 v = *(const u16x8*)(qp + c * 8);
            #pragma unroll
            for (int j = 0; j < 8; ++j) qf[c * 8 + j] = bf2f(v[j]);
        }
    }
    asm volatile("s_waitcnt vmcnt(0)" ::: "memory");   // staging landed (1 wave)
    __builtin_amdgcn_sched_barrier(0);

    // ---- band scores + softmax ----
    float p[11];
    float m = -1e30f;
    #pragma unroll
    for (int i = 0; i < 11; ++i) {
        int u = t - WIN_ + i;
        if (u >= 0 && u < 64) {
            const int ubase = u * 64;
            const int key = u & 7;
            float dot = 0.f;
            #pragma unroll
            for (int c = 0; c < 8; ++c) {
                // slot c^key holds logical chunk c -> pair with qf[c*8+..]
                u16x8 kv = *(const u16x8*)&Kl[ubase + ((c ^ key) << 3)];
                #pragma unroll
                for (int j = 0; j < 8; ++j) dot += qf[c * 8 + j] * bf2f(kv[j]);
            }
            p[i] = dot * 0.125f;   // hd^-0.5
            m = fmaxf(m, p[i]);
        } else {
            p[i] = -1e30f;
        }
    }
    float sum = 0.f;
    #pragma unroll
    for (int i = 0; i < 11; ++i) {
        int u = t - WIN_ + i;
        float e = (u >= 0 && u < 64) ? __expf(p[i] - m) : 0.f;
        p[i] = e;
        sum += e;
    }
    const float inv = 1.f / sum;

    // ---- PV ----
    float o[64];
    #pragma unroll
    for (int d = 0; d < 64; ++d) o[d] = 0.f;
    #pragma unroll
    for (int i = 0; i < 11; ++i) {
        int u = t - WIN_ + i;
        if (u >= 0 && u < 64) {
            const int ubase = u * 64;
            const int key = u & 7;
            float pv = p[i] * inv;
            #pragma unroll
            for (int c = 0; c < 8; ++c) {
                u16x8 vv = *(const u16x8*)&Vl[ubase + ((c ^ key) << 3)];
                #pragma unroll
                for (int j = 0; j < 8; ++j) o[c * 8 + j] += pv * bf2f(vv[j]);
            }
        }
    }
    // ---- pre-swizzled store at physical row rid; keys from s ----
    size_t rowbase = ((size_t)((b << 10) | s) * 64 + t) * (size_t)C_;
    const int cb  = (s >> 3) & 1;
    const int key = (s >> 1) & 3;
    #pragma unroll
    for (int c = 0; c < 8; ++c) {
        u16x8 w;
        #pragma unroll
        for (int j = 0; j < 8; ++j) w[j] = f2bf(o[c * 8 + j]);
        int off = (((2 * h + (c >> 2)) ^ cb) << 5) + (((c & 3) ^ key) << 3);
        *(u16x8*)&attn[rowbase + off] = w;
    }
}

// ---------------------------------------------------------------------------
extern "C" void kernel_launch(void* const* d_in, const int* in_sizes, int n_in,
                              void* d_out, int out_size, void* d_ws, size_t ws_size,
                              hipStream_t stream) {
    const float* x    = (const float*)d_in[0];   // (B, N, C) fp32
    const float* Wqkv = (const float*)d_in[1];   // (512, 1536) fp32
    const float* Wout = (const float*)d_in[2];   // (512, 512) fp32
    float* out = (float*)d_out;

    const size_t xc_elems  = (size_t)M_ * C_;      // 67.1M (x_bf16 / attn alias)
    const size_t qkv_elems = (size_t)M_ * 1536;    // 201.3M
    if (ws_size < (xc_elems + qkv_elems) * sizeof(u16)) return;  // 537 MiB

    u16* xb       = (u16*)d_ws;              // [0, 134MB): x_bf16 (b,s,t)-rows
    u16* qkv      = xb + xc_elems;           // [134MB, 537MB), (b,s,t)-rows
    u16* attn_buf = xb;                      // alias: written after xb is dead
    u16* WqkvT    = (u16*)d_out;             // scratch in d_out (dead until gemm3)
    u16* WoutT    = qkv;                     // alias: written after qkv is dead

    // 1) weight + activation prep (weights linear bf16; x permuted+swizzled)
    prep_w<<<(1536 * 64) / 256, 256, 0, stream>>>(Wqkv, WqkvT, 1536);
    prep_x<<<8192, 256, 0, stream>>>(x, xb);

    // 2) qkv = x @ W_qkv  (A-LDS + B-direct GEMM, bf16 out)
    gemm8_k<1536, true, false><<<3072, 512, 0, stream>>>(xb, WqkvT, (void*)qkv, 6);

    // 3) banded temporal attention (LDS-staged, swizzled, barrier-free)
    attn_k<<<B_ * H_ * S_, 64, 0, stream>>>(qkv, attn_buf);

    // 4) WoutT into the now-dead qkv region
    prep_w<<<(512 * 64) / 256, 256, 0, stream>>>(Wout, WoutT, 512);

    // 5) out = attn @ W_out  (A-LDS + B-direct, fp32 out; A un-permuted rows)
    gemm8_k<512, false, true><<<1024, 512, 0, stream>>>(attn_buf, WoutT, (void*)out, 2);
}

// Round 14
// 623.667 us; speedup vs baseline: 1.2935x; 1.2935x over previous
//
#include <hip/hip_runtime.h>
#include <stdint.h>

// Problem constants (fixed instance from setup_inputs)
#define B_   2
#define T_   64
#define S_   1024
#define C_   512
#define H_   8
#define N_   (T_ * S_)      // 65536
#define M_   (B_ * N_)      // 131072
#define WIN_ 5

typedef unsigned short u16;
typedef __bf16 bf16;
typedef __bf16 bf16x8 __attribute__((ext_vector_type(8)));
typedef float  f32x4  __attribute__((ext_vector_type(4)));
typedef u16    u16x8  __attribute__((ext_vector_type(8)));

static __device__ __forceinline__ u16 f2bf(float f) {
    return __builtin_bit_cast(u16, (bf16)f);   // RNE
}
static __device__ __forceinline__ float bf2f(u16 u) {
    return __builtin_bit_cast(float, (uint32_t)u << 16);
}
// async global->LDS, 16B per lane; LDS dest is wave-uniform base + lane*16
static __device__ __forceinline__ void gload16(const void* g, void* l) {
    __builtin_amdgcn_global_load_lds(
        (const __attribute__((address_space(1))) void*)g,
        (__attribute__((address_space(3))) void*)l, 16, 0, 0);
}
// row permutation: logical (b,t,s) flat row -> physical (b,s,t) flat row
static __device__ __forceinline__ long permute_row(long grow) {
    int b = (int)(grow >> 16);
    int t = (int)(grow >> 10) & 63;
    int s = (int)grow & 1023;
    return ((long)((b << 10) | s)) * 64 + t;
}

// Pre-swizzle layout (every bf16 [row][512] operand, row = PHYSICAL row):
// logical (chunk c in [0,16), granule g in [0,4), elem j) stored at
// r*512 + (c ^ ((r>>3)&1))*32 + ((g ^ ((r>>1)&3))<<3) + j, keys from the
// row index mod 256 (= GEMM tile-local LDS row). 0 bank conflicts measured.

// ---------------------------------------------------------------------------
// Weight prep: W [512][NCOL] fp32 -> WT [NCOL][512] bf16, pre-swizzled.
// ---------------------------------------------------------------------------
__global__ __launch_bounds__(256) void prep_w(const float* __restrict__ W,
                                              u16* __restrict__ WT, int NCOL) {
    int id = blockIdx.x * 256 + threadIdx.x;
    int n  = id % NCOL;
    int gi = id / NCOL;
    int chunk = gi >> 2;
    int g     = gi & 3;
    int k0 = chunk * 32 + g * 8;
    int cs = chunk ^ ((n >> 3) & 1);
    int gs = g ^ ((n >> 1) & 3);
    u16x8 w;
    #pragma unroll
    for (int j = 0; j < 8; ++j) w[j] = f2bf(W[(size_t)(k0 + j) * NCOL + n]);
    *(u16x8*)&WT[(size_t)n * 512 + cs * 32 + gs * 8] = w;
}

// ---------------------------------------------------------------------------
// x prep: x [M][512] fp32 (rows (b,t,s)) -> xb bf16 rows PERMUTED to (b,s,t),
// pre-swizzled with keys from the permuted row index.
// ---------------------------------------------------------------------------
__global__ __launch_bounds__(256) void prep_x(const float* __restrict__ x,
                                              u16* __restrict__ xb) {
    const size_t total = (size_t)M_ * 64;   // 16B granules
    for (size_t id = (size_t)blockIdx.x * 256 + threadIdx.x; id < total;
         id += (size_t)gridDim.x * 256) {
        long r_in = (long)(id >> 6);
        int  gi   = (int)(id & 63);
        int chunk = gi >> 2;
        int g     = gi & 3;
        long rid  = permute_row(r_in);
        int cb  = (int)(rid >> 3) & 1;
        int key = (int)(rid >> 1) & 3;
        const float* src = x + r_in * 512 + chunk * 32 + g * 8;
        f32x4 v0 = *(const f32x4*)(src);
        f32x4 v1 = *(const f32x4*)(src + 4);
        u16x8 w;
        #pragma unroll
        for (int j = 0; j < 4; ++j) { w[j] = f2bf(v0[j]); w[4 + j] = f2bf(v1[j]); }
        *(u16x8*)&xb[(size_t)rid * 512 + (chunk ^ cb) * 32 + ((g ^ key) << 3)] = w;
    }
}

#define LDF(off) __builtin_bit_cast(bf16x8, *(const u16x8*)&lds[(off)])
#define MFMA16(d, a, b) d = __builtin_amdgcn_mfma_f32_16x16x32_bf16(a, b, d, 0, 0, 0)

// ---------------------------------------------------------------------------
// 256x256 8-phase pipelined GEMM = r11 structure with DEEPER A-PREFETCH:
// A triple-buffered (3 x 32KB), B double-buffered (2 x 32KB) -> 160KB LDS.
// Stage A(t+2) at ph0/ph1 (8-phase prefetch window ~2000cy, covers HBM);
// stage B(t+2) at ph2/ph3 (r11-validated same-buf pattern, B is L2-hot).
// Tile-end wait = vmcnt(8): retires tile t-1's stages, keeps ALL of tile t's
// 8 stage-issues in flight across the barrier (T4: never drain mid-loop).
// WAR: A(t+2)%3 buffer's reads completed at tile t-1 (before its end bar);
// B(t+2)%2 = current B buf, all B reads done by ph1's lgkm+barrier.
// 512 thr = 8 waves (2 wm x 4 wn), BK=64, balanced {8,8,4,4} phase reads.
// ---------------------------------------------------------------------------
template<int NCOL, bool OUT_BF16, bool A_PERM>
__global__ __launch_bounds__(512, 2) void gemm8_k(const u16* __restrict__ Ap,
                                                  const u16* __restrict__ Bp,
                                                  void* __restrict__ Dp, int gx) {
    __shared__ u16 lds[81920];   // A0|A1|A2 @ {0,16384,32768}, B0|B1 @ {49152,65536}

    const int tid  = threadIdx.x;
    const int lane = tid & 63;
    const int wid  = tid >> 6;    // 0..7
    const int wm   = wid >> 2;    // 0..1
    const int wn   = wid & 3;     // 0..3
    const int fr   = lane & 15;
    const int g0   = lane >> 4;

    // XCD-aware bijective swizzle (grid % 8 == 0)
    const int nwg = gridDim.x;
    const int q8  = nwg >> 3;
    const int bid = blockIdx.x;
    const int wg  = (bid & 7) * q8 + (bid >> 3);
    const int bx  = wg % gx;
    const int by  = wg / gx;
    const long row0 = (long)by * 256;
    const int  col0 = bx * 256;

    // per-frag LDS offsets (u16, rel. to A/B buffer base), kk=0; kk=1 = ^32
    int aoffs[8], boffs[4];
    #pragma unroll
    for (int mf = 0; mf < 8; ++mf) {
        int lr = wm * 128 + mf * 16 + fr;
        aoffs[mf] = lr * 64 + (((lr >> 3) & 1) << 5) + (((g0 ^ (lr >> 1)) & 3) << 3);
    }
    #pragma unroll
    for (int nf = 0; nf < 4; ++nf) {
        int lc = wn * 64 + nf * 16 + fr;
        boffs[nf] = lc * 64 + (((lc >> 3) & 1) << 5) + (((g0 ^ (lc >> 1)) & 3) << 3);
    }

    const int srow = lane >> 3;        // staging: row within 8-row wave slab
    const int scol = (lane & 7) * 8;   // u16 offset within 128B row window

    // precompute A staging physical row bases (4 rows per thread)
    long arow_phys[4];
    #pragma unroll
    for (int half = 0; half < 2; ++half)
        #pragma unroll
        for (int i = 0; i < 2; ++i) {
            int r = half * 128 + i * 64 + wid * 8 + srow;
            long grow = row0 + r;
            arow_phys[half * 2 + i] = A_PERM ? permute_row(grow) : grow;
        }

    // stage one half-tile (128 rows x 64 k): 2 gload16 per thread
    auto stageA = [&](int tt, int half) {
        const int ab = (tt % 3) * 16384;
        #pragma unroll
        for (int i = 0; i < 2; ++i) {
            int r = half * 128 + i * 64 + wid * 8 + srow;
            const u16* g = Ap + arow_phys[half * 2 + i] * 512 + tt * 64 + scol;
            gload16(g, (void*)&lds[ab + r * 64]);
        }
    };
    auto stageB = [&](int tt, int half) {
        const int bb = 49152 + (tt & 1) * 16384;
        #pragma unroll
        for (int i = 0; i < 2; ++i) {
            int r = half * 128 + i * 64 + wid * 8 + srow;
            const u16* g = Bp + (size_t)(col0 + r) * 512 + tt * 64 + scol;
            gload16(g, (void*)&lds[bb + r * 64]);
        }
    };

    f32x4 acc[8][4] = {};

    // ---- prologue: order [A0,B0,A1,B1] (16 issues); vmcnt(8) -> A0,B0 landed ----
    stageA(0, 0); stageA(0, 1); stageB(0, 0); stageB(0, 1);
    stageA(1, 0); stageA(1, 1); stageB(1, 0); stageB(1, 1);
    asm volatile("s_waitcnt vmcnt(8)" ::: "memory");
    __builtin_amdgcn_sched_barrier(0);
    __builtin_amdgcn_s_barrier();

    #pragma unroll
    for (int t = 0; t < 8; ++t) {
        const int ab = (t % 3) * 16384;
        const int bb = 49152 + (t & 1) * 16384;
        bf16x8 af0[8], af1[8], bf0[4], bf1[4];
        // ================= phase 0 =================
        #pragma unroll
        for (int mf = 0; mf < 4; ++mf) af0[mf] = LDF(ab + aoffs[mf]);
        #pragma unroll
        for (int nf = 0; nf < 4; ++nf) bf0[nf] = LDF(bb + boffs[nf]);
        if (t <= 5) stageA(t + 2, 0);
        __builtin_amdgcn_s_barrier();
        asm volatile("s_waitcnt lgkmcnt(0)" ::: "memory");
        __builtin_amdgcn_sched_barrier(0);
        __builtin_amdgcn_s_setprio(1);
        #pragma unroll
        for (int mf = 0; mf < 4; ++mf) {
            MFMA16(acc[mf][0], af0[mf], bf0[0]);
            MFMA16(acc[mf][1], af0[mf], bf0[1]);
            MFMA16(acc[mf][2], af0[mf], bf0[2]);
            MFMA16(acc[mf][3], af0[mf], bf0[3]);
        }
        __builtin_amdgcn_s_setprio(0);
        __builtin_amdgcn_s_barrier();
        // ================= phase 1 =================
        #pragma unroll
        for (int mf = 4; mf < 8; ++mf) af0[mf] = LDF(ab + aoffs[mf]);
        #pragma unroll
        for (int nf = 0; nf < 4; ++nf) bf1[nf] = LDF(bb + (boffs[nf] ^ 32));
        if (t <= 5) stageA(t + 2, 1);
        __builtin_amdgcn_s_barrier();
        asm volatile("s_waitcnt lgkmcnt(0)" ::: "memory");
        __builtin_amdgcn_sched_barrier(0);
        __builtin_amdgcn_s_setprio(1);
        #pragma unroll
        for (int mf = 4; mf < 8; ++mf) {
            MFMA16(acc[mf][0], af0[mf], bf0[0]);
            MFMA16(acc[mf][1], af0[mf], bf0[1]);
            MFMA16(acc[mf][2], af0[mf], bf0[2]);
            MFMA16(acc[mf][3], af0[mf], bf0[3]);
        }
        __builtin_amdgcn_s_setprio(0);
        __builtin_amdgcn_s_barrier();
        // ================= phase 2 =================
        #pragma unroll
        for (int mf = 0; mf < 4; ++mf) af1[mf] = LDF(ab + (aoffs[mf] ^ 32));
        if (t <= 5) stageB(t + 2, 0);
        __builtin_amdgcn_s_barrier();
        asm volatile("s_waitcnt lgkmcnt(0)" ::: "memory");
        __builtin_amdgcn_sched_barrier(0);
        __builtin_amdgcn_s_setprio(1);
        #pragma unroll
        for (int mf = 0; mf < 4; ++mf) {
            MFMA16(acc[mf][0], af1[mf], bf1[0]);
            MFMA16(acc[mf][1], af1[mf], bf1[1]);
            MFMA16(acc[mf][2], af1[mf], bf1[2]);
            MFMA16(acc[mf][3], af1[mf], bf1[3]);
        }
        __builtin_amdgcn_s_setprio(0);
        __builtin_amdgcn_s_barrier();
        // ================= phase 3 =================
        #pragma unroll
        for (int mf = 4; mf < 8; ++mf) af1[mf] = LDF(ab + (aoffs[mf] ^ 32));
        if (t <= 5) stageB(t + 2, 1);
        __builtin_amdgcn_s_barrier();
        asm volatile("s_waitcnt lgkmcnt(0)" ::: "memory");
        __builtin_amdgcn_sched_barrier(0);
        __builtin_amdgcn_s_setprio(1);
        #pragma unroll
        for (int mf = 4; mf < 8; ++mf) {
            MFMA16(acc[mf][0], af1[mf], bf1[0]);
            MFMA16(acc[mf][1], af1[mf], bf1[1]);
            MFMA16(acc[mf][2], af1[mf], bf1[2]);
            MFMA16(acc[mf][3], af1[mf], bf1[3]);
        }
        __builtin_amdgcn_s_setprio(0);
        if (t <= 5) {
            // in flight: tile t's 8 stages; tile t+1's (issued t-1) retire here
            asm volatile("s_waitcnt vmcnt(8)" ::: "memory");
        } else if (t == 6) {
            asm volatile("s_waitcnt vmcnt(0)" ::: "memory");   // A7,B7 landed
        }
        __builtin_amdgcn_sched_barrier(0);
        __builtin_amdgcn_s_barrier();
    }

    // ---- epilogue: C row = (lane>>4)*4 + r, col = lane&15 (logical rows) ----
    #pragma unroll
    for (int mf = 0; mf < 8; ++mf) {
        #pragma unroll
        for (int nf = 0; nf < 4; ++nf) {
            #pragma unroll
            for (int r = 0; r < 4; ++r) {
                long grow = row0 + wm * 128 + mf * 16 + (lane >> 4) * 4 + r;
                int  gcol = col0 + wn * 64 + nf * 16 + fr;
                float v = acc[mf][nf][r];
                if constexpr (OUT_BF16) ((u16*)Dp)[grow * NCOL + gcol] = f2bf(v);
                else                    ((float*)Dp)[grow * NCOL + gcol] = v;
            }
        }
    }
}

// ---------------------------------------------------------------------------
// Banded temporal attention, LDS-staged via global_load_lds, 1 wave/block,
// NO barriers (wave-private LDS visibility via vmcnt(0)). Validated r11.
// Physical LDS slot p of row u holds LOGICAL chunk p ^ (u&7) (global-source
// pre-swizzle, LDS dest linear). qkv rows (b,s,t)-ordered; output rows
// stored PRE-SWIZZLED (A-side layout, s-based keys) for gemm3.
// ---------------------------------------------------------------------------
__global__ __launch_bounds__(64) void attn_k(const u16* __restrict__ qkv,
                                             u16* __restrict__ attn) {
    __shared__ u16 Kl[64 * 64];   // [u][slot] 128B rows, swizzled granules
    __shared__ u16 Vl[64 * 64];

    const int tid = threadIdx.x;
    const int bid = blockIdx.x;
    const int h = bid & (H_ - 1);
    const int s = (bid >> 3) & (S_ - 1);
    const int b = bid >> 13;

    const size_t base = ((size_t)((b << 10) | s) * 64) * 1536 + h * 64;

    // ---- stage K,V: 8 issues each; lane l covers (row it*8+(l>>3), slot l&7)
    {
        const int ur = tid >> 3;     // row-within-group
        const int cp = tid & 7;      // physical granule slot in LDS
        #pragma unroll
        for (int it = 0; it < 8; ++it) {
            int u = it * 8 + ur;
            int c = cp ^ (u & 7);    // logical chunk fetched into slot cp
            gload16(qkv + base + (size_t)u * 1536 + 512 + c * 8,
                    (void*)&Kl[it * 512]);
        }
        #pragma unroll
        for (int it = 0; it < 8; ++it) {
            int u = it * 8 + ur;
            int c = cp ^ (u & 7);
            gload16(qkv + base + (size_t)u * 1536 + 1024 + c * 8,
                    (void*)&Vl[it * 512]);
        }
    }

    // ---- Q row (direct, fp32 in regs) — overlaps with staging in flight ----
    float qf[64];
    const int t = tid;
    {
        const u16* qp = qkv + base + (size_t)t * 1536;
        #pragma unroll
        for (int c = 0; c < 8; ++c) {
            u16x8 v = *(const u16x8*)(qp + c * 8);
            #pragma unroll
            for (int j = 0; j < 8; ++j) qf[c * 8 + j] = bf2f(v[j]);
        }
    }
    asm volatile("s_waitcnt vmcnt(0)" ::: "memory");   // staging landed (1 wave)
    __builtin_amdgcn_sched_barrier(0);

    // ---- band scores + softmax ----
    float p[11];
    float m = -1e30f;
    #pragma unroll
    for (int i = 0; i < 11; ++i) {
        int u = t - WIN_ + i;
        if (u >= 0 && u < 64) {
            const int ubase = u * 64;
            const int key = u & 7;
            float dot = 0.f;
            #pragma unroll
            for (int c = 0; c < 8; ++c) {
                // slot c^key holds logical chunk c -> pair with qf[c*8+..]
                u16x8 kv = *(const u16x8*)&Kl[ubase + ((c ^ key) << 3)];
                #pragma unroll
                for (int j = 0; j < 8; ++j) dot += qf[c * 8 + j] * bf2f(kv[j]);
            }
            p[i] = dot * 0.125f;   // hd^-0.5
            m = fmaxf(m, p[i]);
        } else {
            p[i] = -1e30f;
        }
    }
    float sum = 0.f;
    #pragma unroll
    for (int i = 0; i < 11; ++i) {
        int u = t - WIN_ + i;
        float e = (u >= 0 && u < 64) ? __expf(p[i] - m) : 0.f;
        p[i] = e;
        sum += e;
    }
    const float inv = 1.f / sum;

    // ---- PV ----
    float o[64];
    #pragma unroll
    for (int d = 0; d < 64; ++d) o[d] = 0.f;
    #pragma unroll
    for (int i = 0; i < 11; ++i) {
        int u = t - WIN_ + i;
        if (u >= 0 && u < 64) {
            const int ubase = u * 64;
            const int key = u & 7;
            float pv = p[i] * inv;
            #pragma unroll
            for (int c = 0; c < 8; ++c) {
                u16x8 vv = *(const u16x8*)&Vl[ubase + ((c ^ key) << 3)];
                #pragma unroll
                for (int j = 0; j < 8; ++j) o[c * 8 + j] += pv * bf2f(vv[j]);
            }
        }
    }
    // ---- pre-swizzled store at physical row rid; keys from s ----
    size_t rowbase = ((size_t)((b << 10) | s) * 64 + t) * (size_t)C_;
    const int cb  = (s >> 3) & 1;
    const int key = (s >> 1) & 3;
    #pragma unroll
    for (int c = 0; c < 8; ++c) {
        u16x8 w;
        #pragma unroll
        for (int j = 0; j < 8; ++j) w[j] = f2bf(o[c * 8 + j]);
        int off = (((2 * h + (c >> 2)) ^ cb) << 5) + (((c & 3) ^ key) << 3);
        *(u16x8*)&attn[rowbase + off] = w;
    }
}

// ---------------------------------------------------------------------------
extern "C" void kernel_launch(void* const* d_in, const int* in_sizes, int n_in,
                              void* d_out, int out_size, void* d_ws, size_t ws_size,
                              hipStream_t stream) {
    const float* x    = (const float*)d_in[0];   // (B, N, C) fp32
    const float* Wqkv = (const float*)d_in[1];   // (512, 1536) fp32
    const float* Wout = (const float*)d_in[2];   // (512, 512) fp32
    float* out = (float*)d_out;

    const size_t xc_elems  = (size_t)M_ * C_;      // 67.1M (x_bf16 / attn alias)
    const size_t qkv_elems = (size_t)M_ * 1536;    // 201.3M
    if (ws_size < (xc_elems + qkv_elems) * sizeof(u16)) return;  // 537 MiB

    u16* xb       = (u16*)d_ws;              // [0, 134MB): x_bf16 (b,s,t)-rows
    u16* qkv      = xb + xc_elems;           // [134MB, 537MB), (b,s,t)-rows
    u16* attn_buf = xb;                      // alias: written after xb is dead
    u16* WqkvT    = (u16*)d_out;             // scratch in d_out (dead until gemm3)
    u16* WoutT    = qkv;                     // alias: written after qkv is dead

    // 1) weight + activation prep (bf16, pre-swizzled; x rows permuted)
    prep_w<<<(1536 * 64) / 256, 256, 0, stream>>>(Wqkv, WqkvT, 1536);
    prep_x<<<8192, 256, 0, stream>>>(x, xb);

    // 2) qkv = x @ W_qkv  (256^2 8-phase, A-triple-buffer deep prefetch)
    gemm8_k<1536, true, false><<<3072, 512, 0, stream>>>(xb, WqkvT, (void*)qkv, 6);

    // 3) banded temporal attention (LDS-staged, swizzled, barrier-free)
    attn_k<<<B_ * H_ * S_, 64, 0, stream>>>(qkv, attn_buf);

    // 4) WoutT into the now-dead qkv region
    prep_w<<<(512 * 64) / 256, 256, 0, stream>>>(Wout, WoutT, 512);

    // 5) out = attn @ W_out  (same GEMM; A un-permuted via per-lane addresses)
    gemm8_k<512, false, true><<<1024, 512, 0, stream>>>(attn_buf, WoutT, (void*)out, 2);
}

// Round 15
// 609.981 us; speedup vs baseline: 1.3225x; 1.0224x over previous
//
#include <hip/hip_runtime.h>
#include <stdint.h>

// Problem constants (fixed instance from setup_inputs)
#define B_   2
#define T_   64
#define S_   1024
#define C_   512
#define H_   8
#define N_   (T_ * S_)      // 65536
#define M_   (B_ * N_)      // 131072
#define WIN_ 5

typedef unsigned short u16;
typedef __bf16 bf16;
typedef __bf16 bf16x8 __attribute__((ext_vector_type(8)));
typedef float  f32x4  __attribute__((ext_vector_type(4)));
typedef u16    u16x8  __attribute__((ext_vector_type(8)));

static __device__ __forceinline__ u16 f2bf(float f) {
    return __builtin_bit_cast(u16, (bf16)f);   // RNE
}
static __device__ __forceinline__ float bf2f(u16 u) {
    return __builtin_bit_cast(float, (uint32_t)u << 16);
}
// async global->LDS, 16B per lane; LDS dest is wave-uniform base + lane*16
static __device__ __forceinline__ void gload16(const void* g, void* l) {
    __builtin_amdgcn_global_load_lds(
        (const __attribute__((address_space(1))) void*)g,
        (__attribute__((address_space(3))) void*)l, 16, 0, 0);
}
// row permutation: logical (b,t,s) flat row -> physical (b,s,t) flat row
static __device__ __forceinline__ long permute_row(long grow) {
    int b = (int)(grow >> 16);
    int t = (int)(grow >> 10) & 63;
    int s = (int)grow & 1023;
    return ((long)((b << 10) | s)) * 64 + t;
}

// Pre-swizzle layout (every bf16 [row][512] operand, row = PHYSICAL row):
// logical (chunk c in [0,16), granule g in [0,4), elem j) stored at
// r*512 + (c ^ ((r>>3)&1))*32 + ((g ^ ((r>>1)&3))<<3) + j, keys from the
// row index mod 256 (= GEMM tile-local LDS row). 0 bank conflicts measured.

// ---------------------------------------------------------------------------
// Weight prep: W [512][NCOL] fp32 -> WT [NCOL][512] bf16, pre-swizzled.
// ---------------------------------------------------------------------------
__global__ __launch_bounds__(256) void prep_w(const float* __restrict__ W,
                                              u16* __restrict__ WT, int NCOL) {
    int id = blockIdx.x * 256 + threadIdx.x;
    int n  = id % NCOL;
    int gi = id / NCOL;
    int chunk = gi >> 2;
    int g     = gi & 3;
    int k0 = chunk * 32 + g * 8;
    int cs = chunk ^ ((n >> 3) & 1);
    int gs = g ^ ((n >> 1) & 3);
    u16x8 w;
    #pragma unroll
    for (int j = 0; j < 8; ++j) w[j] = f2bf(W[(size_t)(k0 + j) * NCOL + n]);
    *(u16x8*)&WT[(size_t)n * 512 + cs * 32 + gs * 8] = w;
}

// ---------------------------------------------------------------------------
// x prep: x [M][512] fp32 (rows (b,t,s)) -> xb bf16 rows PERMUTED to (b,s,t),
// pre-swizzled with keys from the permuted row index.
// ---------------------------------------------------------------------------
__global__ __launch_bounds__(256) void prep_x(const float* __restrict__ x,
                                              u16* __restrict__ xb) {
    const size_t total = (size_t)M_ * 64;   // 16B granules
    for (size_t id = (size_t)blockIdx.x * 256 + threadIdx.x; id < total;
         id += (size_t)gridDim.x * 256) {
        long r_in = (long)(id >> 6);
        int  gi   = (int)(id & 63);
        int chunk = gi >> 2;
        int g     = gi & 3;
        long rid  = permute_row(r_in);
        int cb  = (int)(rid >> 3) & 1;
        int key = (int)(rid >> 1) & 3;
        const float* src = x + r_in * 512 + chunk * 32 + g * 8;
        f32x4 v0 = *(const f32x4*)(src);
        f32x4 v1 = *(const f32x4*)(src + 4);
        u16x8 w;
        #pragma unroll
        for (int j = 0; j < 4; ++j) { w[j] = f2bf(v0[j]); w[4 + j] = f2bf(v1[j]); }
        *(u16x8*)&xb[(size_t)rid * 512 + (chunk ^ cb) * 32 + ((g ^ key) << 3)] = w;
    }
}

#define LDF(off) __builtin_bit_cast(bf16x8, *(const u16x8*)&lds[(off)])
#define MFMA16(d, a, b) d = __builtin_amdgcn_mfma_f32_16x16x32_bf16(a, b, d, 0, 0, 0)

// ---------------------------------------------------------------------------
// 256x256 8-phase pipelined GEMM (r11-validated structure, best measured:
// 237us / 870 TF on gemm1). A rows: physical = A_PERM ? permute_row : id;
// B(transposed) [NCOL][512]; both pre-swizzled bf16.
// 512 thr = 8 waves (2 wm x 4 wn), BK=64, 2 K-tile dbuf (128 KiB LDS).
// Per K-tile t, 4 phases {reads | stage half-tile | barrier | lgkmcnt(0) |
// 16 MFMA (setprio) | barrier}; balanced {8,8,4,4} phase reads:
//   ph0: af0_lo(4)+bf0(4); stage A(t+1,0); MFMA mf0-3 kk0
//   ph1: af0_hi(4)+bf1(4); stage A(t+1,1); MFMA mf4-7 kk0
//   ph2: af1_lo(4);        stage B(t+2,0); MFMA mf0-3 kk1
//   ph3: af1_hi(4);        stage B(t+2,1); MFMA mf4-7 kk1; vmcnt(4)
// WAR: A(t+1)->other dbuf (its reads drained by t-1 ph3 lgkm+barrier);
// B(t+2)->this dbuf's B (all B reads done by ph1 lgkm+barrier).
// vmcnt(4) at tile end keeps B(t+2) in flight; vmcnt(0) only at t=6.
// ---------------------------------------------------------------------------
template<int NCOL, bool OUT_BF16, bool A_PERM>
__global__ __launch_bounds__(512, 2) void gemm8_k(const u16* __restrict__ Ap,
                                                  const u16* __restrict__ Bp,
                                                  void* __restrict__ Dp, int gx) {
    __shared__ u16 lds[65536];   // dbuf0{A,B} | dbuf1{A,B}, 16384 u16 each

    const int tid  = threadIdx.x;
    const int lane = tid & 63;
    const int wid  = tid >> 6;    // 0..7
    const int wm   = wid >> 2;    // 0..1
    const int wn   = wid & 3;     // 0..3
    const int fr   = lane & 15;
    const int g0   = lane >> 4;

    // XCD-aware bijective swizzle (grid % 8 == 0)
    const int nwg = gridDim.x;
    const int q8  = nwg >> 3;
    const int bid = blockIdx.x;
    const int wg  = (bid & 7) * q8 + (bid >> 3);
    const int bx  = wg % gx;
    const int by  = wg / gx;
    const long row0 = (long)by * 256;
    const int  col0 = bx * 256;

    // per-frag LDS offsets (u16, rel. to A/B region base), kk=0; kk=1 = ^32
    int aoffs[8], boffs[4];
    #pragma unroll
    for (int mf = 0; mf < 8; ++mf) {
        int lr = wm * 128 + mf * 16 + fr;
        aoffs[mf] = lr * 64 + (((lr >> 3) & 1) << 5) + (((g0 ^ (lr >> 1)) & 3) << 3);
    }
    #pragma unroll
    for (int nf = 0; nf < 4; ++nf) {
        int lc = wn * 64 + nf * 16 + fr;
        boffs[nf] = lc * 64 + (((lc >> 3) & 1) << 5) + (((g0 ^ (lc >> 1)) & 3) << 3);
    }

    const int srow = lane >> 3;        // staging: row within 8-row wave slab
    const int scol = (lane & 7) * 8;   // u16 offset within 128B row window

    // precompute A staging physical row bases (4 rows per thread)
    long arow_phys[4];
    #pragma unroll
    for (int half = 0; half < 2; ++half)
        #pragma unroll
        for (int i = 0; i < 2; ++i) {
            int r = half * 128 + i * 64 + wid * 8 + srow;
            long grow = row0 + r;
            arow_phys[half * 2 + i] = A_PERM ? permute_row(grow) : grow;
        }

    // stage one half-tile (128 rows x 64 k): 2 gload16 per thread
    auto stageA = [&](int tt, int half) {
        const int ab = (tt & 1) * 32768;
        #pragma unroll
        for (int i = 0; i < 2; ++i) {
            int r = half * 128 + i * 64 + wid * 8 + srow;
            const u16* g = Ap + arow_phys[half * 2 + i] * 512 + tt * 64 + scol;
            gload16(g, (void*)&lds[ab + r * 64]);
        }
    };
    auto stageB = [&](int tt, int half) {
        const int ab = (tt & 1) * 32768;
        #pragma unroll
        for (int i = 0; i < 2; ++i) {
            int r = half * 128 + i * 64 + wid * 8 + srow;
            const u16* g = Bp + (size_t)(col0 + r) * 512 + tt * 64 + scol;
            gload16(g, (void*)&lds[ab + 16384 + r * 64]);
        }
    };

    f32x4 acc[8][4] = {};

    // ---- prologue: tile0 full + tile1 B (12 loads); keep B(t1) in flight ----
    stageA(0, 0); stageA(0, 1); stageB(0, 0); stageB(0, 1);
    stageB(1, 0); stageB(1, 1);
    asm volatile("s_waitcnt vmcnt(4)" ::: "memory");
    __builtin_amdgcn_sched_barrier(0);
    __builtin_amdgcn_s_barrier();

    #pragma unroll
    for (int t = 0; t < 8; ++t) {
        const int ab = (t & 1) * 32768;
        bf16x8 af0[8], af1[8], bf0[4], bf1[4];
        // ================= phase 0 =================
        #pragma unroll
        for (int mf = 0; mf < 4; ++mf) af0[mf] = LDF(ab + aoffs[mf]);
        #pragma unroll
        for (int nf = 0; nf < 4; ++nf) bf0[nf] = LDF(ab + 16384 + boffs[nf]);
        if (t <= 6) stageA(t + 1, 0);
        __builtin_amdgcn_s_barrier();
        asm volatile("s_waitcnt lgkmcnt(0)" ::: "memory");
        __builtin_amdgcn_sched_barrier(0);
        __builtin_amdgcn_s_setprio(1);
        #pragma unroll
        for (int mf = 0; mf < 4; ++mf) {
            MFMA16(acc[mf][0], af0[mf], bf0[0]);
            MFMA16(acc[mf][1], af0[mf], bf0[1]);
            MFMA16(acc[mf][2], af0[mf], bf0[2]);
            MFMA16(acc[mf][3], af0[mf], bf0[3]);
        }
        __builtin_amdgcn_s_setprio(0);
        __builtin_amdgcn_s_barrier();
        // ================= phase 1 =================
        #pragma unroll
        for (int mf = 4; mf < 8; ++mf) af0[mf] = LDF(ab + aoffs[mf]);
        #pragma unroll
        for (int nf = 0; nf < 4; ++nf) bf1[nf] = LDF(ab + 16384 + (boffs[nf] ^ 32));
        if (t <= 6) stageA(t + 1, 1);
        __builtin_amdgcn_s_barrier();
        asm volatile("s_waitcnt lgkmcnt(0)" ::: "memory");
        __builtin_amdgcn_sched_barrier(0);
        __builtin_amdgcn_s_setprio(1);
        #pragma unroll
        for (int mf = 4; mf < 8; ++mf) {
            MFMA16(acc[mf][0], af0[mf], bf0[0]);
            MFMA16(acc[mf][1], af0[mf], bf0[1]);
            MFMA16(acc[mf][2], af0[mf], bf0[2]);
            MFMA16(acc[mf][3], af0[mf], bf0[3]);
        }
        __builtin_amdgcn_s_setprio(0);
        __builtin_amdgcn_s_barrier();
        // ================= phase 2 =================
        #pragma unroll
        for (int mf = 0; mf < 4; ++mf) af1[mf] = LDF(ab + (aoffs[mf] ^ 32));
        if (t <= 5) stageB(t + 2, 0);
        __builtin_amdgcn_s_barrier();
        asm volatile("s_waitcnt lgkmcnt(0)" ::: "memory");
        __builtin_amdgcn_sched_barrier(0);
        __builtin_amdgcn_s_setprio(1);
        #pragma unroll
        for (int mf = 0; mf < 4; ++mf) {
            MFMA16(acc[mf][0], af1[mf], bf1[0]);
            MFMA16(acc[mf][1], af1[mf], bf1[1]);
            MFMA16(acc[mf][2], af1[mf], bf1[2]);
            MFMA16(acc[mf][3], af1[mf], bf1[3]);
        }
        __builtin_amdgcn_s_setprio(0);
        __builtin_amdgcn_s_barrier();
        // ================= phase 3 =================
        #pragma unroll
        for (int mf = 4; mf < 8; ++mf) af1[mf] = LDF(ab + (aoffs[mf] ^ 32));
        if (t <= 5) stageB(t + 2, 1);
        __builtin_amdgcn_s_barrier();
        asm volatile("s_waitcnt lgkmcnt(0)" ::: "memory");
        __builtin_amdgcn_sched_barrier(0);
        __builtin_amdgcn_s_setprio(1);
        #pragma unroll
        for (int mf = 4; mf < 8; ++mf) {
            MFMA16(acc[mf][0], af1[mf], bf1[0]);
            MFMA16(acc[mf][1], af1[mf], bf1[1]);
            MFMA16(acc[mf][2], af1[mf], bf1[2]);
            MFMA16(acc[mf][3], af1[mf], bf1[3]);
        }
        __builtin_amdgcn_s_setprio(0);
        if (t <= 5) {
            asm volatile("s_waitcnt vmcnt(4)" ::: "memory");   // t+1 landed, B(t+2) in flight
        } else if (t == 6) {
            asm volatile("s_waitcnt vmcnt(0)" ::: "memory");   // drain before last tile
        }
        __builtin_amdgcn_sched_barrier(0);
        __builtin_amdgcn_s_barrier();
    }

    // ---- epilogue: C row = (lane>>4)*4 + r, col = lane&15 (logical rows) ----
    #pragma unroll
    for (int mf = 0; mf < 8; ++mf) {
        #pragma unroll
        for (int nf = 0; nf < 4; ++nf) {
            #pragma unroll
            for (int r = 0; r < 4; ++r) {
                long grow = row0 + wm * 128 + mf * 16 + (lane >> 4) * 4 + r;
                int  gcol = col0 + wn * 64 + nf * 16 + fr;
                float v = acc[mf][nf][r];
                if constexpr (OUT_BF16) ((u16*)Dp)[grow * NCOL + gcol] = f2bf(v);
                else                    ((float*)Dp)[grow * NCOL + gcol] = v;
            }
        }
    }
}

// ---------------------------------------------------------------------------
// Banded temporal attention, LDS-staged via global_load_lds, 1 wave/block,
// NO barriers (wave-private LDS visibility via vmcnt(0)). Validated r11.
// Physical LDS slot p of row u holds LOGICAL chunk p ^ (u&7) (global-source
// pre-swizzle, LDS dest linear). qkv rows (b,s,t)-ordered; output rows
// stored PRE-SWIZZLED (A-side layout, s-based keys) for gemm3.
// ---------------------------------------------------------------------------
__global__ __launch_bounds__(64) void attn_k(const u16* __restrict__ qkv,
                                             u16* __restrict__ attn) {
    __shared__ u16 Kl[64 * 64];   // [u][slot] 128B rows, swizzled granules
    __shared__ u16 Vl[64 * 64];

    const int tid = threadIdx.x;
    const int bid = blockIdx.x;
    const int h = bid & (H_ - 1);
    const int s = (bid >> 3) & (S_ - 1);
    const int b = bid >> 13;

    const size_t base = ((size_t)((b << 10) | s) * 64) * 1536 + h * 64;

    // ---- stage K,V: 8 issues each; lane l covers (row it*8+(l>>3), slot l&7)
    {
        const int ur = tid >> 3;     // row-within-group
        const int cp = tid & 7;      // physical granule slot in LDS
        #pragma unroll
        for (int it = 0; it < 8; ++it) {
            int u = it * 8 + ur;
            int c = cp ^ (u & 7);    // logical chunk fetched into slot cp
            gload16(qkv + base + (size_t)u * 1536 + 512 + c * 8,
                    (void*)&Kl[it * 512]);
        }
        #pragma unroll
        for (int it = 0; it < 8; ++it) {
            int u = it * 8 + ur;
            int c = cp ^ (u & 7);
            gload16(qkv + base + (size_t)u * 1536 + 1024 + c * 8,
                    (void*)&Vl[it * 512]);
        }
    }

    // ---- Q row (direct, fp32 in regs) — overlaps with staging in flight ----
    float qf[64];
    const int t = tid;
    {
        const u16* qp = qkv + base + (size_t)t * 1536;
        #pragma unroll
        for (int c = 0; c < 8; ++c) {
            u16x8 v = *(const u16x8*)(qp + c * 8);
            #pragma unroll
            for (int j = 0; j < 8; ++j) qf[c * 8 + j] = bf2f(v[j]);
        }
    }
    asm volatile("s_waitcnt vmcnt(0)" ::: "memory");   // staging landed (1 wave)
    __builtin_amdgcn_sched_barrier(0);

    // ---- band scores + softmax ----
    float p[11];
    float m = -1e30f;
    #pragma unroll
    for (int i = 0; i < 11; ++i) {
        int u = t - WIN_ + i;
        if (u >= 0 && u < 64) {
            const int ubase = u * 64;
            const int key = u & 7;
            float dot = 0.f;
            #pragma unroll
            for (int c = 0; c < 8; ++c) {
                // slot c^key holds logical chunk c -> pair with qf[c*8+..]
                u16x8 kv = *(const u16x8*)&Kl[ubase + ((c ^ key) << 3)];
                #pragma unroll
                for (int j = 0; j < 8; ++j) dot += qf[c * 8 + j] * bf2f(kv[j]);
            }
            p[i] = dot * 0.125f;   // hd^-0.5
            m = fmaxf(m, p[i]);
        } else {
            p[i] = -1e30f;
        }
    }
    float sum = 0.f;
    #pragma unroll
    for (int i = 0; i < 11; ++i) {
        int u = t - WIN_ + i;
        float e = (u >= 0 && u < 64) ? __expf(p[i] - m) : 0.f;
        p[i] = e;
        sum += e;
    }
    const float inv = 1.f / sum;

    // ---- PV ----
    float o[64];
    #pragma unroll
    for (int d = 0; d < 64; ++d) o[d] = 0.f;
    #pragma unroll
    for (int i = 0; i < 11; ++i) {
        int u = t - WIN_ + i;
        if (u >= 0 && u < 64) {
            const int ubase = u * 64;
            const int key = u & 7;
            float pv = p[i] * inv;
            #pragma unroll
            for (int c = 0; c < 8; ++c) {
                u16x8 vv = *(const u16x8*)&Vl[ubase + ((c ^ key) << 3)];
                #pragma unroll
                for (int j = 0; j < 8; ++j) o[c * 8 + j] += pv * bf2f(vv[j]);
            }
        }
    }
    // ---- pre-swizzled store at physical row rid; keys from s ----
    size_t rowbase = ((size_t)((b << 10) | s) * 64 + t) * (size_t)C_;
    const int cb  = (s >> 3) & 1;
    const int key = (s >> 1) & 3;
    #pragma unroll
    for (int c = 0; c < 8; ++c) {
        u16x8 w;
        #pragma unroll
        for (int j = 0; j < 8; ++j) w[j] = f2bf(o[c * 8 + j]);
        int off = (((2 * h + (c >> 2)) ^ cb) << 5) + (((c & 3) ^ key) << 3);
        *(u16x8*)&attn[rowbase + off] = w;
    }
}

// ---------------------------------------------------------------------------
extern "C" void kernel_launch(void* const* d_in, const int* in_sizes, int n_in,
                              void* d_out, int out_size, void* d_ws, size_t ws_size,
                              hipStream_t stream) {
    const float* x    = (const float*)d_in[0];   // (B, N, C) fp32
    const float* Wqkv = (const float*)d_in[1];   // (512, 1536) fp32
    const float* Wout = (const float*)d_in[2];   // (512, 512) fp32
    float* out = (float*)d_out;

    const size_t xc_elems  = (size_t)M_ * C_;      // 67.1M (x_bf16 / attn alias)
    const size_t qkv_elems = (size_t)M_ * 1536;    // 201.3M
    if (ws_size < (xc_elems + qkv_elems) * sizeof(u16)) return;  // 537 MiB

    u16* xb       = (u16*)d_ws;              // [0, 134MB): x_bf16 (b,s,t)-rows
    u16* qkv      = xb + xc_elems;           // [134MB, 537MB), (b,s,t)-rows
    u16* attn_buf = xb;                      // alias: written after xb is dead
    u16* WqkvT    = (u16*)d_out;             // scratch in d_out (dead until gemm3)
    u16* WoutT    = qkv;                     // alias: written after qkv is dead

    // 1) weight + activation prep (bf16, pre-swizzled; x rows permuted)
    prep_w<<<(1536 * 64) / 256, 256, 0, stream>>>(Wqkv, WqkvT, 1536);
    prep_x<<<8192, 256, 0, stream>>>(x, xb);

    // 2) qkv = x @ W_qkv  (256^2 8-phase, bf16 out, rows already permuted)
    gemm8_k<1536, true, false><<<3072, 512, 0, stream>>>(xb, WqkvT, (void*)qkv, 6);

    // 3) banded temporal attention (LDS-staged, swizzled, barrier-free)
    attn_k<<<B_ * H_ * S_, 64, 0, stream>>>(qkv, attn_buf);

    // 4) WoutT into the now-dead qkv region
    prep_w<<<(512 * 64) / 256, 256, 0, stream>>>(Wout, WoutT, 512);

    // 5) out = attn @ W_out  (256^2 8-phase, fp32 out coalesced; A un-permuted
    //    via per-lane gload addresses, attn_buf is L3-resident)
    gemm8_k<512, false, true><<<1024, 512, 0, stream>>>(attn_buf, WoutT, (void*)out, 2);
}

// Round 16
// 587.411 us; speedup vs baseline: 1.3733x; 1.0384x over previous
//
#include <hip/hip_runtime.h>
#include <stdint.h>

// Problem constants (fixed instance from setup_inputs)
#define B_   2
#define T_   64
#define S_   1024
#define C_   512
#define H_   8
#define N_   (T_ * S_)      // 65536
#define M_   (B_ * N_)      // 131072
#define WIN_ 5

typedef unsigned short u16;
typedef __bf16 bf16;
typedef __bf16 bf16x8 __attribute__((ext_vector_type(8)));
typedef float  f32x4  __attribute__((ext_vector_type(4)));
typedef u16    u16x8  __attribute__((ext_vector_type(8)));

static __device__ __forceinline__ u16 f2bf(float f) {
    return __builtin_bit_cast(u16, (bf16)f);   // RNE
}
static __device__ __forceinline__ float bf2f(u16 u) {
    return __builtin_bit_cast(float, (uint32_t)u << 16);
}
// async global->LDS, 16B per lane; LDS dest is wave-uniform base + lane*16
static __device__ __forceinline__ void gload16(const void* g, void* l) {
    __builtin_amdgcn_global_load_lds(
        (const __attribute__((address_space(1))) void*)g,
        (__attribute__((address_space(3))) void*)l, 16, 0, 0);
}
// row permutation: logical (b,t,s) flat row -> physical (b,s,t) flat row
static __device__ __forceinline__ long permute_row(long grow) {
    int b = (int)(grow >> 16);
    int t = (int)(grow >> 10) & 63;
    int s = (int)grow & 1023;
    return ((long)((b << 10) | s)) * 64 + t;
}

// Pre-swizzle layout (bf16 [row][512] operands): logical (chunk c in [0,16),
// granule g in [0,4), elem j) stored at
// r*512 + (c ^ ((rl>>3)&1))*32 + ((g ^ ((rl>>1)&3))<<3) + j,
// keys from the TILE-LOCAL row rl (= r mod tile-rows). 0 conflicts measured.

// ---------------------------------------------------------------------------
// Wout prep: W [512][512] fp32 -> WT [512][512] bf16, pre-swizzled (keys from
// n's low bits = local row, since gemm3 col0 is a multiple of 256).
// ---------------------------------------------------------------------------
__global__ __launch_bounds__(256) void prep_w(const float* __restrict__ W,
                                              u16* __restrict__ WT, int NCOL) {
    int id = blockIdx.x * 256 + threadIdx.x;
    int n  = id % NCOL;
    int gi = id / NCOL;
    int chunk = gi >> 2;
    int g     = gi & 3;
    int k0 = chunk * 32 + g * 8;
    int cs = chunk ^ ((n >> 3) & 1);
    int gs = g ^ ((n >> 1) & 3);
    u16x8 w;
    #pragma unroll
    for (int j = 0; j < 8; ++j) w[j] = f2bf(W[(size_t)(k0 + j) * NCOL + n]);
    *(u16x8*)&WT[(size_t)n * 512 + cs * 32 + gs * 8] = w;
}

// ---------------------------------------------------------------------------
// Wqkv prep, head-grouped: W [512][1536] fp32, col n = which*512 + h*64 + d
// -> WT2 row n' = h*192 + which*64 + d (so head h's B panel = 192 contiguous
// rows), bf16, pre-swizzled with keys from the PANEL-LOCAL row which*64+d.
// ---------------------------------------------------------------------------
__global__ __launch_bounds__(256) void prep_w2(const float* __restrict__ W,
                                               u16* __restrict__ WT2) {
    int id = blockIdx.x * 256 + threadIdx.x;
    int n  = id % 1536;
    int gi = id / 1536;
    int chunk = gi >> 2;
    int g     = gi & 3;
    int k0 = chunk * 32 + g * 8;
    int which = n >> 9;
    int h     = (n >> 6) & 7;
    int d     = n & 63;
    int rloc  = which * 64 + d;          // 0..191 panel-local row
    long np   = h * 192 + rloc;
    int cs = chunk ^ ((rloc >> 3) & 1);
    int gs = g ^ ((rloc >> 1) & 3);
    u16x8 w;
    #pragma unroll
    for (int j = 0; j < 8; ++j) w[j] = f2bf(W[(size_t)(k0 + j) * 1536 + n]);
    *(u16x8*)&WT2[(size_t)np * 512 + cs * 32 + gs * 8] = w;
}

// ---------------------------------------------------------------------------
// x prep: x [M][512] fp32 (rows (b,t,s)) -> xb bf16 rows PERMUTED to (b,s,t),
// pre-swizzled with keys from the permuted row index.
// ---------------------------------------------------------------------------
__global__ __launch_bounds__(256) void prep_x(const float* __restrict__ x,
                                              u16* __restrict__ xb) {
    const size_t total = (size_t)M_ * 64;   // 16B granules
    for (size_t id = (size_t)blockIdx.x * 256 + threadIdx.x; id < total;
         id += (size_t)gridDim.x * 256) {
        long r_in = (long)(id >> 6);
        int  gi   = (int)(id & 63);
        int chunk = gi >> 2;
        int g     = gi & 3;
        long rid  = permute_row(r_in);
        int cb  = (int)(rid >> 3) & 1;
        int key = (int)(rid >> 1) & 3;
        const float* src = x + r_in * 512 + chunk * 32 + g * 8;
        f32x4 v0 = *(const f32x4*)(src);
        f32x4 v1 = *(const f32x4*)(src + 4);
        u16x8 w;
        #pragma unroll
        for (int j = 0; j < 4; ++j) { w[j] = f2bf(v0[j]); w[4 + j] = f2bf(v1[j]); }
        *(u16x8*)&xb[(size_t)rid * 512 + (chunk ^ cb) * 32 + ((g ^ key) << 3)] = w;
    }
}

#define LDF(off) __builtin_bit_cast(bf16x8, *(const u16x8*)&lds[(off)])
#define MFMA16(d, a, b) d = __builtin_amdgcn_mfma_f32_16x16x32_bf16(a, b, d, 0, 0, 0)

// ---------------------------------------------------------------------------
// FUSED qkv-GEMM + banded attention. Grid 4096 = 512 rowtiles x 8 heads
// (rowtile = bid & 511 -> consecutive bids spread rowtiles across XCDs; all
// heads' B panels total 1.5MB, L2-hot). Block: 256 rows (= 4 complete (b,s)
// slabs) x 192 cols (Q|K|V of head h). Same total MFMA as the unfused gemm1.
// 512 thr = 8 waves as 4 wm x 2 wn (wave = 64 rows x 96 cols, 4 mf x 6 nf).
// K-loop: r11 skeleton, BK=64, A dbuf 2x32KB, B dbuf 2x24KB (112KB LDS):
//   ph0: af0(4)+bf0[0-2](3); stageA(t+1,0); bar; lgkm0; 12 MFMA kk0 nf0-2
//   ph1: bf0[3-5](3);        stageA(t+1,1); bar; lgkm0; 12 MFMA kk0 nf3-5
//   ph2: af1(4)+bf1[0-5](6);                bar; lgkm0; 12 MFMA kk1 nf0-2
//   ph3: stageB(t+2) [3 iss; safe: all B reads of tile t done at ph2's
//        lgkm+barrier]; bar; 12 MFMA kk1 nf3-5; vmcnt(3); bar
// vmem queue/tile = [sB(t+1)x3 | sA(t+1)x4 | sB(t+2)x3]: vmcnt(3) at tile end
// retires sB(t+1)+sA(t+1), keeps sB(t+2) in flight. Prologue [A0x4,B0x3,B1x3]
// + vmcnt(3). Guards: stageA t<=6, stageB t<=5, vmcnt(0) at t==6.
// Epilogue: acc -> LDS panel [256][192] bf16 (granule slot g^(row&7) per
// 64-col section), __syncthreads, waves 0-3 run per-slab banded attention
// (validated attn_k math) and store pre-swizzled rows for gemm3.
// ---------------------------------------------------------------------------
__global__ __launch_bounds__(512, 2) void gemm_attn(const u16* __restrict__ Ap,
                                                    const u16* __restrict__ Bp,
                                                    u16* __restrict__ attn) {
    __shared__ u16 lds[57344];   // A0@0 A1@16384 B0@32768 B1@45056 (u16 units)

    const int tid  = threadIdx.x;
    const int lane = tid & 63;
    const int wid  = tid >> 6;    // 0..7
    const int wm   = wid >> 1;    // 0..3
    const int wn   = wid & 1;     // 0..1
    const int fr   = lane & 15;
    const int g0   = lane >> 4;

    const int rowtile = blockIdx.x & 511;
    const int h       = blockIdx.x >> 9;
    const long row0   = (long)rowtile * 256;

    // frag LDS offsets (u16, rel. to buffer base), kk=0; kk=1 = ^32
    int aoffs[4], boffs[6];
    #pragma unroll
    for (int mf = 0; mf < 4; ++mf) {
        int lr = wm * 64 + mf * 16 + fr;
        aoffs[mf] = lr * 64 + (((lr >> 3) & 1) << 5) + (((g0 ^ (lr >> 1)) & 3) << 3);
    }
    #pragma unroll
    for (int nf = 0; nf < 6; ++nf) {
        int lc = wn * 96 + nf * 16 + fr;
        boffs[nf] = lc * 64 + (((lc >> 3) & 1) << 5) + (((g0 ^ (lc >> 1)) & 3) << 3);
    }

    const int srow = lane >> 3;
    const int scol = (lane & 7) * 8;

    auto stageA = [&](int tt, int half) {
        const int ab = (tt & 1) * 16384;
        #pragma unroll
        for (int i = 0; i < 2; ++i) {
            int r = half * 128 + i * 64 + wid * 8 + srow;
            const u16* g = Ap + (row0 + r) * 512 + tt * 64 + scol;
            gload16(g, (void*)&lds[ab + r * 64]);
        }
    };
    auto stageB = [&](int tt) {
        const int bb = 32768 + (tt & 1) * 12288;
        #pragma unroll
        for (int i = 0; i < 3; ++i) {
            int r = i * 64 + wid * 8 + srow;            // 0..191
            const u16* g = Bp + (size_t)(h * 192 + r) * 512 + tt * 64 + scol;
            gload16(g, (void*)&lds[bb + r * 64]);
        }
    };

    f32x4 acc[4][6] = {};

    // ---- prologue ----
    stageA(0, 0); stageA(0, 1); stageB(0); stageB(1);
    asm volatile("s_waitcnt vmcnt(3)" ::: "memory");
    __builtin_amdgcn_sched_barrier(0);
    __builtin_amdgcn_s_barrier();

    #pragma unroll
    for (int t = 0; t < 8; ++t) {
        const int ab = (t & 1) * 16384;
        const int bb = 32768 + (t & 1) * 12288;
        bf16x8 af0[4], af1[4], bf0[6], bf1[6];
        // ================= phase 0 =================
        #pragma unroll
        for (int mf = 0; mf < 4; ++mf) af0[mf] = LDF(ab + aoffs[mf]);
        #pragma unroll
        for (int nf = 0; nf < 3; ++nf) bf0[nf] = LDF(bb + boffs[nf]);
        if (t <= 6) stageA(t + 1, 0);
        __builtin_amdgcn_s_barrier();
        asm volatile("s_waitcnt lgkmcnt(0)" ::: "memory");
        __builtin_amdgcn_sched_barrier(0);
        __builtin_amdgcn_s_setprio(1);
        #pragma unroll
        for (int mf = 0; mf < 4; ++mf) {
            MFMA16(acc[mf][0], af0[mf], bf0[0]);
            MFMA16(acc[mf][1], af0[mf], bf0[1]);
            MFMA16(acc[mf][2], af0[mf], bf0[2]);
        }
        __builtin_amdgcn_s_setprio(0);
        __builtin_amdgcn_s_barrier();
        // ================= phase 1 =================
        #pragma unroll
        for (int nf = 3; nf < 6; ++nf) bf0[nf] = LDF(bb + boffs[nf]);
        if (t <= 6) stageA(t + 1, 1);
        __builtin_amdgcn_s_barrier();
        asm volatile("s_waitcnt lgkmcnt(0)" ::: "memory");
        __builtin_amdgcn_sched_barrier(0);
        __builtin_amdgcn_s_setprio(1);
        #pragma unroll
        for (int mf = 0; mf < 4; ++mf) {
            MFMA16(acc[mf][3], af0[mf], bf0[3]);
            MFMA16(acc[mf][4], af0[mf], bf0[4]);
            MFMA16(acc[mf][5], af0[mf], bf0[5]);
        }
        __builtin_amdgcn_s_setprio(0);
        __builtin_amdgcn_s_barrier();
        // ================= phase 2 =================
        #pragma unroll
        for (int mf = 0; mf < 4; ++mf) af1[mf] = LDF(ab + (aoffs[mf] ^ 32));
        #pragma unroll
        for (int nf = 0; nf < 6; ++nf) bf1[nf] = LDF(bb + (boffs[nf] ^ 32));
        __builtin_amdgcn_s_barrier();
        asm volatile("s_waitcnt lgkmcnt(0)" ::: "memory");
        __builtin_amdgcn_sched_barrier(0);
        __builtin_amdgcn_s_setprio(1);
        #pragma unroll
        for (int mf = 0; mf < 4; ++mf) {
            MFMA16(acc[mf][0], af1[mf], bf1[0]);
            MFMA16(acc[mf][1], af1[mf], bf1[1]);
            MFMA16(acc[mf][2], af1[mf], bf1[2]);
        }
        __builtin_amdgcn_s_setprio(0);
        __builtin_amdgcn_s_barrier();
        // ================= phase 3 =================
        if (t <= 5) stageB(t + 2);
        __builtin_amdgcn_s_barrier();
        __builtin_amdgcn_s_setprio(1);
        #pragma unroll
        for (int mf = 0; mf < 4; ++mf) {
            MFMA16(acc[mf][3], af1[mf], bf1[3]);
            MFMA16(acc[mf][4], af1[mf], bf1[4]);
            MFMA16(acc[mf][5], af1[mf], bf1[5]);
        }
        __builtin_amdgcn_s_setprio(0);
        if (t <= 5) {
            asm volatile("s_waitcnt vmcnt(3)" ::: "memory");
        } else if (t == 6) {
            asm volatile("s_waitcnt vmcnt(0)" ::: "memory");
        }
        __builtin_amdgcn_sched_barrier(0);
        __builtin_amdgcn_s_barrier();
    }

    // ---- epilogue: acc -> LDS panel [256][192], granule slot g^(row&7) ----
    __builtin_amdgcn_sched_barrier(0);
    #pragma unroll
    for (int mf = 0; mf < 4; ++mf) {
        #pragma unroll
        for (int nf = 0; nf < 6; ++nf) {
            #pragma unroll
            for (int r = 0; r < 4; ++r) {
                int row = wm * 64 + mf * 16 + (lane >> 4) * 4 + r;
                int col = wn * 96 + nf * 16 + fr;
                int sec = col >> 6;
                int d   = col & 63;
                int slot = (d >> 3) ^ (row & 7);
                lds[row * 192 + sec * 64 + slot * 8 + (d & 7)] = f2bf(acc[mf][nf][r]);
            }
        }
    }
    __syncthreads();

    // ---- banded attention: waves 0-3, one (b,s) slab each ----
    if (wid < 4) {
        const int slab = wid;
        const int t = lane;
        const int prow = slab * 64 + t;
        float qf[64];
        {
            const int key = prow & 7;
            #pragma unroll
            for (int c = 0; c < 8; ++c) {
                u16x8 v = *(const u16x8*)&lds[prow * 192 + ((c ^ key) << 3)];
                #pragma unroll
                for (int j = 0; j < 8; ++j) qf[c * 8 + j] = bf2f(v[j]);
            }
        }
        float p[11];
        float m = -1e30f;
        #pragma unroll
        for (int i = 0; i < 11; ++i) {
            int u = t - WIN_ + i;
            if (u >= 0 && u < 64) {
                const int ub = (slab * 64 + u) * 192 + 64;
                const int key = (slab * 64 + u) & 7;
                float dot = 0.f;
                #pragma unroll
                for (int c = 0; c < 8; ++c) {
                    u16x8 kv = *(const u16x8*)&lds[ub + ((c ^ key) << 3)];
                    #pragma unroll
                    for (int j = 0; j < 8; ++j) dot += qf[c * 8 + j] * bf2f(kv[j]);
                }
                p[i] = dot * 0.125f;
                m = fmaxf(m, p[i]);
            } else {
                p[i] = -1e30f;
            }
        }
        float sum = 0.f;
        #pragma unroll
        for (int i = 0; i < 11; ++i) {
            int u = t - WIN_ + i;
            float e = (u >= 0 && u < 64) ? __expf(p[i] - m) : 0.f;
            p[i] = e;
            sum += e;
        }
        const float inv = 1.f / sum;
        float o[64];
        #pragma unroll
        for (int d = 0; d < 64; ++d) o[d] = 0.f;
        #pragma unroll
        for (int i = 0; i < 11; ++i) {
            int u = t - WIN_ + i;
            if (u >= 0 && u < 64) {
                const int ub = (slab * 64 + u) * 192 + 128;
                const int key = (slab * 64 + u) & 7;
                float pv = p[i] * inv;
                #pragma unroll
                for (int c = 0; c < 8; ++c) {
                    u16x8 vv = *(const u16x8*)&lds[ub + ((c ^ key) << 3)];
                    #pragma unroll
                    for (int j = 0; j < 8; ++j) o[c * 8 + j] += pv * bf2f(vv[j]);
                }
            }
        }
        // pre-swizzled store at physical row rid; keys from s (gemm3 A layout)
        long rid = row0 + prow;
        int s = (int)(rid >> 6) & 1023;
        size_t rowbase = (size_t)rid * C_;
        const int cb  = (s >> 3) & 1;
        const int key = (s >> 1) & 3;
        #pragma unroll
        for (int c = 0; c < 8; ++c) {
            u16x8 w;
            #pragma unroll
            for (int j = 0; j < 8; ++j) w[j] = f2bf(o[c * 8 + j]);
            int off = (((2 * h + (c >> 2)) ^ cb) << 5) + (((c & 3) ^ key) << 3);
            *(u16x8*)&attn[rowbase + off] = w;
        }
    }
}

// ---------------------------------------------------------------------------
// 256x256 8-phase pipelined GEMM (r11-validated) — used for out = attn@W_out.
// ---------------------------------------------------------------------------
template<int NCOL, bool OUT_BF16, bool A_PERM>
__global__ __launch_bounds__(512, 2) void gemm8_k(const u16* __restrict__ Ap,
                                                  const u16* __restrict__ Bp,
                                                  void* __restrict__ Dp, int gx) {
    __shared__ u16 lds[65536];   // dbuf0{A,B} | dbuf1{A,B}, 16384 u16 each

    const int tid  = threadIdx.x;
    const int lane = tid & 63;
    const int wid  = tid >> 6;
    const int wm   = wid >> 2;
    const int wn   = wid & 3;
    const int fr   = lane & 15;
    const int g0   = lane >> 4;

    const int nwg = gridDim.x;
    const int q8  = nwg >> 3;
    const int bid = blockIdx.x;
    const int wg  = (bid & 7) * q8 + (bid >> 3);
    const int bx  = wg % gx;
    const int by  = wg / gx;
    const long row0 = (long)by * 256;
    const int  col0 = bx * 256;

    int aoffs[8], boffs[4];
    #pragma unroll
    for (int mf = 0; mf < 8; ++mf) {
        int lr = wm * 128 + mf * 16 + fr;
        aoffs[mf] = lr * 64 + (((lr >> 3) & 1) << 5) + (((g0 ^ (lr >> 1)) & 3) << 3);
    }
    #pragma unroll
    for (int nf = 0; nf < 4; ++nf) {
        int lc = wn * 64 + nf * 16 + fr;
        boffs[nf] = lc * 64 + (((lc >> 3) & 1) << 5) + (((g0 ^ (lc >> 1)) & 3) << 3);
    }

    const int srow = lane >> 3;
    const int scol = (lane & 7) * 8;

    long arow_phys[4];
    #pragma unroll
    for (int half = 0; half < 2; ++half)
        #pragma unroll
        for (int i = 0; i < 2; ++i) {
            int r = half * 128 + i * 64 + wid * 8 + srow;
            long grow = row0 + r;
            arow_phys[half * 2 + i] = A_PERM ? permute_row(grow) : grow;
        }

    auto stageA = [&](int tt, int half) {
        const int ab = (tt & 1) * 32768;
        #pragma unroll
        for (int i = 0; i < 2; ++i) {
            int r = half * 128 + i * 64 + wid * 8 + srow;
            const u16* g = Ap + arow_phys[half * 2 + i] * 512 + tt * 64 + scol;
            gload16(g, (void*)&lds[ab + r * 64]);
        }
    };
    auto stageB = [&](int tt, int half) {
        const int ab = (tt & 1) * 32768;
        #pragma unroll
        for (int i = 0; i < 2; ++i) {
            int r = half * 128 + i * 64 + wid * 8 + srow;
            const u16* g = Bp + (size_t)(col0 + r) * 512 + tt * 64 + scol;
            gload16(g, (void*)&lds[ab + 16384 + r * 64]);
        }
    };

    f32x4 acc[8][4] = {};

    stageA(0, 0); stageA(0, 1); stageB(0, 0); stageB(0, 1);
    stageB(1, 0); stageB(1, 1);
    asm volatile("s_waitcnt vmcnt(4)" ::: "memory");
    __builtin_amdgcn_sched_barrier(0);
    __builtin_amdgcn_s_barrier();

    #pragma unroll
    for (int t = 0; t < 8; ++t) {
        const int ab = (t & 1) * 32768;
        bf16x8 af0[8], af1[8], bf0[4], bf1[4];
        // phase 0
        #pragma unroll
        for (int mf = 0; mf < 4; ++mf) af0[mf] = LDF(ab + aoffs[mf]);
        #pragma unroll
        for (int nf = 0; nf < 4; ++nf) bf0[nf] = LDF(ab + 16384 + boffs[nf]);
        if (t <= 6) stageA(t + 1, 0);
        __builtin_amdgcn_s_barrier();
        asm volatile("s_waitcnt lgkmcnt(0)" ::: "memory");
        __builtin_amdgcn_sched_barrier(0);
        __builtin_amdgcn_s_setprio(1);
        #pragma unroll
        for (int mf = 0; mf < 4; ++mf) {
            MFMA16(acc[mf][0], af0[mf], bf0[0]);
            MFMA16(acc[mf][1], af0[mf], bf0[1]);
            MFMA16(acc[mf][2], af0[mf], bf0[2]);
            MFMA16(acc[mf][3], af0[mf], bf0[3]);
        }
        __builtin_amdgcn_s_setprio(0);
        __builtin_amdgcn_s_barrier();
        // phase 1
        #pragma unroll
        for (int mf = 4; mf < 8; ++mf) af0[mf] = LDF(ab + aoffs[mf]);
        #pragma unroll
        for (int nf = 0; nf < 4; ++nf) bf1[nf] = LDF(ab + 16384 + (boffs[nf] ^ 32));
        if (t <= 6) stageA(t + 1, 1);
        __builtin_amdgcn_s_barrier();
        asm volatile("s_waitcnt lgkmcnt(0)" ::: "memory");
        __builtin_amdgcn_sched_barrier(0);
        __builtin_amdgcn_s_setprio(1);
        #pragma unroll
        for (int mf = 4; mf < 8; ++mf) {
            MFMA16(acc[mf][0], af0[mf], bf0[0]);
            MFMA16(acc[mf][1], af0[mf], bf0[1]);
            MFMA16(acc[mf][2], af0[mf], bf0[2]);
            MFMA16(acc[mf][3], af0[mf], bf0[3]);
        }
        __builtin_amdgcn_s_setprio(0);
        __builtin_amdgcn_s_barrier();
        // phase 2
        #pragma unroll
        for (int mf = 0; mf < 4; ++mf) af1[mf] = LDF(ab + (aoffs[mf] ^ 32));
        if (t <= 5) stageB(t + 2, 0);
        __builtin_amdgcn_s_barrier();
        asm volatile("s_waitcnt lgkmcnt(0)" ::: "memory");
        __builtin_amdgcn_sched_barrier(0);
        __builtin_amdgcn_s_setprio(1);
        #pragma unroll
        for (int mf = 0; mf < 4; ++mf) {
            MFMA16(acc[mf][0], af1[mf], bf1[0]);
            MFMA16(acc[mf][1], af1[mf], bf1[1]);
            MFMA16(acc[mf][2], af1[mf], bf1[2]);
            MFMA16(acc[mf][3], af1[mf], bf1[3]);
        }
        __builtin_amdgcn_s_setprio(0);
        __builtin_amdgcn_s_barrier();
        // phase 3
        #pragma unroll
        for (int mf = 4; mf < 8; ++mf) af1[mf] = LDF(ab + (aoffs[mf] ^ 32));
        if (t <= 5) stageB(t + 2, 1);
        __builtin_amdgcn_s_barrier();
        asm volatile("s_waitcnt lgkmcnt(0)" ::: "memory");
        __builtin_amdgcn_sched_barrier(0);
        __builtin_amdgcn_s_setprio(1);
        #pragma unroll
        for (int mf = 4; mf < 8; ++mf) {
            MFMA16(acc[mf][0], af1[mf], bf1[0]);
            MFMA16(acc[mf][1], af1[mf], bf1[1]);
            MFMA16(acc[mf][2], af1[mf], bf1[2]);
            MFMA16(acc[mf][3], af1[mf], bf1[3]);
        }
        __builtin_amdgcn_s_setprio(0);
        if (t <= 5) {
            asm volatile("s_waitcnt vmcnt(4)" ::: "memory");
        } else if (t == 6) {
            asm volatile("s_waitcnt vmcnt(0)" ::: "memory");
        }
        __builtin_amdgcn_sched_barrier(0);
        __builtin_amdgcn_s_barrier();
    }

    #pragma unroll
    for (int mf = 0; mf < 8; ++mf) {
        #pragma unroll
        for (int nf = 0; nf < 4; ++nf) {
            #pragma unroll
            for (int r = 0; r < 4; ++r) {
                long grow = row0 + wm * 128 + mf * 16 + (lane >> 4) * 4 + r;
                int  gcol = col0 + wn * 64 + nf * 16 + fr;
                float v = acc[mf][nf][r];
                if constexpr (OUT_BF16) ((u16*)Dp)[grow * NCOL + gcol] = f2bf(v);
                else                    ((float*)Dp)[grow * NCOL + gcol] = v;
            }
        }
    }
}

// ---------------------------------------------------------------------------
extern "C" void kernel_launch(void* const* d_in, const int* in_sizes, int n_in,
                              void* d_out, int out_size, void* d_ws, size_t ws_size,
                              hipStream_t stream) {
    const float* x    = (const float*)d_in[0];   // (B, N, C) fp32
    const float* Wqkv = (const float*)d_in[1];   // (512, 1536) fp32
    const float* Wout = (const float*)d_in[2];   // (512, 512) fp32
    float* out = (float*)d_out;

    const size_t xc_elems = (size_t)M_ * C_;     // 67.1M u16
    // layout: xb | attn_buf | WqkvT2 | WoutT  (~272 MB total, no aliasing)
    u16* xb       = (u16*)d_ws;
    u16* attn_buf = xb + xc_elems;
    u16* WqkvT2   = attn_buf + xc_elems;
    u16* WoutT    = WqkvT2 + (size_t)1536 * 512;
    if (ws_size < ((size_t)(WoutT + (size_t)512 * 512) - (size_t)d_ws)) return;

    // 1) weight + activation prep
    prep_w2<<<(1536 * 64) / 256, 256, 0, stream>>>(Wqkv, WqkvT2);
    prep_w<<<(512 * 64) / 256, 256, 0, stream>>>(Wout, WoutT, 512);
    prep_x<<<8192, 256, 0, stream>>>(x, xb);

    // 2) fused qkv-GEMM + banded attention (no qkv round-trip)
    gemm_attn<<<4096, 512, 0, stream>>>(xb, WqkvT2, attn_buf);

    // 3) out = attn @ W_out
    gemm8_k<512, false, true><<<1024, 512, 0, stream>>>(attn_buf, WoutT, (void*)out, 2);
}

// Round 17
// 530.482 us; speedup vs baseline: 1.5207x; 1.1073x over previous
//
#include <hip/hip_runtime.h>
#include <stdint.h>

// Problem constants (fixed instance from setup_inputs)
#define B_   2
#define T_   64
#define S_   1024
#define C_   512
#define H_   8
#define N_   (T_ * S_)      // 65536
#define M_   (B_ * N_)      // 131072
#define WIN_ 5

typedef unsigned short u16;
typedef __bf16 bf16;
typedef __bf16 bf16x8 __attribute__((ext_vector_type(8)));
typedef float  f32x4  __attribute__((ext_vector_type(4)));
typedef u16    u16x8  __attribute__((ext_vector_type(8)));

static __device__ __forceinline__ u16 f2bf(float f) {
    return __builtin_bit_cast(u16, (bf16)f);   // RNE
}
static __device__ __forceinline__ float bf2f(u16 u) {
    return __builtin_bit_cast(float, (uint32_t)u << 16);
}
// async global->LDS, 16B per lane; LDS dest is wave-uniform base + lane*16
static __device__ __forceinline__ void gload16(const void* g, void* l) {
    __builtin_amdgcn_global_load_lds(
        (const __attribute__((address_space(1))) void*)g,
        (__attribute__((address_space(3))) void*)l, 16, 0, 0);
}
// row permutation: logical (b,t,s) flat row -> physical (b,s,t) flat row
static __device__ __forceinline__ long permute_row(long grow) {
    int b = (int)(grow >> 16);
    int t = (int)(grow >> 10) & 63;
    int s = (int)grow & 1023;
    return ((long)((b << 10) | s)) * 64 + t;
}

// Pre-swizzle layout (bf16 [row][512] operands): logical (chunk c in [0,16),
// granule g in [0,4), elem j) stored at
// r*512 + (c ^ ((rl>>3)&1))*32 + ((g ^ ((rl>>1)&3))<<3) + j,
// keys from the TILE-LOCAL row rl (= r mod tile-rows). 0 conflicts measured.

// ---------------------------------------------------------------------------
// Wout prep: W [512][512] fp32 -> WT [512][512] bf16, pre-swizzled.
// ---------------------------------------------------------------------------
__global__ __launch_bounds__(256) void prep_w(const float* __restrict__ W,
                                              u16* __restrict__ WT, int NCOL) {
    int id = blockIdx.x * 256 + threadIdx.x;
    int n  = id % NCOL;
    int gi = id / NCOL;
    int chunk = gi >> 2;
    int g     = gi & 3;
    int k0 = chunk * 32 + g * 8;
    int cs = chunk ^ ((n >> 3) & 1);
    int gs = g ^ ((n >> 1) & 3);
    u16x8 w;
    #pragma unroll
    for (int j = 0; j < 8; ++j) w[j] = f2bf(W[(size_t)(k0 + j) * NCOL + n]);
    *(u16x8*)&WT[(size_t)n * 512 + cs * 32 + gs * 8] = w;
}

// ---------------------------------------------------------------------------
// Wqkv prep, head-grouped: W [512][1536] fp32, col n = which*512 + h*64 + d
// -> WT2 row n' = h*192 + which*64 + d, bf16, pre-swizzled with keys from the
// PANEL-LOCAL row which*64+d.
// ---------------------------------------------------------------------------
__global__ __launch_bounds__(256) void prep_w2(const float* __restrict__ W,
                                               u16* __restrict__ WT2) {
    int id = blockIdx.x * 256 + threadIdx.x;
    int n  = id % 1536;
    int gi = id / 1536;
    int chunk = gi >> 2;
    int g     = gi & 3;
    int k0 = chunk * 32 + g * 8;
    int which = n >> 9;
    int h     = (n >> 6) & 7;
    int d     = n & 63;
    int rloc  = which * 64 + d;          // 0..191 panel-local row
    long np   = h * 192 + rloc;
    int cs = chunk ^ ((rloc >> 3) & 1);
    int gs = g ^ ((rloc >> 1) & 3);
    u16x8 w;
    #pragma unroll
    for (int j = 0; j < 8; ++j) w[j] = f2bf(W[(size_t)(k0 + j) * 1536 + n]);
    *(u16x8*)&WT2[(size_t)np * 512 + cs * 32 + gs * 8] = w;
}

// ---------------------------------------------------------------------------
// x prep: x [M][512] fp32 (rows (b,t,s)) -> xb bf16 rows PERMUTED to (b,s,t),
// pre-swizzled with keys from the permuted row index.
// ---------------------------------------------------------------------------
__global__ __launch_bounds__(256) void prep_x(const float* __restrict__ x,
                                              u16* __restrict__ xb) {
    const size_t total = (size_t)M_ * 64;   // 16B granules
    for (size_t id = (size_t)blockIdx.x * 256 + threadIdx.x; id < total;
         id += (size_t)gridDim.x * 256) {
        long r_in = (long)(id >> 6);
        int  gi   = (int)(id & 63);
        int chunk = gi >> 2;
        int g     = gi & 3;
        long rid  = permute_row(r_in);
        int cb  = (int)(rid >> 3) & 1;
        int key = (int)(rid >> 1) & 3;
        const float* src = x + r_in * 512 + chunk * 32 + g * 8;
        f32x4 v0 = *(const f32x4*)(src);
        f32x4 v1 = *(const f32x4*)(src + 4);
        u16x8 w;
        #pragma unroll
        for (int j = 0; j < 4; ++j) { w[j] = f2bf(v0[j]); w[4 + j] = f2bf(v1[j]); }
        *(u16x8*)&xb[(size_t)rid * 512 + (chunk ^ cb) * 32 + ((g ^ key) << 3)] = w;
    }
}

#define LDF(off) __builtin_bit_cast(bf16x8, *(const u16x8*)&lds[(off)])
#define MFMA16(d, a, b) d = __builtin_amdgcn_mfma_f32_16x16x32_bf16(a, b, d, 0, 0, 0)

#define PSTR 200   // panel row stride (u16): 400B = 100 dwords == 4 mod 32 banks

// ---------------------------------------------------------------------------
// FUSED qkv-GEMM + banded attention.
// Grid 4096: bid = q*64 + h*8 + x; rowtile = q*8 + x (0..511), head = (bid>>3)&7.
// XCD = bid%8 = rowtile%8 -> all 8 heads of a rowtile run BACK-TO-BACK on the
// SAME XCD (per-XCD window = 8 rowtiles x 8 heads: A 2MB + B 1.5MB < 4MB L2).
// Block: 256 rows (4 (b,s) slabs) x 192 cols (Q|K|V of head h); 8 waves as
// 4 wm x 2 wn. K-loop identical to r16 (validated). Epilogue: acc -> LDS
// panel [256][PSTR=200] bf16 LINEAR (pad makes reads bank-bijective: quad =
// (row+c) mod 8; stores <=2-way), then waves 0-3 run per-slab banded attn and
// store pre-swizzled rows for gemm3.
// ---------------------------------------------------------------------------
__global__ __launch_bounds__(512, 2) void gemm_attn(const u16* __restrict__ Ap,
                                                    const u16* __restrict__ Bp,
                                                    u16* __restrict__ attn) {
    __shared__ u16 lds[57344];   // A0@0 A1@16384 B0@32768 B1@45056 (u16 units)

    const int tid  = threadIdx.x;
    const int lane = tid & 63;
    const int wid  = tid >> 6;    // 0..7
    const int wm   = wid >> 1;    // 0..3
    const int wn   = wid & 1;     // 0..1
    const int fr   = lane & 15;
    const int g0   = lane >> 4;

    const int rowtile = ((blockIdx.x >> 6) << 3) | (blockIdx.x & 7);
    const int h       = (blockIdx.x >> 3) & 7;
    const long row0   = (long)rowtile * 256;

    // frag LDS offsets (u16, rel. to buffer base), kk=0; kk=1 = ^32
    int aoffs[4], boffs[6];
    #pragma unroll
    for (int mf = 0; mf < 4; ++mf) {
        int lr = wm * 64 + mf * 16 + fr;
        aoffs[mf] = lr * 64 + (((lr >> 3) & 1) << 5) + (((g0 ^ (lr >> 1)) & 3) << 3);
    }
    #pragma unroll
    for (int nf = 0; nf < 6; ++nf) {
        int lc = wn * 96 + nf * 16 + fr;
        boffs[nf] = lc * 64 + (((lc >> 3) & 1) << 5) + (((g0 ^ (lc >> 1)) & 3) << 3);
    }

    const int srow = lane >> 3;
    const int scol = (lane & 7) * 8;

    auto stageA = [&](int tt, int half) {
        const int ab = (tt & 1) * 16384;
        #pragma unroll
        for (int i = 0; i < 2; ++i) {
            int r = half * 128 + i * 64 + wid * 8 + srow;
            const u16* g = Ap + (row0 + r) * 512 + tt * 64 + scol;
            gload16(g, (void*)&lds[ab + r * 64]);
        }
    };
    auto stageB = [&](int tt) {
        const int bb = 32768 + (tt & 1) * 12288;
        #pragma unroll
        for (int i = 0; i < 3; ++i) {
            int r = i * 64 + wid * 8 + srow;            // 0..191
            const u16* g = Bp + (size_t)(h * 192 + r) * 512 + tt * 64 + scol;
            gload16(g, (void*)&lds[bb + r * 64]);
        }
    };

    f32x4 acc[4][6] = {};

    // ---- prologue ----
    stageA(0, 0); stageA(0, 1); stageB(0); stageB(1);
    asm volatile("s_waitcnt vmcnt(3)" ::: "memory");
    __builtin_amdgcn_sched_barrier(0);
    __builtin_amdgcn_s_barrier();

    #pragma unroll
    for (int t = 0; t < 8; ++t) {
        const int ab = (t & 1) * 16384;
        const int bb = 32768 + (t & 1) * 12288;
        bf16x8 af0[4], af1[4], bf0[6], bf1[6];
        // ================= phase 0 =================
        #pragma unroll
        for (int mf = 0; mf < 4; ++mf) af0[mf] = LDF(ab + aoffs[mf]);
        #pragma unroll
        for (int nf = 0; nf < 3; ++nf) bf0[nf] = LDF(bb + boffs[nf]);
        if (t <= 6) stageA(t + 1, 0);
        __builtin_amdgcn_s_barrier();
        asm volatile("s_waitcnt lgkmcnt(0)" ::: "memory");
        __builtin_amdgcn_sched_barrier(0);
        __builtin_amdgcn_s_setprio(1);
        #pragma unroll
        for (int mf = 0; mf < 4; ++mf) {
            MFMA16(acc[mf][0], af0[mf], bf0[0]);
            MFMA16(acc[mf][1], af0[mf], bf0[1]);
            MFMA16(acc[mf][2], af0[mf], bf0[2]);
        }
        __builtin_amdgcn_s_setprio(0);
        __builtin_amdgcn_s_barrier();
        // ================= phase 1 =================
        #pragma unroll
        for (int nf = 3; nf < 6; ++nf) bf0[nf] = LDF(bb + boffs[nf]);
        if (t <= 6) stageA(t + 1, 1);
        __builtin_amdgcn_s_barrier();
        asm volatile("s_waitcnt lgkmcnt(0)" ::: "memory");
        __builtin_amdgcn_sched_barrier(0);
        __builtin_amdgcn_s_setprio(1);
        #pragma unroll
        for (int mf = 0; mf < 4; ++mf) {
            MFMA16(acc[mf][3], af0[mf], bf0[3]);
            MFMA16(acc[mf][4], af0[mf], bf0[4]);
            MFMA16(acc[mf][5], af0[mf], bf0[5]);
        }
        __builtin_amdgcn_s_setprio(0);
        __builtin_amdgcn_s_barrier();
        // ================= phase 2 =================
        #pragma unroll
        for (int mf = 0; mf < 4; ++mf) af1[mf] = LDF(ab + (aoffs[mf] ^ 32));
        #pragma unroll
        for (int nf = 0; nf < 6; ++nf) bf1[nf] = LDF(bb + (boffs[nf] ^ 32));
        __builtin_amdgcn_s_barrier();
        asm volatile("s_waitcnt lgkmcnt(0)" ::: "memory");
        __builtin_amdgcn_sched_barrier(0);
        __builtin_amdgcn_s_setprio(1);
        #pragma unroll
        for (int mf = 0; mf < 4; ++mf) {
            MFMA16(acc[mf][0], af1[mf], bf1[0]);
            MFMA16(acc[mf][1], af1[mf], bf1[1]);
            MFMA16(acc[mf][2], af1[mf], bf1[2]);
        }
        __builtin_amdgcn_s_setprio(0);
        __builtin_amdgcn_s_barrier();
        // ================= phase 3 =================
        if (t <= 5) stageB(t + 2);
        __builtin_amdgcn_s_barrier();
        __builtin_amdgcn_s_setprio(1);
        #pragma unroll
        for (int mf = 0; mf < 4; ++mf) {
            MFMA16(acc[mf][3], af1[mf], bf1[3]);
            MFMA16(acc[mf][4], af1[mf], bf1[4]);
            MFMA16(acc[mf][5], af1[mf], bf1[5]);
        }
        __builtin_amdgcn_s_setprio(0);
        if (t <= 5) {
            asm volatile("s_waitcnt vmcnt(3)" ::: "memory");
        } else if (t == 6) {
            asm volatile("s_waitcnt vmcnt(0)" ::: "memory");
        }
        __builtin_amdgcn_sched_barrier(0);
        __builtin_amdgcn_s_barrier();
    }

    // ---- epilogue: acc -> LDS panel [256][PSTR] bf16, LINEAR cols ----
    __builtin_amdgcn_sched_barrier(0);
    #pragma unroll
    for (int mf = 0; mf < 4; ++mf) {
        #pragma unroll
        for (int nf = 0; nf < 6; ++nf) {
            #pragma unroll
            for (int r = 0; r < 4; ++r) {
                int row = wm * 64 + mf * 16 + (lane >> 4) * 4 + r;
                int col = wn * 96 + nf * 16 + fr;
                lds[row * PSTR + col] = f2bf(acc[mf][nf][r]);
            }
        }
    }
    __syncthreads();

    // ---- banded attention: waves 0-3, one (b,s) slab each ----
    if (wid < 4) {
        const int slab = wid;
        const int t = lane;
        const int prow = slab * 64 + t;
        float qf[64];
        #pragma unroll
        for (int c = 0; c < 8; ++c) {
            u16x8 v = *(const u16x8*)&lds[prow * PSTR + c * 8];
            #pragma unroll
            for (int j = 0; j < 8; ++j) qf[c * 8 + j] = bf2f(v[j]);
        }
        float p[11];
        float m = -1e30f;
        #pragma unroll
        for (int i = 0; i < 11; ++i) {
            int u = t - WIN_ + i;
            if (u >= 0 && u < 64) {
                const int ub = (slab * 64 + u) * PSTR + 64;
                float dot = 0.f;
                #pragma unroll
                for (int c = 0; c < 8; ++c) {
                    u16x8 kv = *(const u16x8*)&lds[ub + c * 8];
                    #pragma unroll
                    for (int j = 0; j < 8; ++j) dot += qf[c * 8 + j] * bf2f(kv[j]);
                }
                p[i] = dot * 0.125f;
                m = fmaxf(m, p[i]);
            } else {
                p[i] = -1e30f;
            }
        }
        float sum = 0.f;
        #pragma unroll
        for (int i = 0; i < 11; ++i) {
            int u = t - WIN_ + i;
            float e = (u >= 0 && u < 64) ? __expf(p[i] - m) : 0.f;
            p[i] = e;
            sum += e;
        }
        const float inv = 1.f / sum;
        float o[64];
        #pragma unroll
        for (int d = 0; d < 64; ++d) o[d] = 0.f;
        #pragma unroll
        for (int i = 0; i < 11; ++i) {
            int u = t - WIN_ + i;
            if (u >= 0 && u < 64) {
                const int ub = (slab * 64 + u) * PSTR + 128;
                float pv = p[i] * inv;
                #pragma unroll
                for (int c = 0; c < 8; ++c) {
                    u16x8 vv = *(const u16x8*)&lds[ub + c * 8];
                    #pragma unroll
                    for (int j = 0; j < 8; ++j) o[c * 8 + j] += pv * bf2f(vv[j]);
                }
            }
        }
        // pre-swizzled store at physical row rid; keys from s (gemm3 A layout)
        long rid = row0 + prow;
        int s = (int)(rid >> 6) & 1023;
        size_t rowbase = (size_t)rid * C_;
        const int cb  = (s >> 3) & 1;
        const int key = (s >> 1) & 3;
        #pragma unroll
        for (int c = 0; c < 8; ++c) {
            u16x8 w;
            #pragma unroll
            for (int j = 0; j < 8; ++j) w[j] = f2bf(o[c * 8 + j]);
            int off = (((2 * h + (c >> 2)) ^ cb) << 5) + (((c & 3) ^ key) << 3);
            *(u16x8*)&attn[rowbase + off] = w;
        }
    }
}

// ---------------------------------------------------------------------------
// 256x256 8-phase pipelined GEMM (r11-validated) — used for out = attn@W_out.
// ---------------------------------------------------------------------------
template<int NCOL, bool OUT_BF16, bool A_PERM>
__global__ __launch_bounds__(512, 2) void gemm8_k(const u16* __restrict__ Ap,
                                                  const u16* __restrict__ Bp,
                                                  void* __restrict__ Dp, int gx) {
    __shared__ u16 lds[65536];   // dbuf0{A,B} | dbuf1{A,B}, 16384 u16 each

    const int tid  = threadIdx.x;
    const int lane = tid & 63;
    const int wid  = tid >> 6;
    const int wm   = wid >> 2;
    const int wn   = wid & 3;
    const int fr   = lane & 15;
    const int g0   = lane >> 4;

    const int nwg = gridDim.x;
    const int q8  = nwg >> 3;
    const int bid = blockIdx.x;
    const int wg  = (bid & 7) * q8 + (bid >> 3);
    const int bx  = wg % gx;
    const int by  = wg / gx;
    const long row0 = (long)by * 256;
    const int  col0 = bx * 256;

    int aoffs[8], boffs[4];
    #pragma unroll
    for (int mf = 0; mf < 8; ++mf) {
        int lr = wm * 128 + mf * 16 + fr;
        aoffs[mf] = lr * 64 + (((lr >> 3) & 1) << 5) + (((g0 ^ (lr >> 1)) & 3) << 3);
    }
    #pragma unroll
    for (int nf = 0; nf < 4; ++nf) {
        int lc = wn * 64 + nf * 16 + fr;
        boffs[nf] = lc * 64 + (((lc >> 3) & 1) << 5) + (((g0 ^ (lc >> 1)) & 3) << 3);
    }

    const int srow = lane >> 3;
    const int scol = (lane & 7) * 8;

    long arow_phys[4];
    #pragma unroll
    for (int half = 0; half < 2; ++half)
        #pragma unroll
        for (int i = 0; i < 2; ++i) {
            int r = half * 128 + i * 64 + wid * 8 + srow;
            long grow = row0 + r;
            arow_phys[half * 2 + i] = A_PERM ? permute_row(grow) : grow;
        }

    auto stageA = [&](int tt, int half) {
        const int ab = (tt & 1) * 32768;
        #pragma unroll
        for (int i = 0; i < 2; ++i) {
            int r = half * 128 + i * 64 + wid * 8 + srow;
            const u16* g = Ap + arow_phys[half * 2 + i] * 512 + tt * 64 + scol;
            gload16(g, (void*)&lds[ab + r * 64]);
        }
    };
    auto stageB = [&](int tt, int half) {
        const int ab = (tt & 1) * 32768;
        #pragma unroll
        for (int i = 0; i < 2; ++i) {
            int r = half * 128 + i * 64 + wid * 8 + srow;
            const u16* g = Bp + (size_t)(col0 + r) * 512 + tt * 64 + scol;
            gload16(g, (void*)&lds[ab + 16384 + r * 64]);
        }
    };

    f32x4 acc[8][4] = {};

    stageA(0, 0); stageA(0, 1); stageB(0, 0); stageB(0, 1);
    stageB(1, 0); stageB(1, 1);
    asm volatile("s_waitcnt vmcnt(4)" ::: "memory");
    __builtin_amdgcn_sched_barrier(0);
    __builtin_amdgcn_s_barrier();

    #pragma unroll
    for (int t = 0; t < 8; ++t) {
        const int ab = (t & 1) * 32768;
        bf16x8 af0[8], af1[8], bf0[4], bf1[4];
        // phase 0
        #pragma unroll
        for (int mf = 0; mf < 4; ++mf) af0[mf] = LDF(ab + aoffs[mf]);
        #pragma unroll
        for (int nf = 0; nf < 4; ++nf) bf0[nf] = LDF(ab + 16384 + boffs[nf]);
        if (t <= 6) stageA(t + 1, 0);
        __builtin_amdgcn_s_barrier();
        asm volatile("s_waitcnt lgkmcnt(0)" ::: "memory");
        __builtin_amdgcn_sched_barrier(0);
        __builtin_amdgcn_s_setprio(1);
        #pragma unroll
        for (int mf = 0; mf < 4; ++mf) {
            MFMA16(acc[mf][0], af0[mf], bf0[0]);
            MFMA16(acc[mf][1], af0[mf], bf0[1]);
            MFMA16(acc[mf][2], af0[mf], bf0[2]);
            MFMA16(acc[mf][3], af0[mf], bf0[3]);
        }
        __builtin_amdgcn_s_setprio(0);
        __builtin_amdgcn_s_barrier();
        // phase 1
        #pragma unroll
        for (int mf = 4; mf < 8; ++mf) af0[mf] = LDF(ab + aoffs[mf]);
        #pragma unroll
        for (int nf = 0; nf < 4; ++nf) bf1[nf] = LDF(ab + 16384 + (boffs[nf] ^ 32));
        if (t <= 6) stageA(t + 1, 1);
        __builtin_amdgcn_s_barrier();
        asm volatile("s_waitcnt lgkmcnt(0)" ::: "memory");
        __builtin_amdgcn_sched_barrier(0);
        __builtin_amdgcn_s_setprio(1);
        #pragma unroll
        for (int mf = 4; mf < 8; ++mf) {
            MFMA16(acc[mf][0], af0[mf], bf0[0]);
            MFMA16(acc[mf][1], af0[mf], bf0[1]);
            MFMA16(acc[mf][2], af0[mf], bf0[2]);
            MFMA16(acc[mf][3], af0[mf], bf0[3]);
        }
        __builtin_amdgcn_s_setprio(0);
        __builtin_amdgcn_s_barrier();
        // phase 2
        #pragma unroll
        for (int mf = 0; mf < 4; ++mf) af1[mf] = LDF(ab + (aoffs[mf] ^ 32));
        if (t <= 5) stageB(t + 2, 0);
        __builtin_amdgcn_s_barrier();
        asm volatile("s_waitcnt lgkmcnt(0)" ::: "memory");
        __builtin_amdgcn_sched_barrier(0);
        __builtin_amdgcn_s_setprio(1);
        #pragma unroll
        for (int mf = 0; mf < 4; ++mf) {
            MFMA16(acc[mf][0], af1[mf], bf1[0]);
            MFMA16(acc[mf][1], af1[mf], bf1[1]);
            MFMA16(acc[mf][2], af1[mf], bf1[2]);
            MFMA16(acc[mf][3], af1[mf], bf1[3]);
        }
        __builtin_amdgcn_s_setprio(0);
        __builtin_amdgcn_s_barrier();
        // phase 3
        #pragma unroll
        for (int mf = 4; mf < 8; ++mf) af1[mf] = LDF(ab + (aoffs[mf] ^ 32));
        if (t <= 5) stageB(t + 2, 1);
        __builtin_amdgcn_s_barrier();
        asm volatile("s_waitcnt lgkmcnt(0)" ::: "memory");
        __builtin_amdgcn_sched_barrier(0);
        __builtin_amdgcn_s_setprio(1);
        #pragma unroll
        for (int mf = 4; mf < 8; ++mf) {
            MFMA16(acc[mf][0], af1[mf], bf1[0]);
            MFMA16(acc[mf][1], af1[mf], bf1[1]);
            MFMA16(acc[mf][2], af1[mf], bf1[2]);
            MFMA16(acc[mf][3], af1[mf], bf1[3]);
        }
        __builtin_amdgcn_s_setprio(0);
        if (t <= 5) {
            asm volatile("s_waitcnt vmcnt(4)" ::: "memory");
        } else if (t == 6) {
            asm volatile("s_waitcnt vmcnt(0)" ::: "memory");
        }
        __builtin_amdgcn_sched_barrier(0);
        __builtin_amdgcn_s_barrier();
    }

    #pragma unroll
    for (int mf = 0; mf < 8; ++mf) {
        #pragma unroll
        for (int nf = 0; nf < 4; ++nf) {
            #pragma unroll
            for (int r = 0; r < 4; ++r) {
                long grow = row0 + wm * 128 + mf * 16 + (lane >> 4) * 4 + r;
                int  gcol = col0 + wn * 64 + nf * 16 + fr;
                float v = acc[mf][nf][r];
                if constexpr (OUT_BF16) ((u16*)Dp)[grow * NCOL + gcol] = f2bf(v);
                else                    ((float*)Dp)[grow * NCOL + gcol] = v;
            }
        }
    }
}

// ---------------------------------------------------------------------------
extern "C" void kernel_launch(void* const* d_in, const int* in_sizes, int n_in,
                              void* d_out, int out_size, void* d_ws, size_t ws_size,
                              hipStream_t stream) {
    const float* x    = (const float*)d_in[0];   // (B, N, C) fp32
    const float* Wqkv = (const float*)d_in[1];   // (512, 1536) fp32
    const float* Wout = (const float*)d_in[2];   // (512, 512) fp32
    float* out = (float*)d_out;

    const size_t xc_elems = (size_t)M_ * C_;     // 67.1M u16
    // layout: xb | attn_buf | WqkvT2 | WoutT  (~272 MB total, no aliasing)
    u16* xb       = (u16*)d_ws;
    u16* attn_buf = xb + xc_elems;
    u16* WqkvT2   = attn_buf + xc_elems;
    u16* WoutT    = WqkvT2 + (size_t)1536 * 512;
    if (ws_size < ((size_t)(WoutT + (size_t)512 * 512) - (size_t)d_ws)) return;

    // 1) weight + activation prep
    prep_w2<<<(1536 * 64) / 256, 256, 0, stream>>>(Wqkv, WqkvT2);
    prep_w<<<(512 * 64) / 256, 256, 0, stream>>>(Wout, WoutT, 512);
    prep_x<<<8192, 256, 0, stream>>>(x, xb);

    // 2) fused qkv-GEMM + banded attention (no qkv round-trip)
    gemm_attn<<<4096, 512, 0, stream>>>(xb, WqkvT2, attn_buf);

    // 3) out = attn @ W_out
    gemm8_k<512, false, true><<<1024, 512, 0, stream>>>(attn_buf, WoutT, (void*)out, 2);
}

// Round 18
// 510.647 us; speedup vs baseline: 1.5798x; 1.0388x over previous
//
#include <hip/hip_runtime.h>
#include <stdint.h>

// Problem constants (fixed instance from setup_inputs)
#define B_   2
#define T_   64
#define S_   1024
#define C_   512
#define H_   8
#define N_   (T_ * S_)      // 65536
#define M_   (B_ * N_)      // 131072
#define WIN_ 5

typedef unsigned short u16;
typedef __bf16 bf16;
typedef __bf16 bf16x8 __attribute__((ext_vector_type(8)));
typedef float  f32x4  __attribute__((ext_vector_type(4)));
typedef u16    u16x8  __attribute__((ext_vector_type(8)));

static __device__ __forceinline__ u16 f2bf(float f) {
    return __builtin_bit_cast(u16, (bf16)f);   // RNE
}
static __device__ __forceinline__ float bf2f(u16 u) {
    return __builtin_bit_cast(float, (uint32_t)u << 16);
}
// async global->LDS, 16B per lane; LDS dest is wave-uniform base + lane*16
static __device__ __forceinline__ void gload16(const void* g, void* l) {
    __builtin_amdgcn_global_load_lds(
        (const __attribute__((address_space(1))) void*)g,
        (__attribute__((address_space(3))) void*)l, 16, 0, 0);
}
// row permutation: logical (b,t,s) flat row -> physical (b,s,t) flat row
static __device__ __forceinline__ long permute_row(long grow) {
    int b = (int)(grow >> 16);
    int t = (int)(grow >> 10) & 63;
    int s = (int)grow & 1023;
    return ((long)((b << 10) | s)) * 64 + t;
}

// Pre-swizzle layout (bf16 [row][512] operands): logical (chunk c in [0,16),
// granule g in [0,4), elem j) stored at
// r*512 + (c ^ ((rl>>3)&1))*32 + ((g ^ ((rl>>1)&3))<<3) + j,
// keys from the TILE-LOCAL row rl (only bits 1-3 of r used, so any tile size
// that's a multiple of 16 gives identical keys). 0 conflicts measured.

// ---------------------------------------------------------------------------
// Wout prep: W [512][512] fp32 -> WT [512][512] bf16, pre-swizzled.
// ---------------------------------------------------------------------------
__global__ __launch_bounds__(256) void prep_w(const float* __restrict__ W,
                                              u16* __restrict__ WT, int NCOL) {
    int id = blockIdx.x * 256 + threadIdx.x;
    int n  = id % NCOL;
    int gi = id / NCOL;
    int chunk = gi >> 2;
    int g     = gi & 3;
    int k0 = chunk * 32 + g * 8;
    int cs = chunk ^ ((n >> 3) & 1);
    int gs = g ^ ((n >> 1) & 3);
    u16x8 w;
    #pragma unroll
    for (int j = 0; j < 8; ++j) w[j] = f2bf(W[(size_t)(k0 + j) * NCOL + n]);
    *(u16x8*)&WT[(size_t)n * 512 + cs * 32 + gs * 8] = w;
}

// ---------------------------------------------------------------------------
// Wqkv prep, head-grouped: W [512][1536] fp32, col n = which*512 + h*64 + d
// -> WT2 row n' = h*192 + which*64 + d, bf16, pre-swizzled with keys from the
// PANEL-LOCAL row which*64+d.
// ---------------------------------------------------------------------------
__global__ __launch_bounds__(256) void prep_w2(const float* __restrict__ W,
                                               u16* __restrict__ WT2) {
    int id = blockIdx.x * 256 + threadIdx.x;
    int n  = id % 1536;
    int gi = id / 1536;
    int chunk = gi >> 2;
    int g     = gi & 3;
    int k0 = chunk * 32 + g * 8;
    int which = n >> 9;
    int h     = (n >> 6) & 7;
    int d     = n & 63;
    int rloc  = which * 64 + d;          // 0..191 panel-local row
    long np   = h * 192 + rloc;
    int cs = chunk ^ ((rloc >> 3) & 1);
    int gs = g ^ ((rloc >> 1) & 3);
    u16x8 w;
    #pragma unroll
    for (int j = 0; j < 8; ++j) w[j] = f2bf(W[(size_t)(k0 + j) * 1536 + n]);
    *(u16x8*)&WT2[(size_t)np * 512 + cs * 32 + gs * 8] = w;
}

// ---------------------------------------------------------------------------
// x prep: x [M][512] fp32 (rows (b,t,s)) -> xb bf16 rows PERMUTED to (b,s,t),
// pre-swizzled with keys from the permuted row index.
// ---------------------------------------------------------------------------
__global__ __launch_bounds__(256) void prep_x(const float* __restrict__ x,
                                              u16* __restrict__ xb) {
    const size_t total = (size_t)M_ * 64;   // 16B granules
    for (size_t id = (size_t)blockIdx.x * 256 + threadIdx.x; id < total;
         id += (size_t)gridDim.x * 256) {
        long r_in = (long)(id >> 6);
        int  gi   = (int)(id & 63);
        int chunk = gi >> 2;
        int g     = gi & 3;
        long rid  = permute_row(r_in);
        int cb  = (int)(rid >> 3) & 1;
        int key = (int)(rid >> 1) & 3;
        const float* src = x + r_in * 512 + chunk * 32 + g * 8;
        f32x4 v0 = *(const f32x4*)(src);
        f32x4 v1 = *(const f32x4*)(src + 4);
        u16x8 w;
        #pragma unroll
        for (int j = 0; j < 4; ++j) { w[j] = f2bf(v0[j]); w[4 + j] = f2bf(v1[j]); }
        *(u16x8*)&xb[(size_t)rid * 512 + (chunk ^ cb) * 32 + ((g ^ key) << 3)] = w;
    }
}

#define LDF(off) __builtin_bit_cast(bf16x8, *(const u16x8*)&lds[(off)])
#define MFMA16(d, a, b) d = __builtin_amdgcn_mfma_f32_16x16x32_bf16(a, b, d, 0, 0, 0)

#define PSTR 200   // panel row stride (u16): pad keeps reads bank-bijective

// ---------------------------------------------------------------------------
// FUSED qkv-GEMM + banded attention, 128-ROW TILES for 2 blocks/CU.
// Grid 8192: bid = q*64 + h*8 + x; rowtile = q*8 + x (0..1023), head=(bid>>3)&7.
// XCD = bid%8 = rowtile%8 -> all 8 heads of a rowtile back-to-back on one XCD
// (window: 8 rowtiles x 128KB A + 1.5MB B < 4MB L2).
// Block: 128 rows (2 (b,s) slabs) x 192 cols; 8 waves = 2 wm x 4 wn
// (wave = 64 rows x 48 cols, 4 mf x 3 nf). LDS = A dbuf 2x16KB + B dbuf
// 2x24KB = 80KB EXACTLY -> 2 blocks/CU: one block's attention epilogue
// overlaps the other's K-loop (m114), hiding the serial tail.
// Per K-tile t, 3 phases:
//   ph0: read af0(4)+bf0(3); stageA(t+1,0..1) [2]; bar; lgkm0; 12 MFMA kk0; bar
//   ph1: read af1(4)+bf1(3);                       bar; lgkm0; 12 MFMA kk1; bar
//   ph2: stageB(t+2) [3] (AFTER ph1's lgkm+bar retired ALL waves' B(t) reads
//        — r11's WAR rule); vmcnt(3); bar
// vmem ledger/tile: issue [sA(t+1)x2 @ph0, sB(t+2)x3 @ph2]; steady-state
// outstanding entering ph0 = sB(t+1)x3; vmcnt(3) at ph2 retires sA(t+1) and
// sB(t+1), keeps sB(t+2) in flight (never 0 mid-loop). Guards: stageA t<=6,
// stageB t<=5, vmcnt(0) at t==6, no ph2 at t==7.
// Epilogue: acc -> LDS panel [128][PSTR] bf16 linear; barrier; waves 0-1 run
// per-slab banded attention; store pre-swizzled rows for gemm3.
// ---------------------------------------------------------------------------
__global__ __launch_bounds__(512, 4) void gemm_attn(const u16* __restrict__ Ap,
                                                    const u16* __restrict__ Bp,
                                                    u16* __restrict__ attn) {
    __shared__ u16 lds[40960];   // A0@0 A1@8192 B0@16384 B1@28672 (u16 units)

    const int tid  = threadIdx.x;
    const int lane = tid & 63;
    const int wid  = tid >> 6;    // 0..7
    const int wm   = wid >> 2;    // 0..1
    const int wn   = wid & 3;     // 0..3
    const int fr   = lane & 15;
    const int g0   = lane >> 4;

    const int rowtile = ((blockIdx.x >> 6) << 3) | (blockIdx.x & 7);  // 0..1023
    const int h       = (blockIdx.x >> 3) & 7;
    const long row0   = (long)rowtile * 128;

    // frag LDS offsets (u16, rel. to buffer base), kk=0; kk=1 = ^32
    int aoffs[4], boffs[3];
    #pragma unroll
    for (int mf = 0; mf < 4; ++mf) {
        int lr = wm * 64 + mf * 16 + fr;          // 0..127
        aoffs[mf] = lr * 64 + (((lr >> 3) & 1) << 5) + (((g0 ^ (lr >> 1)) & 3) << 3);
    }
    #pragma unroll
    for (int nf = 0; nf < 3; ++nf) {
        int lc = wn * 48 + nf * 16 + fr;          // 0..191
        boffs[nf] = lc * 64 + (((lc >> 3) & 1) << 5) + (((g0 ^ (lc >> 1)) & 3) << 3);
    }

    const int srow = lane >> 3;        // 0..7
    const int scol = (lane & 7) * 8;   // u16 offset within 128B row window

    auto stageA = [&](int tt, int half) {       // 64 rows per half, 1 issue
        const int ab = (tt & 1) * 8192;
        int r = half * 64 + wid * 8 + srow;     // 0..127
        const u16* g = Ap + (row0 + r) * 512 + tt * 64 + scol;
        gload16(g, (void*)&lds[ab + r * 64]);
    };
    auto stageB = [&](int tt) {                 // 192 rows, 3 issues
        const int bb = 16384 + (tt & 1) * 12288;
        #pragma unroll
        for (int i = 0; i < 3; ++i) {
            int r = i * 64 + wid * 8 + srow;    // 0..191
            const u16* g = Bp + (size_t)(h * 192 + r) * 512 + tt * 64 + scol;
            gload16(g, (void*)&lds[bb + r * 64]);
        }
    };

    f32x4 acc[4][3] = {};

    // ---- prologue: [A0x2, B0x3, B1x3]; vmcnt(3) -> A0,B0 landed, B1 in flight
    stageA(0, 0); stageA(0, 1); stageB(0); stageB(1);
    asm volatile("s_waitcnt vmcnt(3)" ::: "memory");
    __builtin_amdgcn_sched_barrier(0);
    __builtin_amdgcn_s_barrier();

    #pragma unroll
    for (int t = 0; t < 8; ++t) {
        const int ab = (t & 1) * 8192;
        const int bb = 16384 + (t & 1) * 12288;
        bf16x8 af[4], bfv[3];
        // ================= phase 0: kk0 =================
        #pragma unroll
        for (int mf = 0; mf < 4; ++mf) af[mf] = LDF(ab + aoffs[mf]);
        #pragma unroll
        for (int nf = 0; nf < 3; ++nf) bfv[nf] = LDF(bb + boffs[nf]);
        if (t <= 6) { stageA(t + 1, 0); stageA(t + 1, 1); }
        __builtin_amdgcn_s_barrier();
        asm volatile("s_waitcnt lgkmcnt(0)" ::: "memory");
        __builtin_amdgcn_sched_barrier(0);
        __builtin_amdgcn_s_setprio(1);
        #pragma unroll
        for (int mf = 0; mf < 4; ++mf) {
            MFMA16(acc[mf][0], af[mf], bfv[0]);
            MFMA16(acc[mf][1], af[mf], bfv[1]);
            MFMA16(acc[mf][2], af[mf], bfv[2]);
        }
        __builtin_amdgcn_s_setprio(0);
        __builtin_amdgcn_s_barrier();
        // ================= phase 1: kk1 =================
        #pragma unroll
        for (int mf = 0; mf < 4; ++mf) af[mf] = LDF(ab + (aoffs[mf] ^ 32));
        #pragma unroll
        for (int nf = 0; nf < 3; ++nf) bfv[nf] = LDF(bb + (boffs[nf] ^ 32));
        __builtin_amdgcn_s_barrier();
        asm volatile("s_waitcnt lgkmcnt(0)" ::: "memory");
        __builtin_amdgcn_sched_barrier(0);
        __builtin_amdgcn_s_setprio(1);
        #pragma unroll
        for (int mf = 0; mf < 4; ++mf) {
            MFMA16(acc[mf][0], af[mf], bfv[0]);
            MFMA16(acc[mf][1], af[mf], bfv[1]);
            MFMA16(acc[mf][2], af[mf], bfv[2]);
        }
        __builtin_amdgcn_s_setprio(0);
        __builtin_amdgcn_s_barrier();
        // ================= phase 2: B prefetch (all B(t) reads retired) =====
        if (t <= 6) {
            if (t <= 5) {
                stageB(t + 2);
                asm volatile("s_waitcnt vmcnt(3)" ::: "memory");
            } else {
                asm volatile("s_waitcnt vmcnt(0)" ::: "memory");   // A7,B7 landed
            }
            __builtin_amdgcn_sched_barrier(0);
            __builtin_amdgcn_s_barrier();
        }
    }

    // ---- epilogue: acc -> LDS panel [128][PSTR] bf16, linear cols ----
    __builtin_amdgcn_sched_barrier(0);
    #pragma unroll
    for (int mf = 0; mf < 4; ++mf) {
        #pragma unroll
        for (int nf = 0; nf < 3; ++nf) {
            #pragma unroll
            for (int r = 0; r < 4; ++r) {
                int row = wm * 64 + mf * 16 + (lane >> 4) * 4 + r;
                int col = wn * 48 + nf * 16 + fr;
                lds[row * PSTR + col] = f2bf(acc[mf][nf][r]);
            }
        }
    }
    __syncthreads();

    // ---- banded attention: waves 0-1, one (b,s) slab each ----
    if (wid < 2) {
        const int slab = wid;
        const int t = lane;
        const int prow = slab * 64 + t;
        float qf[64];
        #pragma unroll
        for (int c = 0; c < 8; ++c) {
            u16x8 v = *(const u16x8*)&lds[prow * PSTR + c * 8];
            #pragma unroll
            for (int j = 0; j < 8; ++j) qf[c * 8 + j] = bf2f(v[j]);
        }
        float p[11];
        float m = -1e30f;
        #pragma unroll
        for (int i = 0; i < 11; ++i) {
            int u = t - WIN_ + i;
            if (u >= 0 && u < 64) {
                const int ub = (slab * 64 + u) * PSTR + 64;
                float dot = 0.f;
                #pragma unroll
                for (int c = 0; c < 8; ++c) {
                    u16x8 kv = *(const u16x8*)&lds[ub + c * 8];
                    #pragma unroll
                    for (int j = 0; j < 8; ++j) dot += qf[c * 8 + j] * bf2f(kv[j]);
                }
                p[i] = dot * 0.125f;
                m = fmaxf(m, p[i]);
            } else {
                p[i] = -1e30f;
            }
        }
        float sum = 0.f;
        #pragma unroll
        for (int i = 0; i < 11; ++i) {
            int u = t - WIN_ + i;
            float e = (u >= 0 && u < 64) ? __expf(p[i] - m) : 0.f;
            p[i] = e;
            sum += e;
        }
        const float inv = 1.f / sum;
        float o[64];
        #pragma unroll
        for (int d = 0; d < 64; ++d) o[d] = 0.f;
        #pragma unroll
        for (int i = 0; i < 11; ++i) {
            int u = t - WIN_ + i;
            if (u >= 0 && u < 64) {
                const int ub = (slab * 64 + u) * PSTR + 128;
                float pv = p[i] * inv;
                #pragma unroll
                for (int c = 0; c < 8; ++c) {
                    u16x8 vv = *(const u16x8*)&lds[ub + c * 8];
                    #pragma unroll
                    for (int j = 0; j < 8; ++j) o[c * 8 + j] += pv * bf2f(vv[j]);
                }
            }
        }
        // pre-swizzled store at physical row rid; keys from s (gemm3 A layout)
        long rid = row0 + prow;
        int s = (int)(rid >> 6) & 1023;
        size_t rowbase = (size_t)rid * C_;
        const int cb  = (s >> 3) & 1;
        const int key = (s >> 1) & 3;
        #pragma unroll
        for (int c = 0; c < 8; ++c) {
            u16x8 w;
            #pragma unroll
            for (int j = 0; j < 8; ++j) w[j] = f2bf(o[c * 8 + j]);
            int off = (((2 * h + (c >> 2)) ^ cb) << 5) + (((c & 3) ^ key) << 3);
            *(u16x8*)&attn[rowbase + off] = w;
        }
    }
}

// ---------------------------------------------------------------------------
// 256x256 8-phase pipelined GEMM (r11-validated) — used for out = attn@W_out.
// ---------------------------------------------------------------------------
template<int NCOL, bool OUT_BF16, bool A_PERM>
__global__ __launch_bounds__(512, 2) void gemm8_k(const u16* __restrict__ Ap,
                                                  const u16* __restrict__ Bp,
                                                  void* __restrict__ Dp, int gx) {
    __shared__ u16 lds[65536];   // dbuf0{A,B} | dbuf1{A,B}, 16384 u16 each

    const int tid  = threadIdx.x;
    const int lane = tid & 63;
    const int wid  = tid >> 6;
    const int wm   = wid >> 2;
    const int wn   = wid & 3;
    const int fr   = lane & 15;
    const int g0   = lane >> 4;

    const int nwg = gridDim.x;
    const int q8  = nwg >> 3;
    const int bid = blockIdx.x;
    const int wg  = (bid & 7) * q8 + (bid >> 3);
    const int bx  = wg % gx;
    const int by  = wg / gx;
    const long row0 = (long)by * 256;
    const int  col0 = bx * 256;

    int aoffs[8], boffs[4];
    #pragma unroll
    for (int mf = 0; mf < 8; ++mf) {
        int lr = wm * 128 + mf * 16 + fr;
        aoffs[mf] = lr * 64 + (((lr >> 3) & 1) << 5) + (((g0 ^ (lr >> 1)) & 3) << 3);
    }
    #pragma unroll
    for (int nf = 0; nf < 4; ++nf) {
        int lc = wn * 64 + nf * 16 + fr;
        boffs[nf] = lc * 64 + (((lc >> 3) & 1) << 5) + (((g0 ^ (lc >> 1)) & 3) << 3);
    }

    const int srow = lane >> 3;
    const int scol = (lane & 7) * 8;

    long arow_phys[4];
    #pragma unroll
    for (int half = 0; half < 2; ++half)
        #pragma unroll
        for (int i = 0; i < 2; ++i) {
            int r = half * 128 + i * 64 + wid * 8 + srow;
            long grow = row0 + r;
            arow_phys[half * 2 + i] = A_PERM ? permute_row(grow) : grow;
        }

    auto stageA = [&](int tt, int half) {
        const int ab = (tt & 1) * 32768;
        #pragma unroll
        for (int i = 0; i < 2; ++i) {
            int r = half * 128 + i * 64 + wid * 8 + srow;
            const u16* g = Ap + arow_phys[half * 2 + i] * 512 + tt * 64 + scol;
            gload16(g, (void*)&lds[ab + r * 64]);
        }
    };
    auto stageB = [&](int tt, int half) {
        const int ab = (tt & 1) * 32768;
        #pragma unroll
        for (int i = 0; i < 2; ++i) {
            int r = half * 128 + i * 64 + wid * 8 + srow;
            const u16* g = Bp + (size_t)(col0 + r) * 512 + tt * 64 + scol;
            gload16(g, (void*)&lds[ab + 16384 + r * 64]);
        }
    };

    f32x4 acc[8][4] = {};

    stageA(0, 0); stageA(0, 1); stageB(0, 0); stageB(0, 1);
    stageB(1, 0); stageB(1, 1);
    asm volatile("s_waitcnt vmcnt(4)" ::: "memory");
    __builtin_amdgcn_sched_barrier(0);
    __builtin_amdgcn_s_barrier();

    #pragma unroll
    for (int t = 0; t < 8; ++t) {
        const int ab = (t & 1) * 32768;
        bf16x8 af0[8], af1[8], bf0[4], bf1[4];
        // phase 0
        #pragma unroll
        for (int mf = 0; mf < 4; ++mf) af0[mf] = LDF(ab + aoffs[mf]);
        #pragma unroll
        for (int nf = 0; nf < 4; ++nf) bf0[nf] = LDF(ab + 16384 + boffs[nf]);
        if (t <= 6) stageA(t + 1, 0);
        __builtin_amdgcn_s_barrier();
        asm volatile("s_waitcnt lgkmcnt(0)" ::: "memory");
        __builtin_amdgcn_sched_barrier(0);
        __builtin_amdgcn_s_setprio(1);
        #pragma unroll
        for (int mf = 0; mf < 4; ++mf) {
            MFMA16(acc[mf][0], af0[mf], bf0[0]);
            MFMA16(acc[mf][1], af0[mf], bf0[1]);
            MFMA16(acc[mf][2], af0[mf], bf0[2]);
            MFMA16(acc[mf][3], af0[mf], bf0[3]);
        }
        __builtin_amdgcn_s_setprio(0);
        __builtin_amdgcn_s_barrier();
        // phase 1
        #pragma unroll
        for (int mf = 4; mf < 8; ++mf) af0[mf] = LDF(ab + aoffs[mf]);
        #pragma unroll
        for (int nf = 0; nf < 4; ++nf) bf1[nf] = LDF(ab + 16384 + (boffs[nf] ^ 32));
        if (t <= 6) stageA(t + 1, 1);
        __builtin_amdgcn_s_barrier();
        asm volatile("s_waitcnt lgkmcnt(0)" ::: "memory");
        __builtin_amdgcn_sched_barrier(0);
        __builtin_amdgcn_s_setprio(1);
        #pragma unroll
        for (int mf = 4; mf < 8; ++mf) {
            MFMA16(acc[mf][0], af0[mf], bf0[0]);
            MFMA16(acc[mf][1], af0[mf], bf0[1]);
            MFMA16(acc[mf][2], af0[mf], bf0[2]);
            MFMA16(acc[mf][3], af0[mf], bf0[3]);
        }
        __builtin_amdgcn_s_setprio(0);
        __builtin_amdgcn_s_barrier();
        // phase 2
        #pragma unroll
        for (int mf = 0; mf < 4; ++mf) af1[mf] = LDF(ab + (aoffs[mf] ^ 32));
        if (t <= 5) stageB(t + 2, 0);
        __builtin_amdgcn_s_barrier();
        asm volatile("s_waitcnt lgkmcnt(0)" ::: "memory");
        __builtin_amdgcn_sched_barrier(0);
        __builtin_amdgcn_s_setprio(1);
        #pragma unroll
        for (int mf = 0; mf < 4; ++mf) {
            MFMA16(acc[mf][0], af1[mf], bf1[0]);
            MFMA16(acc[mf][1], af1[mf], bf1[1]);
            MFMA16(acc[mf][2], af1[mf], bf1[2]);
            MFMA16(acc[mf][3], af1[mf], bf1[3]);
        }
        __builtin_amdgcn_s_setprio(0);
        __builtin_amdgcn_s_barrier();
        // phase 3
        #pragma unroll
        for (int mf = 4; mf < 8; ++mf) af1[mf] = LDF(ab + (aoffs[mf] ^ 32));
        if (t <= 5) stageB(t + 2, 1);
        __builtin_amdgcn_s_barrier();
        asm volatile("s_waitcnt lgkmcnt(0)" ::: "memory");
        __builtin_amdgcn_sched_barrier(0);
        __builtin_amdgcn_s_setprio(1);
        #pragma unroll
        for (int mf = 4; mf < 8; ++mf) {
            MFMA16(acc[mf][0], af1[mf], bf1[0]);
            MFMA16(acc[mf][1], af1[mf], bf1[1]);
            MFMA16(acc[mf][2], af1[mf], bf1[2]);
            MFMA16(acc[mf][3], af1[mf], bf1[3]);
        }
        __builtin_amdgcn_s_setprio(0);
        if (t <= 5) {
            asm volatile("s_waitcnt vmcnt(4)" ::: "memory");
        } else if (t == 6) {
            asm volatile("s_waitcnt vmcnt(0)" ::: "memory");
        }
        __builtin_amdgcn_sched_barrier(0);
        __builtin_amdgcn_s_barrier();
    }

    #pragma unroll
    for (int mf = 0; mf < 8; ++mf) {
        #pragma unroll
        for (int nf = 0; nf < 4; ++nf) {
            #pragma unroll
            for (int r = 0; r < 4; ++r) {
                long grow = row0 + wm * 128 + mf * 16 + (lane >> 4) * 4 + r;
                int  gcol = col0 + wn * 64 + nf * 16 + fr;
                float v = acc[mf][nf][r];
                if constexpr (OUT_BF16) ((u16*)Dp)[grow * NCOL + gcol] = f2bf(v);
                else                    ((float*)Dp)[grow * NCOL + gcol] = v;
            }
        }
    }
}

// ---------------------------------------------------------------------------
extern "C" void kernel_launch(void* const* d_in, const int* in_sizes, int n_in,
                              void* d_out, int out_size, void* d_ws, size_t ws_size,
                              hipStream_t stream) {
    const float* x    = (const float*)d_in[0];   // (B, N, C) fp32
    const float* Wqkv = (const float*)d_in[1];   // (512, 1536) fp32
    const float* Wout = (const float*)d_in[2];   // (512, 512) fp32
    float* out = (float*)d_out;

    const size_t xc_elems = (size_t)M_ * C_;     // 67.1M u16
    // layout: xb | attn_buf | WqkvT2 | WoutT  (~272 MB total, no aliasing)
    u16* xb       = (u16*)d_ws;
    u16* attn_buf = xb + xc_elems;
    u16* WqkvT2   = attn_buf + xc_elems;
    u16* WoutT    = WqkvT2 + (size_t)1536 * 512;
    if (ws_size < ((size_t)(WoutT + (size_t)512 * 512) - (size_t)d_ws)) return;

    // 1) weight + activation prep
    prep_w2<<<(1536 * 64) / 256, 256, 0, stream>>>(Wqkv, WqkvT2);
    prep_w<<<(512 * 64) / 256, 256, 0, stream>>>(Wout, WoutT, 512);
    prep_x<<<8192, 256, 0, stream>>>(x, xb);

    // 2) fused qkv-GEMM + banded attention (128-row tiles, 2 blocks/CU)
    gemm_attn<<<8192, 512, 0, stream>>>(xb, WqkvT2, attn_buf);

    // 3) out = attn @ W_out
    gemm8_k<512, false, true><<<1024, 512, 0, stream>>>(attn_buf, WoutT, (void*)out, 2);
}

// Round 19
// 485.444 us; speedup vs baseline: 1.6618x; 1.0519x over previous
//
#include <hip/hip_runtime.h>
#include <stdint.h>

// Problem constants (fixed instance from setup_inputs)
#define B_   2
#define T_   64
#define S_   1024
#define C_   512
#define H_   8
#define N_   (T_ * S_)      // 65536
#define M_   (B_ * N_)      // 131072
#define WIN_ 5

typedef unsigned short u16;
typedef __bf16 bf16;
typedef __bf16 bf16x8 __attribute__((ext_vector_type(8)));
typedef float  f32x4  __attribute__((ext_vector_type(4)));
typedef u16    u16x8  __attribute__((ext_vector_type(8)));

static __device__ __forceinline__ u16 f2bf(float f) {
    return __builtin_bit_cast(u16, (bf16)f);   // RNE
}
static __device__ __forceinline__ float bf2f(u16 u) {
    return __builtin_bit_cast(float, (uint32_t)u << 16);
}
// async global->LDS, 16B per lane; LDS dest is wave-uniform base + lane*16
static __device__ __forceinline__ void gload16(const void* g, void* l) {
    __builtin_amdgcn_global_load_lds(
        (const __attribute__((address_space(1))) void*)g,
        (__attribute__((address_space(3))) void*)l, 16, 0, 0);
}
// row permutation: logical (b,t,s) flat row -> physical (b,s,t) flat row
static __device__ __forceinline__ long permute_row(long grow) {
    int b = (int)(grow >> 16);
    int t = (int)(grow >> 10) & 63;
    int s = (int)grow & 1023;
    return ((long)((b << 10) | s)) * 64 + t;
}

// Pre-swizzle layout (bf16 [row][512] operands): logical (chunk c in [0,16),
// granule g in [0,4), elem j) stored at
// r*512 + (c ^ ((rl>>3)&1))*32 + ((g ^ ((rl>>1)&3))<<3) + j,
// keys from the TILE-LOCAL row rl. 0 conflicts measured.

// ---------------------------------------------------------------------------
// Wout prep: W [512][512] fp32 -> WT [512][512] bf16, pre-swizzled.
// ---------------------------------------------------------------------------
__global__ __launch_bounds__(256) void prep_w(const float* __restrict__ W,
                                              u16* __restrict__ WT, int NCOL) {
    int id = blockIdx.x * 256 + threadIdx.x;
    int n  = id % NCOL;
    int gi = id / NCOL;
    int chunk = gi >> 2;
    int g     = gi & 3;
    int k0 = chunk * 32 + g * 8;
    int cs = chunk ^ ((n >> 3) & 1);
    int gs = g ^ ((n >> 1) & 3);
    u16x8 w;
    #pragma unroll
    for (int j = 0; j < 8; ++j) w[j] = f2bf(W[(size_t)(k0 + j) * NCOL + n]);
    *(u16x8*)&WT[(size_t)n * 512 + cs * 32 + gs * 8] = w;
}

// ---------------------------------------------------------------------------
// Wqkv prep, head-grouped: W [512][1536] fp32, col n = which*512 + h*64 + d
// -> WT2 row n' = h*192 + which*64 + d, bf16, pre-swizzled with keys from the
// PANEL-LOCAL row which*64+d.
// ---------------------------------------------------------------------------
__global__ __launch_bounds__(256) void prep_w2(const float* __restrict__ W,
                                               u16* __restrict__ WT2) {
    int id = blockIdx.x * 256 + threadIdx.x;
    int n  = id % 1536;
    int gi = id / 1536;
    int chunk = gi >> 2;
    int g     = gi & 3;
    int k0 = chunk * 32 + g * 8;
    int which = n >> 9;
    int h     = (n >> 6) & 7;
    int d     = n & 63;
    int rloc  = which * 64 + d;          // 0..191 panel-local row
    long np   = h * 192 + rloc;
    int cs = chunk ^ ((rloc >> 3) & 1);
    int gs = g ^ ((rloc >> 1) & 3);
    u16x8 w;
    #pragma unroll
    for (int j = 0; j < 8; ++j) w[j] = f2bf(W[(size_t)(k0 + j) * 1536 + n]);
    *(u16x8*)&WT2[(size_t)np * 512 + cs * 32 + gs * 8] = w;
}

// ---------------------------------------------------------------------------
// x prep: x [M][512] fp32 (rows (b,t,s)) -> xb bf16 rows PERMUTED to (b,s,t),
// pre-swizzled with keys from the permuted row index.
// ---------------------------------------------------------------------------
__global__ __launch_bounds__(256) void prep_x(const float* __restrict__ x,
                                              u16* __restrict__ xb) {
    const size_t total = (size_t)M_ * 64;   // 16B granules
    for (size_t id = (size_t)blockIdx.x * 256 + threadIdx.x; id < total;
         id += (size_t)gridDim.x * 256) {
        long r_in = (long)(id >> 6);
        int  gi   = (int)(id & 63);
        int chunk = gi >> 2;
        int g     = gi & 3;
        long rid  = permute_row(r_in);
        int cb  = (int)(rid >> 3) & 1;
        int key = (int)(rid >> 1) & 3;
        const float* src = x + r_in * 512 + chunk * 32 + g * 8;
        f32x4 v0 = *(const f32x4*)(src);
        f32x4 v1 = *(const f32x4*)(src + 4);
        u16x8 w;
        #pragma unroll
        for (int j = 0; j < 4; ++j) { w[j] = f2bf(v0[j]); w[4 + j] = f2bf(v1[j]); }
        *(u16x8*)&xb[(size_t)rid * 512 + (chunk ^ cb) * 32 + ((g ^ key) << 3)] = w;
    }
}

#define LDF(off) __builtin_bit_cast(bf16x8, *(const u16x8*)&lds[(off)])
#define MFMA16(d, a, b) d = __builtin_amdgcn_mfma_f32_16x16x32_bf16(a, b, d, 0, 0, 0)

#define PSTR 200   // panel row stride (u16): pad keeps reads bank-bijective

// ---------------------------------------------------------------------------
// FUSED qkv-GEMM + banded attention, 128-row tiles, 2 blocks/CU (r18 base).
// K-loop unchanged from r18 (validated). Epilogue now uses ALL 8 WAVES:
// wave = (slab = wid>>2, d-quarter q = wid&3); each wave computes QK PARTIAL
// dots over its 16 d-channels, writes [row][i][q] f32 partials to LDS scratch
// (22.5KB @ u16 offset 25600, beside the 51.2KB panel; 73.7KB < 80KB budget),
// barrier, every thread reduces its row's 11x4 partials (f32x4 reads) +
// softmax, then PV for its own 16 output channels and stores 2 pre-swizzled
// 16B chunks. Invalid band offsets re-masked locally (zero partials must not
// enter softmax).
// ---------------------------------------------------------------------------
__global__ __launch_bounds__(512, 4) void gemm_attn(const u16* __restrict__ Ap,
                                                    const u16* __restrict__ Bp,
                                                    u16* __restrict__ attn) {
    __shared__ u16 lds[40960];   // A0@0 A1@8192 B0@16384 B1@28672 (u16 units)

    const int tid  = threadIdx.x;
    const int lane = tid & 63;
    const int wid  = tid >> 6;    // 0..7
    const int wm   = wid >> 2;    // 0..1
    const int wn   = wid & 3;     // 0..3
    const int fr   = lane & 15;
    const int g0   = lane >> 4;

    const int rowtile = ((blockIdx.x >> 6) << 3) | (blockIdx.x & 7);  // 0..1023
    const int h       = (blockIdx.x >> 3) & 7;
    const long row0   = (long)rowtile * 128;

    // frag LDS offsets (u16, rel. to buffer base), kk=0; kk=1 = ^32
    int aoffs[4], boffs[3];
    #pragma unroll
    for (int mf = 0; mf < 4; ++mf) {
        int lr = wm * 64 + mf * 16 + fr;          // 0..127
        aoffs[mf] = lr * 64 + (((lr >> 3) & 1) << 5) + (((g0 ^ (lr >> 1)) & 3) << 3);
    }
    #pragma unroll
    for (int nf = 0; nf < 3; ++nf) {
        int lc = wn * 48 + nf * 16 + fr;          // 0..191
        boffs[nf] = lc * 64 + (((lc >> 3) & 1) << 5) + (((g0 ^ (lc >> 1)) & 3) << 3);
    }

    const int srow = lane >> 3;        // 0..7
    const int scol = (lane & 7) * 8;   // u16 offset within 128B row window

    auto stageA = [&](int tt, int half) {       // 64 rows per half, 1 issue
        const int ab = (tt & 1) * 8192;
        int r = half * 64 + wid * 8 + srow;     // 0..127
        const u16* g = Ap + (row0 + r) * 512 + tt * 64 + scol;
        gload16(g, (void*)&lds[ab + r * 64]);
    };
    auto stageB = [&](int tt) {                 // 192 rows, 3 issues
        const int bb = 16384 + (tt & 1) * 12288;
        #pragma unroll
        for (int i = 0; i < 3; ++i) {
            int r = i * 64 + wid * 8 + srow;    // 0..191
            const u16* g = Bp + (size_t)(h * 192 + r) * 512 + tt * 64 + scol;
            gload16(g, (void*)&lds[bb + r * 64]);
        }
    };

    f32x4 acc[4][3] = {};

    // ---- prologue: [A0x2, B0x3, B1x3]; vmcnt(3) -> A0,B0 landed, B1 in flight
    stageA(0, 0); stageA(0, 1); stageB(0); stageB(1);
    asm volatile("s_waitcnt vmcnt(3)" ::: "memory");
    __builtin_amdgcn_sched_barrier(0);
    __builtin_amdgcn_s_barrier();

    #pragma unroll
    for (int t = 0; t < 8; ++t) {
        const int ab = (t & 1) * 8192;
        const int bb = 16384 + (t & 1) * 12288;
        bf16x8 af[4], bfv[3];
        // ================= phase 0: kk0 =================
        #pragma unroll
        for (int mf = 0; mf < 4; ++mf) af[mf] = LDF(ab + aoffs[mf]);
        #pragma unroll
        for (int nf = 0; nf < 3; ++nf) bfv[nf] = LDF(bb + boffs[nf]);
        if (t <= 6) { stageA(t + 1, 0); stageA(t + 1, 1); }
        __builtin_amdgcn_s_barrier();
        asm volatile("s_waitcnt lgkmcnt(0)" ::: "memory");
        __builtin_amdgcn_sched_barrier(0);
        __builtin_amdgcn_s_setprio(1);
        #pragma unroll
        for (int mf = 0; mf < 4; ++mf) {
            MFMA16(acc[mf][0], af[mf], bfv[0]);
            MFMA16(acc[mf][1], af[mf], bfv[1]);
            MFMA16(acc[mf][2], af[mf], bfv[2]);
        }
        __builtin_amdgcn_s_setprio(0);
        __builtin_amdgcn_s_barrier();
        // ================= phase 1: kk1 =================
        #pragma unroll
        for (int mf = 0; mf < 4; ++mf) af[mf] = LDF(ab + (aoffs[mf] ^ 32));
        #pragma unroll
        for (int nf = 0; nf < 3; ++nf) bfv[nf] = LDF(bb + (boffs[nf] ^ 32));
        __builtin_amdgcn_s_barrier();
        asm volatile("s_waitcnt lgkmcnt(0)" ::: "memory");
        __builtin_amdgcn_sched_barrier(0);
        __builtin_amdgcn_s_setprio(1);
        #pragma unroll
        for (int mf = 0; mf < 4; ++mf) {
            MFMA16(acc[mf][0], af[mf], bfv[0]);
            MFMA16(acc[mf][1], af[mf], bfv[1]);
            MFMA16(acc[mf][2], af[mf], bfv[2]);
        }
        __builtin_amdgcn_s_setprio(0);
        __builtin_amdgcn_s_barrier();
        // ================= phase 2: B prefetch (all B(t) reads retired) =====
        if (t <= 6) {
            if (t <= 5) {
                stageB(t + 2);
                asm volatile("s_waitcnt vmcnt(3)" ::: "memory");
            } else {
                asm volatile("s_waitcnt vmcnt(0)" ::: "memory");   // A7,B7 landed
            }
            __builtin_amdgcn_sched_barrier(0);
            __builtin_amdgcn_s_barrier();
        }
    }

    // ---- epilogue: acc -> LDS panel [128][PSTR] bf16, linear cols ----
    __builtin_amdgcn_sched_barrier(0);
    #pragma unroll
    for (int mf = 0; mf < 4; ++mf) {
        #pragma unroll
        for (int nf = 0; nf < 3; ++nf) {
            #pragma unroll
            for (int r = 0; r < 4; ++r) {
                int row = wm * 64 + mf * 16 + (lane >> 4) * 4 + r;
                int col = wn * 48 + nf * 16 + fr;
                lds[row * PSTR + col] = f2bf(acc[mf][nf][r]);
            }
        }
    }
    __syncthreads();

    // ---- 8-wave banded attention: wave = (slab = wid>>2, d-quarter q) ----
    {
        const int slab = wid >> 2;      // 0..1
        const int q    = wid & 3;       // 0..3 (16-channel quarter)
        const int t    = lane;
        const int prow = slab * 64 + t;
        float* scr = (float*)&lds[25600];   // [128 rows][11 i][4 q] f32

        // Q quarter (16 channels) into regs
        float qf[16];
        #pragma unroll
        for (int cc = 0; cc < 2; ++cc) {
            u16x8 v = *(const u16x8*)&lds[prow * PSTR + (q * 2 + cc) * 8];
            #pragma unroll
            for (int j = 0; j < 8; ++j) qf[cc * 8 + j] = bf2f(v[j]);
        }
        // partial QK dots over this quarter
        #pragma unroll
        for (int i = 0; i < 11; ++i) {
            int u = t - WIN_ + i;
            float dot = 0.f;
            if (u >= 0 && u < 64) {
                const int ub = (slab * 64 + u) * PSTR + 64;
                #pragma unroll
                for (int cc = 0; cc < 2; ++cc) {
                    u16x8 kv = *(const u16x8*)&lds[ub + (q * 2 + cc) * 8];
                    #pragma unroll
                    for (int j = 0; j < 8; ++j) dot += qf[cc * 8 + j] * bf2f(kv[j]);
                }
            }
            scr[(prow * 11 + i) * 4 + q] = dot;
        }
        __syncthreads();

        // reduce partials + softmax (every thread, own row)
        float p[11];
        float m = -1e30f;
        #pragma unroll
        for (int i = 0; i < 11; ++i) {
            int u = t - WIN_ + i;
            if (u >= 0 && u < 64) {
                f32x4 v = *(const f32x4*)&scr[(prow * 11 + i) * 4];
                p[i] = (v[0] + v[1] + v[2] + v[3]) * 0.125f;
                m = fmaxf(m, p[i]);
            } else {
                p[i] = -1e30f;
            }
        }
        float sum = 0.f;
        #pragma unroll
        for (int i = 0; i < 11; ++i) {
            int u = t - WIN_ + i;
            float e = (u >= 0 && u < 64) ? __expf(p[i] - m) : 0.f;
            p[i] = e;
            sum += e;
        }
        const float inv = 1.f / sum;

        // PV for this quarter's 16 output channels
        float o[16];
        #pragma unroll
        for (int d = 0; d < 16; ++d) o[d] = 0.f;
        #pragma unroll
        for (int i = 0; i < 11; ++i) {
            int u = t - WIN_ + i;
            if (u >= 0 && u < 64) {
                const int ub = (slab * 64 + u) * PSTR + 128;
                float pv = p[i] * inv;
                #pragma unroll
                for (int cc = 0; cc < 2; ++cc) {
                    u16x8 vv = *(const u16x8*)&lds[ub + (q * 2 + cc) * 8];
                    #pragma unroll
                    for (int j = 0; j < 8; ++j) o[cc * 8 + j] += pv * bf2f(vv[j]);
                }
            }
        }
        // pre-swizzled store (2 chunks c = 2q, 2q+1); keys from s (gemm3 A)
        long rid = row0 + prow;
        int s = (int)(rid >> 6) & 1023;
        size_t rowbase = (size_t)rid * C_;
        const int cb  = (s >> 3) & 1;
        const int key = (s >> 1) & 3;
        #pragma unroll
        for (int cc = 0; cc < 2; ++cc) {
            int c = q * 2 + cc;
            u16x8 w;
            #pragma unroll
            for (int j = 0; j < 8; ++j) w[j] = f2bf(o[cc * 8 + j]);
            int off = (((2 * h + (c >> 2)) ^ cb) << 5) + (((c & 3) ^ key) << 3);
            *(u16x8*)&attn[rowbase + off] = w;
        }
    }
}

// ---------------------------------------------------------------------------
// 256x256 8-phase pipelined GEMM (r11-validated) — used for out = attn@W_out.
// ---------------------------------------------------------------------------
template<int NCOL, bool OUT_BF16, bool A_PERM>
__global__ __launch_bounds__(512, 2) void gemm8_k(const u16* __restrict__ Ap,
                                                  const u16* __restrict__ Bp,
                                                  void* __restrict__ Dp, int gx) {
    __shared__ u16 lds[65536];   // dbuf0{A,B} | dbuf1{A,B}, 16384 u16 each

    const int tid  = threadIdx.x;
    const int lane = tid & 63;
    const int wid  = tid >> 6;
    const int wm   = wid >> 2;
    const int wn   = wid & 3;
    const int fr   = lane & 15;
    const int g0   = lane >> 4;

    const int nwg = gridDim.x;
    const int q8  = nwg >> 3;
    const int bid = blockIdx.x;
    const int wg  = (bid & 7) * q8 + (bid >> 3);
    const int bx  = wg % gx;
    const int by  = wg / gx;
    const long row0 = (long)by * 256;
    const int  col0 = bx * 256;

    int aoffs[8], boffs[4];
    #pragma unroll
    for (int mf = 0; mf < 8; ++mf) {
        int lr = wm * 128 + mf * 16 + fr;
        aoffs[mf] = lr * 64 + (((lr >> 3) & 1) << 5) + (((g0 ^ (lr >> 1)) & 3) << 3);
    }
    #pragma unroll
    for (int nf = 0; nf < 4; ++nf) {
        int lc = wn * 64 + nf * 16 + fr;
        boffs[nf] = lc * 64 + (((lc >> 3) & 1) << 5) + (((g0 ^ (lc >> 1)) & 3) << 3);
    }

    const int srow = lane >> 3;
    const int scol = (lane & 7) * 8;

    long arow_phys[4];
    #pragma unroll
    for (int half = 0; half < 2; ++half)
        #pragma unroll
        for (int i = 0; i < 2; ++i) {
            int r = half * 128 + i * 64 + wid * 8 + srow;
            long grow = row0 + r;
            arow_phys[half * 2 + i] = A_PERM ? permute_row(grow) : grow;
        }

    auto stageA = [&](int tt, int half) {
        const int ab = (tt & 1) * 32768;
        #pragma unroll
        for (int i = 0; i < 2; ++i) {
            int r = half * 128 + i * 64 + wid * 8 + srow;
            const u16* g = Ap + arow_phys[half * 2 + i] * 512 + tt * 64 + scol;
            gload16(g, (void*)&lds[ab + r * 64]);
        }
    };
    auto stageB = [&](int tt, int half) {
        const int ab = (tt & 1) * 32768;
        #pragma unroll
        for (int i = 0; i < 2; ++i) {
            int r = half * 128 + i * 64 + wid * 8 + srow;
            const u16* g = Bp + (size_t)(col0 + r) * 512 + tt * 64 + scol;
            gload16(g, (void*)&lds[ab + 16384 + r * 64]);
        }
    };

    f32x4 acc[8][4] = {};

    stageA(0, 0); stageA(0, 1); stageB(0, 0); stageB(0, 1);
    stageB(1, 0); stageB(1, 1);
    asm volatile("s_waitcnt vmcnt(4)" ::: "memory");
    __builtin_amdgcn_sched_barrier(0);
    __builtin_amdgcn_s_barrier();

    #pragma unroll
    for (int t = 0; t < 8; ++t) {
        const int ab = (t & 1) * 32768;
        bf16x8 af0[8], af1[8], bf0[4], bf1[4];
        // phase 0
        #pragma unroll
        for (int mf = 0; mf < 4; ++mf) af0[mf] = LDF(ab + aoffs[mf]);
        #pragma unroll
        for (int nf = 0; nf < 4; ++nf) bf0[nf] = LDF(ab + 16384 + boffs[nf]);
        if (t <= 6) stageA(t + 1, 0);
        __builtin_amdgcn_s_barrier();
        asm volatile("s_waitcnt lgkmcnt(0)" ::: "memory");
        __builtin_amdgcn_sched_barrier(0);
        __builtin_amdgcn_s_setprio(1);
        #pragma unroll
        for (int mf = 0; mf < 4; ++mf) {
            MFMA16(acc[mf][0], af0[mf], bf0[0]);
            MFMA16(acc[mf][1], af0[mf], bf0[1]);
            MFMA16(acc[mf][2], af0[mf], bf0[2]);
            MFMA16(acc[mf][3], af0[mf], bf0[3]);
        }
        __builtin_amdgcn_s_setprio(0);
        __builtin_amdgcn_s_barrier();
        // phase 1
        #pragma unroll
        for (int mf = 4; mf < 8; ++mf) af0[mf] = LDF(ab + aoffs[mf]);
        #pragma unroll
        for (int nf = 0; nf < 4; ++nf) bf1[nf] = LDF(ab + 16384 + (boffs[nf] ^ 32));
        if (t <= 6) stageA(t + 1, 1);
        __builtin_amdgcn_s_barrier();
        asm volatile("s_waitcnt lgkmcnt(0)" ::: "memory");
        __builtin_amdgcn_sched_barrier(0);
        __builtin_amdgcn_s_setprio(1);
        #pragma unroll
        for (int mf = 4; mf < 8; ++mf) {
            MFMA16(acc[mf][0], af0[mf], bf0[0]);
            MFMA16(acc[mf][1], af0[mf], bf0[1]);
            MFMA16(acc[mf][2], af0[mf], bf0[2]);
            MFMA16(acc[mf][3], af0[mf], bf0[3]);
        }
        __builtin_amdgcn_s_setprio(0);
        __builtin_amdgcn_s_barrier();
        // phase 2
        #pragma unroll
        for (int mf = 0; mf < 4; ++mf) af1[mf] = LDF(ab + (aoffs[mf] ^ 32));
        if (t <= 5) stageB(t + 2, 0);
        __builtin_amdgcn_s_barrier();
        asm volatile("s_waitcnt lgkmcnt(0)" ::: "memory");
        __builtin_amdgcn_sched_barrier(0);
        __builtin_amdgcn_s_setprio(1);
        #pragma unroll
        for (int mf = 0; mf < 4; ++mf) {
            MFMA16(acc[mf][0], af1[mf], bf1[0]);
            MFMA16(acc[mf][1], af1[mf], bf1[1]);
            MFMA16(acc[mf][2], af1[mf], bf1[2]);
            MFMA16(acc[mf][3], af1[mf], bf1[3]);
        }
        __builtin_amdgcn_s_setprio(0);
        __builtin_amdgcn_s_barrier();
        // phase 3
        #pragma unroll
        for (int mf = 4; mf < 8; ++mf) af1[mf] = LDF(ab + (aoffs[mf] ^ 32));
        if (t <= 5) stageB(t + 2, 1);
        __builtin_amdgcn_s_barrier();
        asm volatile("s_waitcnt lgkmcnt(0)" ::: "memory");
        __builtin_amdgcn_sched_barrier(0);
        __builtin_amdgcn_s_setprio(1);
        #pragma unroll
        for (int mf = 4; mf < 8; ++mf) {
            MFMA16(acc[mf][0], af1[mf], bf1[0]);
            MFMA16(acc[mf][1], af1[mf], bf1[1]);
            MFMA16(acc[mf][2], af1[mf], bf1[2]);
            MFMA16(acc[mf][3], af1[mf], bf1[3]);
        }
        __builtin_amdgcn_s_setprio(0);
        if (t <= 5) {
            asm volatile("s_waitcnt vmcnt(4)" ::: "memory");
        } else if (t == 6) {
            asm volatile("s_waitcnt vmcnt(0)" ::: "memory");
        }
        __builtin_amdgcn_sched_barrier(0);
        __builtin_amdgcn_s_barrier();
    }

    #pragma unroll
    for (int mf = 0; mf < 8; ++mf) {
        #pragma unroll
        for (int nf = 0; nf < 4; ++nf) {
            #pragma unroll
            for (int r = 0; r < 4; ++r) {
                long grow = row0 + wm * 128 + mf * 16 + (lane >> 4) * 4 + r;
                int  gcol = col0 + wn * 64 + nf * 16 + fr;
                float v = acc[mf][nf][r];
                if constexpr (OUT_BF16) ((u16*)Dp)[grow * NCOL + gcol] = f2bf(v);
                else                    ((float*)Dp)[grow * NCOL + gcol] = v;
            }
        }
    }
}

// ---------------------------------------------------------------------------
extern "C" void kernel_launch(void* const* d_in, const int* in_sizes, int n_in,
                              void* d_out, int out_size, void* d_ws, size_t ws_size,
                              hipStream_t stream) {
    const float* x    = (const float*)d_in[0];   // (B, N, C) fp32
    const float* Wqkv = (const float*)d_in[1];   // (512, 1536) fp32
    const float* Wout = (const float*)d_in[2];   // (512, 512) fp32
    float* out = (float*)d_out;

    const size_t xc_elems = (size_t)M_ * C_;     // 67.1M u16
    // layout: xb | attn_buf | WqkvT2 | WoutT  (~272 MB total, no aliasing)
    u16* xb       = (u16*)d_ws;
    u16* attn_buf = xb + xc_elems;
    u16* WqkvT2   = attn_buf + xc_elems;
    u16* WoutT    = WqkvT2 + (size_t)1536 * 512;
    if (ws_size < ((size_t)(WoutT + (size_t)512 * 512) - (size_t)d_ws)) return;

    // 1) weight + activation prep
    prep_w2<<<(1536 * 64) / 256, 256, 0, stream>>>(Wqkv, WqkvT2);
    prep_w<<<(512 * 64) / 256, 256, 0, stream>>>(Wout, WoutT, 512);
    prep_x<<<8192, 256, 0, stream>>>(x, xb);

    // 2) fused qkv-GEMM + banded attention (128-row tiles, 2 blocks/CU,
    //    8-wave epilogue)
    gemm_attn<<<8192, 512, 0, stream>>>(xb, WqkvT2, attn_buf);

    // 3) out = attn @ W_out
    gemm8_k<512, false, true><<<1024, 512, 0, stream>>>(attn_buf, WoutT, (void*)out, 2);
}

// Round 20
// 484.872 us; speedup vs baseline: 1.6638x; 1.0012x over previous
//
#include <hip/hip_runtime.h>
#include <stdint.h>

// Problem constants (fixed instance from setup_inputs)
#define B_   2
#define T_   64
#define S_   1024
#define C_   512
#define H_   8
#define N_   (T_ * S_)      // 65536
#define M_   (B_ * N_)      // 131072
#define WIN_ 5

typedef unsigned short u16;
typedef __bf16 bf16;
typedef __bf16 bf16x8 __attribute__((ext_vector_type(8)));
typedef float  f32x4  __attribute__((ext_vector_type(4)));
typedef u16    u16x8  __attribute__((ext_vector_type(8)));

static __device__ __forceinline__ u16 f2bf(float f) {
    return __builtin_bit_cast(u16, (bf16)f);   // RNE
}
static __device__ __forceinline__ float bf2f(u16 u) {
    return __builtin_bit_cast(float, (uint32_t)u << 16);
}
// async global->LDS, 16B per lane; LDS dest is wave-uniform base + lane*16
static __device__ __forceinline__ void gload16(const void* g, void* l) {
    __builtin_amdgcn_global_load_lds(
        (const __attribute__((address_space(1))) void*)g,
        (__attribute__((address_space(3))) void*)l, 16, 0, 0);
}
// row permutation: logical (b,t,s) flat row -> physical (b,s,t) flat row
static __device__ __forceinline__ long permute_row(long grow) {
    int b = (int)(grow >> 16);
    int t = (int)(grow >> 10) & 63;
    int s = (int)grow & 1023;
    return ((long)((b << 10) | s)) * 64 + t;
}

// Pre-swizzle layout (bf16 [row][512] operands): logical (chunk c in [0,16),
// granule g in [0,4), elem j) stored at
// r*512 + (c ^ ((rl>>3)&1))*32 + ((g ^ ((rl>>1)&3))<<3) + j,
// keys from the TILE-LOCAL row rl. 0 conflicts measured.

// ---------------------------------------------------------------------------
// Wout prep: W [512][512] fp32 -> WT [512][512] bf16, pre-swizzled.
// ---------------------------------------------------------------------------
__global__ __launch_bounds__(256) void prep_w(const float* __restrict__ W,
                                              u16* __restrict__ WT, int NCOL) {
    int id = blockIdx.x * 256 + threadIdx.x;
    int n  = id % NCOL;
    int gi = id / NCOL;
    int chunk = gi >> 2;
    int g     = gi & 3;
    int k0 = chunk * 32 + g * 8;
    int cs = chunk ^ ((n >> 3) & 1);
    int gs = g ^ ((n >> 1) & 3);
    u16x8 w;
    #pragma unroll
    for (int j = 0; j < 8; ++j) w[j] = f2bf(W[(size_t)(k0 + j) * NCOL + n]);
    *(u16x8*)&WT[(size_t)n * 512 + cs * 32 + gs * 8] = w;
}

// ---------------------------------------------------------------------------
// Wqkv prep, head-grouped: W [512][1536] fp32, col n = which*512 + h*64 + d
// -> WT2 row n' = h*192 + which*64 + d, bf16, pre-swizzled with keys from the
// PANEL-LOCAL row which*64+d.
// ---------------------------------------------------------------------------
__global__ __launch_bounds__(256) void prep_w2(const float* __restrict__ W,
                                               u16* __restrict__ WT2) {
    int id = blockIdx.x * 256 + threadIdx.x;
    int n  = id % 1536;
    int gi = id / 1536;
    int chunk = gi >> 2;
    int g     = gi & 3;
    int k0 = chunk * 32 + g * 8;
    int which = n >> 9;
    int h     = (n >> 6) & 7;
    int d     = n & 63;
    int rloc  = which * 64 + d;          // 0..191 panel-local row
    long np   = h * 192 + rloc;
    int cs = chunk ^ ((rloc >> 3) & 1);
    int gs = g ^ ((rloc >> 1) & 3);
    u16x8 w;
    #pragma unroll
    for (int j = 0; j < 8; ++j) w[j] = f2bf(W[(size_t)(k0 + j) * 1536 + n]);
    *(u16x8*)&WT2[(size_t)np * 512 + cs * 32 + gs * 8] = w;
}

// ---------------------------------------------------------------------------
// x prep: x [M][512] fp32 (rows (b,t,s)) -> xb bf16 rows PERMUTED to (b,s,t),
// pre-swizzled with keys from the permuted row index.
// ---------------------------------------------------------------------------
__global__ __launch_bounds__(256) void prep_x(const float* __restrict__ x,
                                              u16* __restrict__ xb) {
    const size_t total = (size_t)M_ * 64;   // 16B granules
    for (size_t id = (size_t)blockIdx.x * 256 + threadIdx.x; id < total;
         id += (size_t)gridDim.x * 256) {
        long r_in = (long)(id >> 6);
        int  gi   = (int)(id & 63);
        int chunk = gi >> 2;
        int g     = gi & 3;
        long rid  = permute_row(r_in);
        int cb  = (int)(rid >> 3) & 1;
        int key = (int)(rid >> 1) & 3;
        const float* src = x + r_in * 512 + chunk * 32 + g * 8;
        f32x4 v0 = *(const f32x4*)(src);
        f32x4 v1 = *(const f32x4*)(src + 4);
        u16x8 w;
        #pragma unroll
        for (int j = 0; j < 4; ++j) { w[j] = f2bf(v0[j]); w[4 + j] = f2bf(v1[j]); }
        *(u16x8*)&xb[(size_t)rid * 512 + (chunk ^ cb) * 32 + ((g ^ key) << 3)] = w;
    }
}

#define LDF(off) __builtin_bit_cast(bf16x8, *(const u16x8*)&lds[(off)])
#define MFMA16(d, a, b) d = __builtin_amdgcn_mfma_f32_16x16x32_bf16(a, b, d, 0, 0, 0)

#define PSTR 200   // panel row stride (u16): pad keeps reads bank-bijective

// ---------------------------------------------------------------------------
// FUSED qkv-GEMM + banded attention, 128-row tiles, 2 blocks/CU (r18 base).
// K-loop unchanged (validated). 8-wave epilogue (r19) with CONFLICT-FREE
// scratch: partials stored TRANSPOSED scr[(i*4+q)][128] so both the partial
// writes and the scalar reduce reads put consecutive lanes in consecutive
// dwords (r19's [row][i][q] layout had stride 44 -> 8-way conflicts, 4.3M).
// ---------------------------------------------------------------------------
__global__ __launch_bounds__(512, 4) void gemm_attn(const u16* __restrict__ Ap,
                                                    const u16* __restrict__ Bp,
                                                    u16* __restrict__ attn) {
    __shared__ u16 lds[40960];   // A0@0 A1@8192 B0@16384 B1@28672 (u16 units)

    const int tid  = threadIdx.x;
    const int lane = tid & 63;
    const int wid  = tid >> 6;    // 0..7
    const int wm   = wid >> 2;    // 0..1
    const int wn   = wid & 3;     // 0..3
    const int fr   = lane & 15;
    const int g0   = lane >> 4;

    const int rowtile = ((blockIdx.x >> 6) << 3) | (blockIdx.x & 7);  // 0..1023
    const int h       = (blockIdx.x >> 3) & 7;
    const long row0   = (long)rowtile * 128;

    // frag LDS offsets (u16, rel. to buffer base), kk=0; kk=1 = ^32
    int aoffs[4], boffs[3];
    #pragma unroll
    for (int mf = 0; mf < 4; ++mf) {
        int lr = wm * 64 + mf * 16 + fr;          // 0..127
        aoffs[mf] = lr * 64 + (((lr >> 3) & 1) << 5) + (((g0 ^ (lr >> 1)) & 3) << 3);
    }
    #pragma unroll
    for (int nf = 0; nf < 3; ++nf) {
        int lc = wn * 48 + nf * 16 + fr;          // 0..191
        boffs[nf] = lc * 64 + (((lc >> 3) & 1) << 5) + (((g0 ^ (lc >> 1)) & 3) << 3);
    }

    const int srow = lane >> 3;        // 0..7
    const int scol = (lane & 7) * 8;   // u16 offset within 128B row window

    auto stageA = [&](int tt, int half) {       // 64 rows per half, 1 issue
        const int ab = (tt & 1) * 8192;
        int r = half * 64 + wid * 8 + srow;     // 0..127
        const u16* g = Ap + (row0 + r) * 512 + tt * 64 + scol;
        gload16(g, (void*)&lds[ab + r * 64]);
    };
    auto stageB = [&](int tt) {                 // 192 rows, 3 issues
        const int bb = 16384 + (tt & 1) * 12288;
        #pragma unroll
        for (int i = 0; i < 3; ++i) {
            int r = i * 64 + wid * 8 + srow;    // 0..191
            const u16* g = Bp + (size_t)(h * 192 + r) * 512 + tt * 64 + scol;
            gload16(g, (void*)&lds[bb + r * 64]);
        }
    };

    f32x4 acc[4][3] = {};

    // ---- prologue: [A0x2, B0x3, B1x3]; vmcnt(3) -> A0,B0 landed, B1 in flight
    stageA(0, 0); stageA(0, 1); stageB(0); stageB(1);
    asm volatile("s_waitcnt vmcnt(3)" ::: "memory");
    __builtin_amdgcn_sched_barrier(0);
    __builtin_amdgcn_s_barrier();

    #pragma unroll
    for (int t = 0; t < 8; ++t) {
        const int ab = (t & 1) * 8192;
        const int bb = 16384 + (t & 1) * 12288;
        bf16x8 af[4], bfv[3];
        // ================= phase 0: kk0 =================
        #pragma unroll
        for (int mf = 0; mf < 4; ++mf) af[mf] = LDF(ab + aoffs[mf]);
        #pragma unroll
        for (int nf = 0; nf < 3; ++nf) bfv[nf] = LDF(bb + boffs[nf]);
        if (t <= 6) { stageA(t + 1, 0); stageA(t + 1, 1); }
        __builtin_amdgcn_s_barrier();
        asm volatile("s_waitcnt lgkmcnt(0)" ::: "memory");
        __builtin_amdgcn_sched_barrier(0);
        __builtin_amdgcn_s_setprio(1);
        #pragma unroll
        for (int mf = 0; mf < 4; ++mf) {
            MFMA16(acc[mf][0], af[mf], bfv[0]);
            MFMA16(acc[mf][1], af[mf], bfv[1]);
            MFMA16(acc[mf][2], af[mf], bfv[2]);
        }
        __builtin_amdgcn_s_setprio(0);
        __builtin_amdgcn_s_barrier();
        // ================= phase 1: kk1 =================
        #pragma unroll
        for (int mf = 0; mf < 4; ++mf) af[mf] = LDF(ab + (aoffs[mf] ^ 32));
        #pragma unroll
        for (int nf = 0; nf < 3; ++nf) bfv[nf] = LDF(bb + (boffs[nf] ^ 32));
        __builtin_amdgcn_s_barrier();
        asm volatile("s_waitcnt lgkmcnt(0)" ::: "memory");
        __builtin_amdgcn_sched_barrier(0);
        __builtin_amdgcn_s_setprio(1);
        #pragma unroll
        for (int mf = 0; mf < 4; ++mf) {
            MFMA16(acc[mf][0], af[mf], bfv[0]);
            MFMA16(acc[mf][1], af[mf], bfv[1]);
            MFMA16(acc[mf][2], af[mf], bfv[2]);
        }
        __builtin_amdgcn_s_setprio(0);
        __builtin_amdgcn_s_barrier();
        // ================= phase 2: B prefetch (all B(t) reads retired) =====
        if (t <= 6) {
            if (t <= 5) {
                stageB(t + 2);
                asm volatile("s_waitcnt vmcnt(3)" ::: "memory");
            } else {
                asm volatile("s_waitcnt vmcnt(0)" ::: "memory");   // A7,B7 landed
            }
            __builtin_amdgcn_sched_barrier(0);
            __builtin_amdgcn_s_barrier();
        }
    }

    // ---- epilogue: acc -> LDS panel [128][PSTR] bf16, linear cols ----
    __builtin_amdgcn_sched_barrier(0);
    #pragma unroll
    for (int mf = 0; mf < 4; ++mf) {
        #pragma unroll
        for (int nf = 0; nf < 3; ++nf) {
            #pragma unroll
            for (int r = 0; r < 4; ++r) {
                int row = wm * 64 + mf * 16 + (lane >> 4) * 4 + r;
                int col = wn * 48 + nf * 16 + fr;
                lds[row * PSTR + col] = f2bf(acc[mf][nf][r]);
            }
        }
    }
    __syncthreads();

    // ---- 8-wave banded attention: wave = (slab = wid>>2, d-quarter q) ----
    {
        const int slab = wid >> 2;      // 0..1
        const int q    = wid & 3;       // 0..3 (16-channel quarter)
        const int t    = lane;
        const int prow = slab * 64 + t;
        float* scr = (float*)&lds[25600];   // [44 = i*4+q][128 rows] f32

        // Q quarter (16 channels) into regs
        float qf[16];
        #pragma unroll
        for (int cc = 0; cc < 2; ++cc) {
            u16x8 v = *(const u16x8*)&lds[prow * PSTR + (q * 2 + cc) * 8];
            #pragma unroll
            for (int j = 0; j < 8; ++j) qf[cc * 8 + j] = bf2f(v[j]);
        }
        // partial QK dots over this quarter -> transposed scratch (conflict-free)
        #pragma unroll
        for (int i = 0; i < 11; ++i) {
            int u = t - WIN_ + i;
            float dot = 0.f;
            if (u >= 0 && u < 64) {
                const int ub = (slab * 64 + u) * PSTR + 64;
                #pragma unroll
                for (int cc = 0; cc < 2; ++cc) {
                    u16x8 kv = *(const u16x8*)&lds[ub + (q * 2 + cc) * 8];
                    #pragma unroll
                    for (int j = 0; j < 8; ++j) dot += qf[cc * 8 + j] * bf2f(kv[j]);
                }
            }
            scr[(i * 4 + q) * 128 + prow] = dot;
        }
        __syncthreads();

        // reduce partials + softmax (every thread, own row; scalar reads are
        // consecutive-lane -> conflict-free)
        float p[11];
        float m = -1e30f;
        #pragma unroll
        for (int i = 0; i < 11; ++i) {
            int u = t - WIN_ + i;
            if (u >= 0 && u < 64) {
                float d0 = scr[(i * 4 + 0) * 128 + prow];
                float d1 = scr[(i * 4 + 1) * 128 + prow];
                float d2 = scr[(i * 4 + 2) * 128 + prow];
                float d3 = scr[(i * 4 + 3) * 128 + prow];
                p[i] = (d0 + d1 + d2 + d3) * 0.125f;
                m = fmaxf(m, p[i]);
            } else {
                p[i] = -1e30f;
            }
        }
        float sum = 0.f;
        #pragma unroll
        for (int i = 0; i < 11; ++i) {
            int u = t - WIN_ + i;
            float e = (u >= 0 && u < 64) ? __expf(p[i] - m) : 0.f;
            p[i] = e;
            sum += e;
        }
        const float inv = 1.f / sum;

        // PV for this quarter's 16 output channels
        float o[16];
        #pragma unroll
        for (int d = 0; d < 16; ++d) o[d] = 0.f;
        #pragma unroll
        for (int i = 0; i < 11; ++i) {
            int u = t - WIN_ + i;
            if (u >= 0 && u < 64) {
                const int ub = (slab * 64 + u) * PSTR + 128;
                float pv = p[i] * inv;
                #pragma unroll
                for (int cc = 0; cc < 2; ++cc) {
                    u16x8 vv = *(const u16x8*)&lds[ub + (q * 2 + cc) * 8];
                    #pragma unroll
                    for (int j = 0; j < 8; ++j) o[cc * 8 + j] += pv * bf2f(vv[j]);
                }
            }
        }
        // pre-swizzled store (2 chunks c = 2q, 2q+1); keys from s (gemm3 A)
        long rid = row0 + prow;
        int s = (int)(rid >> 6) & 1023;
        size_t rowbase = (size_t)rid * C_;
        const int cb  = (s >> 3) & 1;
        const int key = (s >> 1) & 3;
        #pragma unroll
        for (int cc = 0; cc < 2; ++cc) {
            int c = q * 2 + cc;
            u16x8 w;
            #pragma unroll
            for (int j = 0; j < 8; ++j) w[j] = f2bf(o[cc * 8 + j]);
            int off = (((2 * h + (c >> 2)) ^ cb) << 5) + (((c & 3) ^ key) << 3);
            *(u16x8*)&attn[rowbase + off] = w;
        }
    }
}

// ---------------------------------------------------------------------------
// 256x256 8-phase pipelined GEMM (r11-validated) — used for out = attn@W_out.
// ---------------------------------------------------------------------------
template<int NCOL, bool OUT_BF16, bool A_PERM>
__global__ __launch_bounds__(512, 2) void gemm8_k(const u16* __restrict__ Ap,
                                                  const u16* __restrict__ Bp,
                                                  void* __restrict__ Dp, int gx) {
    __shared__ u16 lds[65536];   // dbuf0{A,B} | dbuf1{A,B}, 16384 u16 each

    const int tid  = threadIdx.x;
    const int lane = tid & 63;
    const int wid  = tid >> 6;
    const int wm   = wid >> 2;
    const int wn   = wid & 3;
    const int fr   = lane & 15;
    const int g0   = lane >> 4;

    const int nwg = gridDim.x;
    const int q8  = nwg >> 3;
    const int bid = blockIdx.x;
    const int wg  = (bid & 7) * q8 + (bid >> 3);
    const int bx  = wg % gx;
    const int by  = wg / gx;
    const long row0 = (long)by * 256;
    const int  col0 = bx * 256;

    int aoffs[8], boffs[4];
    #pragma unroll
    for (int mf = 0; mf < 8; ++mf) {
        int lr = wm * 128 + mf * 16 + fr;
        aoffs[mf] = lr * 64 + (((lr >> 3) & 1) << 5) + (((g0 ^ (lr >> 1)) & 3) << 3);
    }
    #pragma unroll
    for (int nf = 0; nf < 4; ++nf) {
        int lc = wn * 64 + nf * 16 + fr;
        boffs[nf] = lc * 64 + (((lc >> 3) & 1) << 5) + (((g0 ^ (lc >> 1)) & 3) << 3);
    }

    const int srow = lane >> 3;
    const int scol = (lane & 7) * 8;

    long arow_phys[4];
    #pragma unroll
    for (int half = 0; half < 2; ++half)
        #pragma unroll
        for (int i = 0; i < 2; ++i) {
            int r = half * 128 + i * 64 + wid * 8 + srow;
            long grow = row0 + r;
            arow_phys[half * 2 + i] = A_PERM ? permute_row(grow) : grow;
        }

    auto stageA = [&](int tt, int half) {
        const int ab = (tt & 1) * 32768;
        #pragma unroll
        for (int i = 0; i < 2; ++i) {
            int r = half * 128 + i * 64 + wid * 8 + srow;
            const u16* g = Ap + arow_phys[half * 2 + i] * 512 + tt * 64 + scol;
            gload16(g, (void*)&lds[ab + r * 64]);
        }
    };
    auto stageB = [&](int tt, int half) {
        const int ab = (tt & 1) * 32768;
        #pragma unroll
        for (int i = 0; i < 2; ++i) {
            int r = half * 128 + i * 64 + wid * 8 + srow;
            const u16* g = Bp + (size_t)(col0 + r) * 512 + tt * 64 + scol;
            gload16(g, (void*)&lds[ab + 16384 + r * 64]);
        }
    };

    f32x4 acc[8][4] = {};

    stageA(0, 0); stageA(0, 1); stageB(0, 0); stageB(0, 1);
    stageB(1, 0); stageB(1, 1);
    asm volatile("s_waitcnt vmcnt(4)" ::: "memory");
    __builtin_amdgcn_sched_barrier(0);
    __builtin_amdgcn_s_barrier();

    #pragma unroll
    for (int t = 0; t < 8; ++t) {
        const int ab = (t & 1) * 32768;
        bf16x8 af0[8], af1[8], bf0[4], bf1[4];
        // phase 0
        #pragma unroll
        for (int mf = 0; mf < 4; ++mf) af0[mf] = LDF(ab + aoffs[mf]);
        #pragma unroll
        for (int nf = 0; nf < 4; ++nf) bf0[nf] = LDF(ab + 16384 + boffs[nf]);
        if (t <= 6) stageA(t + 1, 0);
        __builtin_amdgcn_s_barrier();
        asm volatile("s_waitcnt lgkmcnt(0)" ::: "memory");
        __builtin_amdgcn_sched_barrier(0);
        __builtin_amdgcn_s_setprio(1);
        #pragma unroll
        for (int mf = 0; mf < 4; ++mf) {
            MFMA16(acc[mf][0], af0[mf], bf0[0]);
            MFMA16(acc[mf][1], af0[mf], bf0[1]);
            MFMA16(acc[mf][2], af0[mf], bf0[2]);
            MFMA16(acc[mf][3], af0[mf], bf0[3]);
        }
        __builtin_amdgcn_s_setprio(0);
        __builtin_amdgcn_s_barrier();
        // phase 1
        #pragma unroll
        for (int mf = 4; mf < 8; ++mf) af0[mf] = LDF(ab + aoffs[mf]);
        #pragma unroll
        for (int nf = 0; nf < 4; ++nf) bf1[nf] = LDF(ab + 16384 + (boffs[nf] ^ 32));
        if (t <= 6) stageA(t + 1, 1);
        __builtin_amdgcn_s_barrier();
        asm volatile("s_waitcnt lgkmcnt(0)" ::: "memory");
        __builtin_amdgcn_sched_barrier(0);
        __builtin_amdgcn_s_setprio(1);
        #pragma unroll
        for (int mf = 4; mf < 8; ++mf) {
            MFMA16(acc[mf][0], af0[mf], bf0[0]);
            MFMA16(acc[mf][1], af0[mf], bf0[1]);
            MFMA16(acc[mf][2], af0[mf], bf0[2]);
            MFMA16(acc[mf][3], af0[mf], bf0[3]);
        }
        __builtin_amdgcn_s_setprio(0);
        __builtin_amdgcn_s_barrier();
        // phase 2
        #pragma unroll
        for (int mf = 0; mf < 4; ++mf) af1[mf] = LDF(ab + (aoffs[mf] ^ 32));
        if (t <= 5) stageB(t + 2, 0);
        __builtin_amdgcn_s_barrier();
        asm volatile("s_waitcnt lgkmcnt(0)" ::: "memory");
        __builtin_amdgcn_sched_barrier(0);
        __builtin_amdgcn_s_setprio(1);
        #pragma unroll
        for (int mf = 0; mf < 4; ++mf) {
            MFMA16(acc[mf][0], af1[mf], bf1[0]);
            MFMA16(acc[mf][1], af1[mf], bf1[1]);
            MFMA16(acc[mf][2], af1[mf], bf1[2]);
            MFMA16(acc[mf][3], af1[mf], bf1[3]);
        }
        __builtin_amdgcn_s_setprio(0);
        __builtin_amdgcn_s_barrier();
        // phase 3
        #pragma unroll
        for (int mf = 4; mf < 8; ++mf) af1[mf] = LDF(ab + (aoffs[mf] ^ 32));
        if (t <= 5) stageB(t + 2, 1);
        __builtin_amdgcn_s_barrier();
        asm volatile("s_waitcnt lgkmcnt(0)" ::: "memory");
        __builtin_amdgcn_sched_barrier(0);
        __builtin_amdgcn_s_setprio(1);
        #pragma unroll
        for (int mf = 4; mf < 8; ++mf) {
            MFMA16(acc[mf][0], af1[mf], bf1[0]);
            MFMA16(acc[mf][1], af1[mf], bf1[1]);
            MFMA16(acc[mf][2], af1[mf], bf1[2]);
            MFMA16(acc[mf][3], af1[mf], bf1[3]);
        }
        __builtin_amdgcn_s_setprio(0);
        if (t <= 5) {
            asm volatile("s_waitcnt vmcnt(4)" ::: "memory");
        } else if (t == 6) {
            asm volatile("s_waitcnt vmcnt(0)" ::: "memory");
        }
        __builtin_amdgcn_sched_barrier(0);
        __builtin_amdgcn_s_barrier();
    }

    #pragma unroll
    for (int mf = 0; mf < 8; ++mf) {
        #pragma unroll
        for (int nf = 0; nf < 4; ++nf) {
            #pragma unroll
            for (int r = 0; r < 4; ++r) {
                long grow = row0 + wm * 128 + mf * 16 + (lane >> 4) * 4 + r;
                int  gcol = col0 + wn * 64 + nf * 16 + fr;
                float v = acc[mf][nf][r];
                if constexpr (OUT_BF16) ((u16*)Dp)[grow * NCOL + gcol] = f2bf(v);
                else                    ((float*)Dp)[grow * NCOL + gcol] = v;
            }
        }
    }
}

// ---------------------------------------------------------------------------
extern "C" void kernel_launch(void* const* d_in, const int* in_sizes, int n_in,
                              void* d_out, int out_size, void* d_ws, size_t ws_size,
                              hipStream_t stream) {
    const float* x    = (const float*)d_in[0];   // (B, N, C) fp32
    const float* Wqkv = (const float*)d_in[1];   // (512, 1536) fp32
    const float* Wout = (const float*)d_in[2];   // (512, 512) fp32
    float* out = (float*)d_out;

    const size_t xc_elems = (size_t)M_ * C_;     // 67.1M u16
    // layout: xb | attn_buf | WqkvT2 | WoutT  (~272 MB total, no aliasing)
    u16* xb       = (u16*)d_ws;
    u16* attn_buf = xb + xc_elems;
    u16* WqkvT2   = attn_buf + xc_elems;
    u16* WoutT    = WqkvT2 + (size_t)1536 * 512;
    if (ws_size < ((size_t)(WoutT + (size_t)512 * 512) - (size_t)d_ws)) return;

    // 1) weight + activation prep
    prep_w2<<<(1536 * 64) / 256, 256, 0, stream>>>(Wqkv, WqkvT2);
    prep_w<<<(512 * 64) / 256, 256, 0, stream>>>(Wout, WoutT, 512);
    prep_x<<<8192, 256, 0, stream>>>(x, xb);

    // 2) fused qkv-GEMM + banded attention (128-row tiles, 2 blocks/CU,
    //    8-wave epilogue, conflict-free scratch)
    gemm_attn<<<8192, 512, 0, stream>>>(xb, WqkvT2, attn_buf);

    // 3) out = attn @ W_out
    gemm8_k<512, false, true><<<1024, 512, 0, stream>>>(attn_buf, WoutT, (void*)out, 2);
}

// Round 21
// 453.626 us; speedup vs baseline: 1.7784x; 1.0689x over previous
//
#include <hip/hip_runtime.h>
#include <stdint.h>

// Problem constants (fixed instance from setup_inputs)
#define B_   2
#define T_   64
#define S_   1024
#define C_   512
#define H_   8
#define N_   (T_ * S_)      // 65536
#define M_   (B_ * N_)      // 131072
#define WIN_ 5

typedef unsigned short u16;
typedef __bf16 bf16;
typedef __bf16 bf16x8 __attribute__((ext_vector_type(8)));
typedef float  f32x4  __attribute__((ext_vector_type(4)));
typedef u16    u16x8  __attribute__((ext_vector_type(8)));

static __device__ __forceinline__ u16 f2bf(float f) {
    return __builtin_bit_cast(u16, (bf16)f);   // RNE
}
static __device__ __forceinline__ float bf2f(u16 u) {
    return __builtin_bit_cast(float, (uint32_t)u << 16);
}
// async global->LDS, 16B per lane; LDS dest is wave-uniform base + lane*16
static __device__ __forceinline__ void gload16(const void* g, void* l) {
    __builtin_amdgcn_global_load_lds(
        (const __attribute__((address_space(1))) void*)g,
        (__attribute__((address_space(3))) void*)l, 16, 0, 0);
}
// row permutation: logical (b,t,s) flat row -> physical (b,s,t) flat row
static __device__ __forceinline__ long permute_row(long grow) {
    int b = (int)(grow >> 16);
    int t = (int)(grow >> 10) & 63;
    int s = (int)grow & 1023;
    return ((long)((b << 10) | s)) * 64 + t;
}

// Pre-swizzle layout (bf16 [row][512] operands): logical (chunk c in [0,16),
// granule g in [0,4), elem j) stored at
// r*512 + (c ^ ((rl>>3)&1))*32 + ((g ^ ((rl>>1)&3))<<3) + j,
// keys from the TILE-LOCAL row rl. 0 conflicts measured.

// ---------------------------------------------------------------------------
// Wout prep: W [512][512] fp32 -> WT [512][512] bf16, pre-swizzled.
// ---------------------------------------------------------------------------
__global__ __launch_bounds__(256) void prep_w(const float* __restrict__ W,
                                              u16* __restrict__ WT, int NCOL) {
    int id = blockIdx.x * 256 + threadIdx.x;
    int n  = id % NCOL;
    int gi = id / NCOL;
    int chunk = gi >> 2;
    int g     = gi & 3;
    int k0 = chunk * 32 + g * 8;
    int cs = chunk ^ ((n >> 3) & 1);
    int gs = g ^ ((n >> 1) & 3);
    u16x8 w;
    #pragma unroll
    for (int j = 0; j < 8; ++j) w[j] = f2bf(W[(size_t)(k0 + j) * NCOL + n]);
    *(u16x8*)&WT[(size_t)n * 512 + cs * 32 + gs * 8] = w;
}

// ---------------------------------------------------------------------------
// Wqkv prep, head-grouped: W [512][1536] fp32, col n = which*512 + h*64 + d
// -> WT2 row n' = h*192 + which*64 + d, bf16, pre-swizzled with keys from the
// PANEL-LOCAL row which*64+d.
// ---------------------------------------------------------------------------
__global__ __launch_bounds__(256) void prep_w2(const float* __restrict__ W,
                                               u16* __restrict__ WT2) {
    int id = blockIdx.x * 256 + threadIdx.x;
    int n  = id % 1536;
    int gi = id / 1536;
    int chunk = gi >> 2;
    int g     = gi & 3;
    int k0 = chunk * 32 + g * 8;
    int which = n >> 9;
    int h     = (n >> 6) & 7;
    int d     = n & 63;
    int rloc  = which * 64 + d;          // 0..191 panel-local row
    long np   = h * 192 + rloc;
    int cs = chunk ^ ((rloc >> 3) & 1);
    int gs = g ^ ((rloc >> 1) & 3);
    u16x8 w;
    #pragma unroll
    for (int j = 0; j < 8; ++j) w[j] = f2bf(W[(size_t)(k0 + j) * 1536 + n]);
    *(u16x8*)&WT2[(size_t)np * 512 + cs * 32 + gs * 8] = w;
}

// ---------------------------------------------------------------------------
// x prep: x [M][512] fp32 (rows (b,t,s)) -> xb bf16 rows PERMUTED to (b,s,t),
// pre-swizzled with keys from the permuted row index.
// ---------------------------------------------------------------------------
__global__ __launch_bounds__(256) void prep_x(const float* __restrict__ x,
                                              u16* __restrict__ xb) {
    const size_t total = (size_t)M_ * 64;   // 16B granules
    for (size_t id = (size_t)blockIdx.x * 256 + threadIdx.x; id < total;
         id += (size_t)gridDim.x * 256) {
        long r_in = (long)(id >> 6);
        int  gi   = (int)(id & 63);
        int chunk = gi >> 2;
        int g     = gi & 3;
        long rid  = permute_row(r_in);
        int cb  = (int)(rid >> 3) & 1;
        int key = (int)(rid >> 1) & 3;
        const float* src = x + r_in * 512 + chunk * 32 + g * 8;
        f32x4 v0 = *(const f32x4*)(src);
        f32x4 v1 = *(const f32x4*)(src + 4);
        u16x8 w;
        #pragma unroll
        for (int j = 0; j < 4; ++j) { w[j] = f2bf(v0[j]); w[4 + j] = f2bf(v1[j]); }
        *(u16x8*)&xb[(size_t)rid * 512 + (chunk ^ cb) * 32 + ((g ^ key) << 3)] = w;
    }
}

#define LDF(off) __builtin_bit_cast(bf16x8, *(const u16x8*)&lds[(off)])
#define MFMA16(d, a, b) d = __builtin_amdgcn_mfma_f32_16x16x32_bf16(a, b, d, 0, 0, 0)

#define PSTR 200   // panel row stride (u16): pad keeps reads bank-bijective

// ---------------------------------------------------------------------------
// FUSED qkv-GEMM + banded attention, 128-row tiles, 2 blocks/CU (r18 base).
// K-loop unchanged (validated). Epilogue v3: S = QK^T computed ON THE MATRIX
// PIPE from the LDS panel (only the 10 near-diagonal 16x16 tiles per slab;
// wave = (slab, row-strip I), J in {I-1,I,I+1}: 8 ds_read_b128 + <=6 MFMA),
// masked scatter of the band values to scr[row][13] f32 (stride 13 coprime
// to 32 -> conflict-free writes, 2-way reads). Removes the per-thread QK
// VALU loop (352 ops + 22 b128) and the partial-reduce. Softmax + PV +
// pre-swizzled stores unchanged (validated r19/r20).
// ---------------------------------------------------------------------------
__global__ __launch_bounds__(512, 4) void gemm_attn(const u16* __restrict__ Ap,
                                                    const u16* __restrict__ Bp,
                                                    u16* __restrict__ attn) {
    __shared__ u16 lds[40960];   // A0@0 A1@8192 B0@16384 B1@28672 (u16 units)

    const int tid  = threadIdx.x;
    const int lane = tid & 63;
    const int wid  = tid >> 6;    // 0..7
    const int wm   = wid >> 2;    // 0..1
    const int wn   = wid & 3;     // 0..3
    const int fr   = lane & 15;
    const int g0   = lane >> 4;

    const int rowtile = ((blockIdx.x >> 6) << 3) | (blockIdx.x & 7);  // 0..1023
    const int h       = (blockIdx.x >> 3) & 7;
    const long row0   = (long)rowtile * 128;

    // frag LDS offsets (u16, rel. to buffer base), kk=0; kk=1 = ^32
    int aoffs[4], boffs[3];
    #pragma unroll
    for (int mf = 0; mf < 4; ++mf) {
        int lr = wm * 64 + mf * 16 + fr;          // 0..127
        aoffs[mf] = lr * 64 + (((lr >> 3) & 1) << 5) + (((g0 ^ (lr >> 1)) & 3) << 3);
    }
    #pragma unroll
    for (int nf = 0; nf < 3; ++nf) {
        int lc = wn * 48 + nf * 16 + fr;          // 0..191
        boffs[nf] = lc * 64 + (((lc >> 3) & 1) << 5) + (((g0 ^ (lc >> 1)) & 3) << 3);
    }

    const int srow = lane >> 3;        // 0..7
    const int scol = (lane & 7) * 8;   // u16 offset within 128B row window

    auto stageA = [&](int tt, int half) {       // 64 rows per half, 1 issue
        const int ab = (tt & 1) * 8192;
        int r = half * 64 + wid * 8 + srow;     // 0..127
        const u16* g = Ap + (row0 + r) * 512 + tt * 64 + scol;
        gload16(g, (void*)&lds[ab + r * 64]);
    };
    auto stageB = [&](int tt) {                 // 192 rows, 3 issues
        const int bb = 16384 + (tt & 1) * 12288;
        #pragma unroll
        for (int i = 0; i < 3; ++i) {
            int r = i * 64 + wid * 8 + srow;    // 0..191
            const u16* g = Bp + (size_t)(h * 192 + r) * 512 + tt * 64 + scol;
            gload16(g, (void*)&lds[bb + r * 64]);
        }
    };

    f32x4 acc[4][3] = {};

    // ---- prologue: [A0x2, B0x3, B1x3]; vmcnt(3) -> A0,B0 landed, B1 in flight
    stageA(0, 0); stageA(0, 1); stageB(0); stageB(1);
    asm volatile("s_waitcnt vmcnt(3)" ::: "memory");
    __builtin_amdgcn_sched_barrier(0);
    __builtin_amdgcn_s_barrier();

    #pragma unroll
    for (int t = 0; t < 8; ++t) {
        const int ab = (t & 1) * 8192;
        const int bb = 16384 + (t & 1) * 12288;
        bf16x8 af[4], bfv[3];
        // ================= phase 0: kk0 =================
        #pragma unroll
        for (int mf = 0; mf < 4; ++mf) af[mf] = LDF(ab + aoffs[mf]);
        #pragma unroll
        for (int nf = 0; nf < 3; ++nf) bfv[nf] = LDF(bb + boffs[nf]);
        if (t <= 6) { stageA(t + 1, 0); stageA(t + 1, 1); }
        __builtin_amdgcn_s_barrier();
        asm volatile("s_waitcnt lgkmcnt(0)" ::: "memory");
        __builtin_amdgcn_sched_barrier(0);
        __builtin_amdgcn_s_setprio(1);
        #pragma unroll
        for (int mf = 0; mf < 4; ++mf) {
            MFMA16(acc[mf][0], af[mf], bfv[0]);
            MFMA16(acc[mf][1], af[mf], bfv[1]);
            MFMA16(acc[mf][2], af[mf], bfv[2]);
        }
        __builtin_amdgcn_s_setprio(0);
        __builtin_amdgcn_s_barrier();
        // ================= phase 1: kk1 =================
        #pragma unroll
        for (int mf = 0; mf < 4; ++mf) af[mf] = LDF(ab + (aoffs[mf] ^ 32));
        #pragma unroll
        for (int nf = 0; nf < 3; ++nf) bfv[nf] = LDF(bb + (boffs[nf] ^ 32));
        __builtin_amdgcn_s_barrier();
        asm volatile("s_waitcnt lgkmcnt(0)" ::: "memory");
        __builtin_amdgcn_sched_barrier(0);
        __builtin_amdgcn_s_setprio(1);
        #pragma unroll
        for (int mf = 0; mf < 4; ++mf) {
            MFMA16(acc[mf][0], af[mf], bfv[0]);
            MFMA16(acc[mf][1], af[mf], bfv[1]);
            MFMA16(acc[mf][2], af[mf], bfv[2]);
        }
        __builtin_amdgcn_s_setprio(0);
        __builtin_amdgcn_s_barrier();
        // ================= phase 2: B prefetch (all B(t) reads retired) =====
        if (t <= 6) {
            if (t <= 5) {
                stageB(t + 2);
                asm volatile("s_waitcnt vmcnt(3)" ::: "memory");
            } else {
                asm volatile("s_waitcnt vmcnt(0)" ::: "memory");   // A7,B7 landed
            }
            __builtin_amdgcn_sched_barrier(0);
            __builtin_amdgcn_s_barrier();
        }
    }

    // ---- epilogue: acc -> LDS panel [128][PSTR] bf16, linear cols ----
    __builtin_amdgcn_sched_barrier(0);
    #pragma unroll
    for (int mf = 0; mf < 4; ++mf) {
        #pragma unroll
        for (int nf = 0; nf < 3; ++nf) {
            #pragma unroll
            for (int r = 0; r < 4; ++r) {
                int row = wm * 64 + mf * 16 + (lane >> 4) * 4 + r;
                int col = wn * 48 + nf * 16 + fr;
                lds[row * PSTR + col] = f2bf(acc[mf][nf][r]);
            }
        }
    }
    __syncthreads();

    float* scr = (float*)&lds[25600];   // [128 rows][13] f32 (stride 13)

    // ---- S = QK^T via MFMA (wave = slab, row-strip I); masked band scatter
    {
        const int slab = wid >> 2;      // 0..1
        const int I    = wid & 3;       // row strip (16 rows)
        const int abase = (slab * 64 + I * 16 + fr) * PSTR;
        bf16x8 qa0 = LDF(abase + g0 * 8);
        bf16x8 qa1 = LDF(abase + 32 + g0 * 8);
        #pragma unroll
        for (int dj = -1; dj <= 1; ++dj) {
            int J = I + dj;
            if (J >= 0 && J <= 3) {     // wave-uniform branch
                const int bbase = (slab * 64 + J * 16 + fr) * PSTR + 64;
                bf16x8 kb0 = LDF(bbase + g0 * 8);
                bf16x8 kb1 = LDF(bbase + 32 + g0 * 8);
                f32x4 sv = {0.f, 0.f, 0.f, 0.f};
                MFMA16(sv, qa0, kb0);
                MFMA16(sv, qa1, kb1);
                #pragma unroll
                for (int r = 0; r < 4; ++r) {
                    int row = I * 16 + (lane >> 4) * 4 + r;   // 0..63 in slab
                    int u   = J * 16 + fr;
                    int i   = u - row + WIN_;
                    if (i >= 0 && i < 11)
                        scr[(slab * 64 + row) * 13 + i] = sv[r];
                }
            }
        }
    }
    __syncthreads();

    // ---- softmax + PV: wave = (slab = wid>>2, d-quarter q = wid&3) ----
    {
        const int slab = wid >> 2;
        const int q    = wid & 3;
        const int t    = lane;
        const int prow = slab * 64 + t;

        float p[11];
        float m = -1e30f;
        #pragma unroll
        for (int i = 0; i < 11; ++i) {
            int u = t - WIN_ + i;
            if (u >= 0 && u < 64) {
                p[i] = scr[prow * 13 + i] * 0.125f;
                m = fmaxf(m, p[i]);
            } else {
                p[i] = -1e30f;
            }
        }
        float sum = 0.f;
        #pragma unroll
        for (int i = 0; i < 11; ++i) {
            int u = t - WIN_ + i;
            float e = (u >= 0 && u < 64) ? __expf(p[i] - m) : 0.f;
            p[i] = e;
            sum += e;
        }
        const float inv = 1.f / sum;

        // PV for this quarter's 16 output channels
        float o[16];
        #pragma unroll
        for (int d = 0; d < 16; ++d) o[d] = 0.f;
        #pragma unroll
        for (int i = 0; i < 11; ++i) {
            int u = t - WIN_ + i;
            if (u >= 0 && u < 64) {
                const int ub = (slab * 64 + u) * PSTR + 128;
                float pv = p[i] * inv;
                #pragma unroll
                for (int cc = 0; cc < 2; ++cc) {
                    u16x8 vv = *(const u16x8*)&lds[ub + (q * 2 + cc) * 8];
                    #pragma unroll
                    for (int j = 0; j < 8; ++j) o[cc * 8 + j] += pv * bf2f(vv[j]);
                }
            }
        }
        // pre-swizzled store (2 chunks c = 2q, 2q+1); keys from s (gemm3 A)
        long rid = row0 + prow;
        int s = (int)(rid >> 6) & 1023;
        size_t rowbase = (size_t)rid * C_;
        const int cb  = (s >> 3) & 1;
        const int key = (s >> 1) & 3;
        #pragma unroll
        for (int cc = 0; cc < 2; ++cc) {
            int c = q * 2 + cc;
            u16x8 w;
            #pragma unroll
            for (int j = 0; j < 8; ++j) w[j] = f2bf(o[cc * 8 + j]);
            int off = (((2 * h + (c >> 2)) ^ cb) << 5) + (((c & 3) ^ key) << 3);
            *(u16x8*)&attn[rowbase + off] = w;
        }
    }
}

// ---------------------------------------------------------------------------
// 256x256 8-phase pipelined GEMM (r11-validated) — used for out = attn@W_out.
// ---------------------------------------------------------------------------
template<int NCOL, bool OUT_BF16, bool A_PERM>
__global__ __launch_bounds__(512, 2) void gemm8_k(const u16* __restrict__ Ap,
                                                  const u16* __restrict__ Bp,
                                                  void* __restrict__ Dp, int gx) {
    __shared__ u16 lds[65536];   // dbuf0{A,B} | dbuf1{A,B}, 16384 u16 each

    const int tid  = threadIdx.x;
    const int lane = tid & 63;
    const int wid  = tid >> 6;
    const int wm   = wid >> 2;
    const int wn   = wid & 3;
    const int fr   = lane & 15;
    const int g0   = lane >> 4;

    const int nwg = gridDim.x;
    const int q8  = nwg >> 3;
    const int bid = blockIdx.x;
    const int wg  = (bid & 7) * q8 + (bid >> 3);
    const int bx  = wg % gx;
    const int by  = wg / gx;
    const long row0 = (long)by * 256;
    const int  col0 = bx * 256;

    int aoffs[8], boffs[4];
    #pragma unroll
    for (int mf = 0; mf < 8; ++mf) {
        int lr = wm * 128 + mf * 16 + fr;
        aoffs[mf] = lr * 64 + (((lr >> 3) & 1) << 5) + (((g0 ^ (lr >> 1)) & 3) << 3);
    }
    #pragma unroll
    for (int nf = 0; nf < 4; ++nf) {
        int lc = wn * 64 + nf * 16 + fr;
        boffs[nf] = lc * 64 + (((lc >> 3) & 1) << 5) + (((g0 ^ (lc >> 1)) & 3) << 3);
    }

    const int srow = lane >> 3;
    const int scol = (lane & 7) * 8;

    long arow_phys[4];
    #pragma unroll
    for (int half = 0; half < 2; ++half)
        #pragma unroll
        for (int i = 0; i < 2; ++i) {
            int r = half * 128 + i * 64 + wid * 8 + srow;
            long grow = row0 + r;
            arow_phys[half * 2 + i] = A_PERM ? permute_row(grow) : grow;
        }

    auto stageA = [&](int tt, int half) {
        const int ab = (tt & 1) * 32768;
        #pragma unroll
        for (int i = 0; i < 2; ++i) {
            int r = half * 128 + i * 64 + wid * 8 + srow;
            const u16* g = Ap + arow_phys[half * 2 + i] * 512 + tt * 64 + scol;
            gload16(g, (void*)&lds[ab + r * 64]);
        }
    };
    auto stageB = [&](int tt, int half) {
        const int ab = (tt & 1) * 32768;
        #pragma unroll
        for (int i = 0; i < 2; ++i) {
            int r = half * 128 + i * 64 + wid * 8 + srow;
            const u16* g = Bp + (size_t)(col0 + r) * 512 + tt * 64 + scol;
            gload16(g, (void*)&lds[ab + 16384 + r * 64]);
        }
    };

    f32x4 acc[8][4] = {};

    stageA(0, 0); stageA(0, 1); stageB(0, 0); stageB(0, 1);
    stageB(1, 0); stageB(1, 1);
    asm volatile("s_waitcnt vmcnt(4)" ::: "memory");
    __builtin_amdgcn_sched_barrier(0);
    __builtin_amdgcn_s_barrier();

    #pragma unroll
    for (int t = 0; t < 8; ++t) {
        const int ab = (t & 1) * 32768;
        bf16x8 af0[8], af1[8], bf0[4], bf1[4];
        // phase 0
        #pragma unroll
        for (int mf = 0; mf < 4; ++mf) af0[mf] = LDF(ab + aoffs[mf]);
        #pragma unroll
        for (int nf = 0; nf < 4; ++nf) bf0[nf] = LDF(ab + 16384 + boffs[nf]);
        if (t <= 6) stageA(t + 1, 0);
        __builtin_amdgcn_s_barrier();
        asm volatile("s_waitcnt lgkmcnt(0)" ::: "memory");
        __builtin_amdgcn_sched_barrier(0);
        __builtin_amdgcn_s_setprio(1);
        #pragma unroll
        for (int mf = 0; mf < 4; ++mf) {
            MFMA16(acc[mf][0], af0[mf], bf0[0]);
            MFMA16(acc[mf][1], af0[mf], bf0[1]);
            MFMA16(acc[mf][2], af0[mf], bf0[2]);
            MFMA16(acc[mf][3], af0[mf], bf0[3]);
        }
        __builtin_amdgcn_s_setprio(0);
        __builtin_amdgcn_s_barrier();
        // phase 1
        #pragma unroll
        for (int mf = 4; mf < 8; ++mf) af0[mf] = LDF(ab + aoffs[mf]);
        #pragma unroll
        for (int nf = 0; nf < 4; ++nf) bf1[nf] = LDF(ab + 16384 + (boffs[nf] ^ 32));
        if (t <= 6) stageA(t + 1, 1);
        __builtin_amdgcn_s_barrier();
        asm volatile("s_waitcnt lgkmcnt(0)" ::: "memory");
        __builtin_amdgcn_sched_barrier(0);
        __builtin_amdgcn_s_setprio(1);
        #pragma unroll
        for (int mf = 4; mf < 8; ++mf) {
            MFMA16(acc[mf][0], af0[mf], bf0[0]);
            MFMA16(acc[mf][1], af0[mf], bf0[1]);
            MFMA16(acc[mf][2], af0[mf], bf0[2]);
            MFMA16(acc[mf][3], af0[mf], bf0[3]);
        }
        __builtin_amdgcn_s_setprio(0);
        __builtin_amdgcn_s_barrier();
        // phase 2
        #pragma unroll
        for (int mf = 0; mf < 4; ++mf) af1[mf] = LDF(ab + (aoffs[mf] ^ 32));
        if (t <= 5) stageB(t + 2, 0);
        __builtin_amdgcn_s_barrier();
        asm volatile("s_waitcnt lgkmcnt(0)" ::: "memory");
        __builtin_amdgcn_sched_barrier(0);
        __builtin_amdgcn_s_setprio(1);
        #pragma unroll
        for (int mf = 0; mf < 4; ++mf) {
            MFMA16(acc[mf][0], af1[mf], bf1[0]);
            MFMA16(acc[mf][1], af1[mf], bf1[1]);
            MFMA16(acc[mf][2], af1[mf], bf1[2]);
            MFMA16(acc[mf][3], af1[mf], bf1[3]);
        }
        __builtin_amdgcn_s_setprio(0);
        __builtin_amdgcn_s_barrier();
        // phase 3
        #pragma unroll
        for (int mf = 4; mf < 8; ++mf) af1[mf] = LDF(ab + (aoffs[mf] ^ 32));
        if (t <= 5) stageB(t + 2, 1);
        __builtin_amdgcn_s_barrier();
        asm volatile("s_waitcnt lgkmcnt(0)" ::: "memory");
        __builtin_amdgcn_sched_barrier(0);
        __builtin_amdgcn_s_setprio(1);
        #pragma unroll
        for (int mf = 4; mf < 8; ++mf) {
            MFMA16(acc[mf][0], af1[mf], bf1[0]);
            MFMA16(acc[mf][1], af1[mf], bf1[1]);
            MFMA16(acc[mf][2], af1[mf], bf1[2]);
            MFMA16(acc[mf][3], af1[mf], bf1[3]);
        }
        __builtin_amdgcn_s_setprio(0);
        if (t <= 5) {
            asm volatile("s_waitcnt vmcnt(4)" ::: "memory");
        } else if (t == 6) {
            asm volatile("s_waitcnt vmcnt(0)" ::: "memory");
        }
        __builtin_amdgcn_sched_barrier(0);
        __builtin_amdgcn_s_barrier();
    }

    #pragma unroll
    for (int mf = 0; mf < 8; ++mf) {
        #pragma unroll
        for (int nf = 0; nf < 4; ++nf) {
            #pragma unroll
            for (int r = 0; r < 4; ++r) {
                long grow = row0 + wm * 128 + mf * 16 + (lane >> 4) * 4 + r;
                int  gcol = col0 + wn * 64 + nf * 16 + fr;
                float v = acc[mf][nf][r];
                if constexpr (OUT_BF16) ((u16*)Dp)[grow * NCOL + gcol] = f2bf(v);
                else                    ((float*)Dp)[grow * NCOL + gcol] = v;
            }
        }
    }
}

// ---------------------------------------------------------------------------
extern "C" void kernel_launch(void* const* d_in, const int* in_sizes, int n_in,
                              void* d_out, int out_size, void* d_ws, size_t ws_size,
                              hipStream_t stream) {
    const float* x    = (const float*)d_in[0];   // (B, N, C) fp32
    const float* Wqkv = (const float*)d_in[1];   // (512, 1536) fp32
    const float* Wout = (const float*)d_in[2];   // (512, 512) fp32
    float* out = (float*)d_out;

    const size_t xc_elems = (size_t)M_ * C_;     // 67.1M u16
    // layout: xb | attn_buf | WqkvT2 | WoutT  (~272 MB total, no aliasing)
    u16* xb       = (u16*)d_ws;
    u16* attn_buf = xb + xc_elems;
    u16* WqkvT2   = attn_buf + xc_elems;
    u16* WoutT    = WqkvT2 + (size_t)1536 * 512;
    if (ws_size < ((size_t)(WoutT + (size_t)512 * 512) - (size_t)d_ws)) return;

    // 1) weight + activation prep
    prep_w2<<<(1536 * 64) / 256, 256, 0, stream>>>(Wqkv, WqkvT2);
    prep_w<<<(512 * 64) / 256, 256, 0, stream>>>(Wout, WoutT, 512);
    prep_x<<<8192, 256, 0, stream>>>(x, xb);

    // 2) fused qkv-GEMM + banded attention (128-row tiles, 2 blocks/CU,
    //    MFMA QK^T epilogue)
    gemm_attn<<<8192, 512, 0, stream>>>(xb, WqkvT2, attn_buf);

    // 3) out = attn @ W_out
    gemm8_k<512, false, true><<<1024, 512, 0, stream>>>(attn_buf, WoutT, (void*)out, 2);
}